// Round 2
// baseline (1329.981 us; speedup 1.0000x reference)
//
#include <hip/hip_runtime.h>
#include <math.h>

#define BATCH 128
#define NR 2312          // 8*17*17 routes
#define RC 68            // route chunk
#define NCH 34           // NR / RC
#define NC 10            // caps
#define OC 16            // out ch
#define IC 8             // in ch

// ---- workspace layout (float offsets) ----
#define OFF_X1    0                        // 128*32*41*41 = 6885376
#define OFF_U0    6885376                  // 128*64*289   = 2367488
#define OFF_XT    9252864                  // 2312*8*128   = 2367488
#define OFF_SC    11620352                 // 1024
#define OFF_BIJ   11621376                 // 23120
#define OFF_C     11644496                 // 23120
#define OFF_SP    11667616                 // 34*10*16*128 = 696320
#define OFF_V     12363936                 // 20480

__global__ void k_zero(float* __restrict__ p, int n) {
    int i = blockIdx.x * 256 + threadIdx.x;
    if (i < n) p[i] = 0.f;
}

// conv1 + bias + relu: data(128,3,49,49) -> x1(128,32,41,41)
__global__ __launch_bounds__(512) void k_conv1(const float* __restrict__ data,
                                               const float* __restrict__ cw,
                                               const float* __restrict__ cb,
                                               float* __restrict__ x1) {
    int b = blockIdx.x >> 2, cog = blockIdx.x & 3;   // 8 out-ch per block
    __shared__ float in_s[3 * 49 * 52];              // row stride 52 (cols 49..51 garbage, never stored)
    __shared__ float w_s[8 * 243];
    __shared__ float b_s[8];
    for (int k = threadIdx.x; k < 3 * 49 * 49; k += 512) {
        int ci = k / 2401, rem = k % 2401;
        int r = rem / 49, cc = rem % 49;
        in_s[ci * 2548 + r * 52 + cc] = data[(b * 3 + ci) * 2401 + rem];
    }
    for (int k = threadIdx.x; k < 8 * 243; k += 512)
        w_s[k] = cw[cog * 8 * 243 + k];
    if (threadIdx.x < 8) b_s[threadIdx.x] = cb[cog * 8 + threadIdx.x];
    __syncthreads();
    int t = threadIdx.x;
    if (t >= 451) return;                 // 41 h * 11 w-groups
    int h = t / 11, w0 = (t % 11) * 4;
    float acc[8][4];
#pragma unroll
    for (int co = 0; co < 8; co++)
#pragma unroll
        for (int j = 0; j < 4; j++) acc[co][j] = 0.f;
    for (int ci = 0; ci < 3; ci++) {
#pragma unroll 1
        for (int kh = 0; kh < 9; kh++) {
            const float* row = &in_s[ci * 2548 + (h + kh) * 52 + w0];
            float in[12];
#pragma unroll
            for (int j = 0; j < 12; j++) in[j] = row[j];
#pragma unroll
            for (int co = 0; co < 8; co++) {
                const float* wr = &w_s[co * 243 + ci * 81 + kh * 9];
#pragma unroll
                for (int kw = 0; kw < 9; kw++) {
                    float wt = wr[kw];
#pragma unroll
                    for (int j = 0; j < 4; j++) acc[co][j] = fmaf(wt, in[kw + j], acc[co][j]);
                }
            }
        }
    }
#pragma unroll
    for (int co = 0; co < 8; co++) {
        float bias = b_s[co];
#pragma unroll
        for (int j = 0; j < 4; j++) {
            int w = w0 + j;
            if (w < 41) {
                float val = acc[co][j] + bias;
                x1[((b * 32 + cog * 8 + co) * 41 + h) * 41 + w] = val > 0.f ? val : 0.f;
            }
        }
    }
}

// conv2 (stride2) + bias: x1(128,32,41,41) -> u0(128,64,17,17)
// block = (b, 16-co group); thread = (h, co) -> full 17-wide output row.
// LDS: input tile (4 ci, rows padded to 44) + weights (kw padded to 12).
__global__ __launch_bounds__(320) void k_conv2(const float* __restrict__ x1,
                                               const float* __restrict__ pw,
                                               const float* __restrict__ pb,
                                               float* __restrict__ u0) {
    int b = blockIdx.x >> 2, cog = blockIdx.x & 3;
    __shared__ float in_s[4 * 41 * 44];    // ci stride 1804 (16B aligned), row stride 44
    __shared__ float w_s[16 * 4 * 9 * 12]; // [co][ci][kh][kw pad 12]
    const int t = threadIdx.x;
    const int h = t >> 4, co = t & 15;     // valid for t < 272
    float acc[17];
#pragma unroll
    for (int j = 0; j < 17; j++) acc[j] = 0.f;
#pragma unroll 1
    for (int g = 0; g < 8; g++) {
        __syncthreads();
        // stage input: 4 ci x 41 x 41
        for (int k = t; k < 4 * 1681; k += 320) {
            int ci = k / 1681, rem = k - ci * 1681;
            int r = rem / 41, cc = rem - r * 41;
            in_s[ci * 1804 + r * 44 + cc] = x1[((b * 32 + g * 4 + ci) * 41 + r) * 41 + cc];
        }
        // stage weights: pw[co_g][ci_g][9][9] -> w_s[co][ci][kh][12]
        for (int k = t; k < 16 * 324; k += 320) {
            int co2 = k / 324, rem = k - co2 * 324;
            int ci = rem / 81, q = rem - ci * 81;
            int kh = q / 9, kw = q - kh * 9;
            w_s[((co2 * 4 + ci) * 9 + kh) * 12 + kw] =
                pw[((cog * 16 + co2) * 32 + g * 4 + ci) * 81 + q];
        }
        __syncthreads();
        if (t < 272) {
#pragma unroll 1
            for (int ci = 0; ci < 4; ci++) {
#pragma unroll 1
                for (int kh = 0; kh < 9; kh++) {
                    const float* row = &in_s[ci * 1804 + (2 * h + kh) * 44];
                    float in[41];
#pragma unroll
                    for (int j = 0; j < 41; j++) in[j] = row[j];
                    const float* wr = &w_s[((co * 4 + ci) * 9 + kh) * 12];
                    float w[9];
#pragma unroll
                    for (int j = 0; j < 9; j++) w[j] = wr[j];
#pragma unroll
                    for (int kw = 0; kw < 9; kw++)
#pragma unroll
                        for (int ow = 0; ow < 17; ow++)
                            acc[ow] = fmaf(w[kw], in[2 * ow + kw], acc[ow]);
                }
            }
        }
    }
    if (t < 272) {
        float bias = pb[cog * 16 + co];
#pragma unroll
        for (int ow = 0; ow < 17; ow++)
            u0[((b * 64 + cog * 16 + co) * 17 + h) * 17 + ow] = acc[ow] + bias;
    }
}

// per-(b,i) squash scale over 2312 routes (contiguous: channels i*8..i*8+7)
__global__ void k_sumsq(const float* __restrict__ u0, float* __restrict__ scale) {
    int bi = blockIdx.x;                     // b*8 + i
    const float* base = &u0[bi * 8 * 289];
    float sum = 0.f;
    for (int k = threadIdx.x; k < 2312; k += 256) { float v = base[k]; sum += v * v; }
#pragma unroll
    for (int d = 32; d; d >>= 1) sum += __shfl_xor(sum, d);
    __shared__ float red[4];
    if ((threadIdx.x & 63) == 0) red[threadIdx.x >> 6] = sum;
    __syncthreads();
    if (threadIdx.x == 0) {
        float sn = red[0] + red[1] + red[2] + red[3];
        scale[bi] = sn / ((1.f + sn) * sqrtf(sn));
    }
}

// build xT[r][i][b] = u0[b][i*8+j][hw] * scale[b,i]  (r = j*289+hw)
// coalesced via LDS tile transpose; block = (i,j), tiles of 32 hw x 128 b
__global__ __launch_bounds__(256) void k_xt(const float* __restrict__ u0,
                                            const float* __restrict__ scale,
                                            float* __restrict__ xT) {
    int i = blockIdx.x >> 3, j = blockIdx.x & 7;
    int ch = i * 8 + j;
    __shared__ float tile[32 * 130];
    int t = threadIdx.x;
#pragma unroll 1
    for (int hw0 = 0; hw0 < 289; hw0 += 32) {
        int rem = 289 - hw0; if (rem > 32) rem = 32;
        __syncthreads();
        for (int k = t; k < 32 * 128; k += 256) {
            int bb = k >> 5, x = k & 31;
            if (x < rem)
                tile[x * 130 + bb] = u0[(bb * 64 + ch) * 289 + hw0 + x];
        }
        __syncthreads();
        for (int k = t; k < 32 * 128; k += 256) {
            int hwl = k >> 7, bb = k & 127;
            if (hwl < rem)
                xT[((size_t)((j * 289 + hw0 + hwl) * 8 + i)) * 128 + bb] =
                    tile[hwl * 130 + bb] * scale[bb * 8 + i];
        }
    }
}

// softmax over caps per route
__global__ void k_softmax(const float* __restrict__ bij, float* __restrict__ cmat) {
    int r = blockIdx.x * 256 + threadIdx.x;
    if (r >= NR) return;
    float x[NC];
    float m = -1e30f;
#pragma unroll
    for (int k = 0; k < NC; k++) { x[k] = bij[r * NC + k]; m = fmaxf(m, x[k]); }
    float s = 0.f;
#pragma unroll
    for (int k = 0; k < NC; k++) { x[k] = expf(x[k] - m); s += x[k]; }
    float inv = 1.f / s;
#pragma unroll
    for (int k = 0; k < NC; k++) cmat[r * NC + k] = x[k] * inv;
}

// s partials: block (chunk,c) computes spart[chunk][c][o][b] = sum over 68 routes
__global__ __launch_bounds__(256) void k_s(const float* __restrict__ xT,
                                           const float* __restrict__ W,
                                           const float* __restrict__ cmat,
                                           float* __restrict__ spart) {
    int chunk = blockIdx.x / NC, c = blockIdx.x % NC;
    int r0 = chunk * RC;
    __shared__ float Wc[RC * 128];
    __shared__ float cs[RC];
    for (int k = threadIdx.x; k < RC * 128; k += 256) {
        int rr = k >> 7, kk = k & 127;
        Wc[k] = W[(size_t)(r0 + rr) * 1280 + c * 128 + kk];
    }
    if (threadIdx.x < RC) cs[threadIdx.x] = cmat[(r0 + threadIdx.x) * NC + c];
    __syncthreads();
    int bl = threadIdx.x & 63;
    int oq = threadIdx.x >> 6;       // wave-uniform
    float acc0[4] = {0.f, 0.f, 0.f, 0.f};
    float acc1[4] = {0.f, 0.f, 0.f, 0.f};
    for (int rr = 0; rr < RC; rr++) {
        const float* xrow = &xT[(size_t)(r0 + rr) * 8 * 128];
        float xa[8], xb[8];
#pragma unroll
        for (int i = 0; i < 8; i++) { xa[i] = xrow[i * 128 + bl]; xb[i] = xrow[i * 128 + bl + 64]; }
        float cr = cs[rr];
        const float* wrow = &Wc[rr * 128 + oq * 32];
#pragma unroll
        for (int oo = 0; oo < 4; oo++) {
            float4 wA = *(const float4*)&wrow[oo * 8];
            float4 wB = *(const float4*)&wrow[oo * 8 + 4];
            float d0 = wA.x * xa[0] + wA.y * xa[1] + wA.z * xa[2] + wA.w * xa[3]
                     + wB.x * xa[4] + wB.y * xa[5] + wB.z * xa[6] + wB.w * xa[7];
            float d1 = wA.x * xb[0] + wA.y * xb[1] + wA.z * xb[2] + wA.w * xb[3]
                     + wB.x * xb[4] + wB.y * xb[5] + wB.z * xb[6] + wB.w * xb[7];
            acc0[oo] = fmaf(cr, d0, acc0[oo]);
            acc1[oo] = fmaf(cr, d1, acc1[oo]);
        }
    }
    float* sp = &spart[((size_t)(chunk * NC + c) * 16) * 128];
#pragma unroll
    for (int oo = 0; oo < 4; oo++) {
        int o = oq * 4 + oo;
        sp[o * 128 + bl] = acc0[oo];
        sp[o * 128 + bl + 64] = acc1[oo];
    }
}

// reduce spart over chunks, squash over o -> v (and d_out[0:20480])
__global__ void k_v(const float* __restrict__ spart, float* __restrict__ v,
                    float* __restrict__ out) {
    int idx = blockIdx.x * 256 + threadIdx.x;     // (bc, o), o = low 4 bits
    int o = idx & 15;
    int bc = idx >> 4;
    int c = bc % NC, b = bc / NC;
    float s = 0.f;
    for (int k = 0; k < NCH; k++)
        s += spart[((size_t)(k * NC + c) * 16 + o) * 128 + b];
    float sq = s * s;
#pragma unroll
    for (int d = 1; d < 16; d <<= 1) sq += __shfl_xor(sq, d);
    float sn = sq;
    float vv = s * sn / ((1.f + sn) * sqrtf(sn));
    v[idx] = vv;
    out[idx] = vv;
}

// a[r,c] = 1/B * sum_{i,o} W[r,c,o,i] * (sum_b xT[r,i,b] * v[b,c,o]);  bij += a
__global__ __launch_bounds__(256) void k_a(const float* __restrict__ xT,
                                           const float* __restrict__ W,
                                           const float* __restrict__ v,
                                           float* __restrict__ bij) {
    int chunk = blockIdx.x / NC, c = blockIdx.x % NC;
    int r0 = chunk * RC;
    __shared__ float Vs[16 * 132];        // stride 132: bank-spread + 16B aligned
    __shared__ float red[4];
    for (int k = threadIdx.x; k < 2048; k += 256) {
        int o = k & 15, b = k >> 4;
        Vs[o * 132 + b] = v[(b * NC + c) * 16 + o];
    }
    __syncthreads();
    int t = threadIdx.x;
    int half = t >> 7;
    int i = t & 7;
    int o = (t >> 3) & 15;
    const float* vr = &Vs[o * 132];
    for (int rs = 0; rs < NCH; rs++) {
        int r = r0 + rs * 2 + half;
        const float* xr = &xT[(size_t)(r * 8 + i) * 128];
        float g = 0.f;
#pragma unroll 8
        for (int bb = 0; bb < 128; bb += 4) {
            float4 xv = *(const float4*)&xr[bb];
            float4 vv = *(const float4*)&vr[bb];
            g = fmaf(xv.x, vv.x, g); g = fmaf(xv.y, vv.y, g);
            g = fmaf(xv.z, vv.z, g); g = fmaf(xv.w, vv.w, g);
        }
        float p = W[(size_t)r * 1280 + c * 128 + o * 8 + i] * g;
#pragma unroll
        for (int d = 1; d < 64; d <<= 1) p += __shfl_xor(p, d);
        if ((t & 63) == 0) red[t >> 6] = p;
        __syncthreads();
        if (t == 0)   bij[(r0 + rs * 2) * NC + c]     += (red[0] + red[1]) * 0.0078125f;
        if (t == 128) bij[(r0 + rs * 2 + 1) * NC + c] += (red[2] + red[3]) * 0.0078125f;
        __syncthreads();
    }
}

// head: h = tanh(v @ w1 + b1); logit = h @ w2 + b2; sigmoid
__global__ void k_head(const float* __restrict__ v, const float* __restrict__ w1,
                       const float* __restrict__ b1, const float* __restrict__ w2,
                       const float* __restrict__ b2, float* __restrict__ out) {
    int b = blockIdx.x / NC, c = blockIdx.x % NC;
    int t = threadIdx.x;
    float p = 0.f;
    if (t < 100) {
        float hs = b1[c * 100 + t];
        const float* vb = &v[(b * NC + c) * 16];
#pragma unroll
        for (int i = 0; i < 16; i++) hs = fmaf(vb[i], w1[(c * 16 + i) * 100 + t], hs);
        p = tanhf(hs) * w2[c * 100 + t];
    }
#pragma unroll
    for (int d = 1; d < 64; d <<= 1) p += __shfl_xor(p, d);
    __shared__ float red[2];
    if ((t & 63) == 0) red[t >> 6] = p;
    __syncthreads();
    if (t == 0) {
        float logit = red[0] + red[1] + b2[c];
        out[20480 + c * 128 + b] = 1.f / (1.f + expf(-logit));
    }
}

extern "C" void kernel_launch(void* const* d_in, const int* in_sizes, int n_in,
                              void* d_out, int out_size, void* d_ws, size_t ws_size,
                              hipStream_t stream) {
    const float* data   = (const float*)d_in[0];
    const float* conv_w = (const float*)d_in[1];
    const float* conv_b = (const float*)d_in[2];
    const float* prim_w = (const float*)d_in[3];
    const float* prim_b = (const float*)d_in[4];
    const float* Wd     = (const float*)d_in[5];
    const float* hw1    = (const float*)d_in[6];
    const float* hb1    = (const float*)d_in[7];
    const float* hw2    = (const float*)d_in[8];
    const float* hb2    = (const float*)d_in[9];
    float* ws = (float*)d_ws;
    float* x1    = ws + OFF_X1;
    float* u0    = ws + OFF_U0;
    float* xT    = ws + OFF_XT;
    float* scale = ws + OFF_SC;
    float* bij   = ws + OFF_BIJ;
    float* cmat  = ws + OFF_C;
    float* spart = ws + OFF_SP;
    float* v     = ws + OFF_V;
    float* out = (float*)d_out;

    k_zero<<<(23120 + 255) / 256, 256, 0, stream>>>(bij, 23120);
    k_conv1<<<128 * 4, 512, 0, stream>>>(data, conv_w, conv_b, x1);
    k_conv2<<<128 * 4, 320, 0, stream>>>(x1, prim_w, prim_b, u0);
    k_sumsq<<<1024, 256, 0, stream>>>(u0, scale);
    k_xt<<<64, 256, 0, stream>>>(u0, scale, xT);
    for (int it = 0; it < 3; it++) {
        k_softmax<<<(NR + 255) / 256, 256, 0, stream>>>(bij, cmat);
        k_s<<<NCH * NC, 256, 0, stream>>>(xT, Wd, cmat, spart);
        k_v<<<80, 256, 0, stream>>>(spart, v, out);
        if (it < 2) k_a<<<NCH * NC, 256, 0, stream>>>(xT, Wd, v, bij);
    }
    k_head<<<128 * NC, 128, 0, stream>>>(v, hw1, hb1, hw2, hb2, out);
}

// Round 3
// 1010.090 us; speedup vs baseline: 1.3167x; 1.3167x over previous
//
#include <hip/hip_runtime.h>
#include <math.h>

#define BATCH 128
#define NR 2312          // 8*17*17 routes
#define RC 68            // route chunk
#define NCH 34           // NR / RC
#define NC 10            // caps
#define OC 16            // out ch
#define IC 8             // in ch

typedef short short8 __attribute__((ext_vector_type(8)));
typedef float f32x4 __attribute__((ext_vector_type(4)));

// ---- workspace layout (float-slot offsets) ----
#define OFF_XH    0                        // bf16[128][1681][32] = 6885376 bf16 = 3442688 floats
#define OFF_U0    3442688                  // 128*64*289 = 2367488
#define OFF_XT    5810176                  // 2312*8*128 = 2367488
#define OFF_SC    8177664                  // 1024
#define OFF_BIJ   8178688                  // 23120
#define OFF_SP    8201808                  // 34*10*16*128 = 696320
#define OFF_V     8898128                  // 20480
#define OFF_WB    8918608                  // bf16[81][4][16][32] = 165888 bf16 = 82944 floats
// end: 9001552 floats = 36.0 MB

__device__ __forceinline__ unsigned short f2bf(float f) {
    unsigned int u = __float_as_uint(f);
    u = (u + 0x7FFFu + ((u >> 16) & 1u)) >> 16;   // RNE
    return (unsigned short)u;
}

__global__ void k_zero(float* __restrict__ p, int n) {
    int i = blockIdx.x * 256 + threadIdx.x;
    if (i < n) p[i] = 0.f;
}

// conv1 + bias + relu: data(128,3,49,49) -> xh bf16 NHWC [b][h*41+w][ci=32]
__global__ __launch_bounds__(512) void k_conv1(const float* __restrict__ data,
                                               const float* __restrict__ cw,
                                               const float* __restrict__ cb,
                                               unsigned short* __restrict__ xh) {
    int b = blockIdx.x >> 2, cog = blockIdx.x & 3;   // 8 out-ch per block
    __shared__ float in_s[3 * 49 * 52];
    __shared__ float w_s[8 * 243];
    __shared__ float b_s[8];
    for (int k = threadIdx.x; k < 3 * 49 * 49; k += 512) {
        int ci = k / 2401, rem = k % 2401;
        int r = rem / 49, cc = rem % 49;
        in_s[ci * 2548 + r * 52 + cc] = data[(b * 3 + ci) * 2401 + rem];
    }
    for (int k = threadIdx.x; k < 8 * 243; k += 512)
        w_s[k] = cw[cog * 8 * 243 + k];
    if (threadIdx.x < 8) b_s[threadIdx.x] = cb[cog * 8 + threadIdx.x];
    __syncthreads();
    int t = threadIdx.x;
    if (t >= 451) return;                 // 41 h * 11 w-groups
    int h = t / 11, w0 = (t % 11) * 4;
    float acc[8][4];
#pragma unroll
    for (int co = 0; co < 8; co++)
#pragma unroll
        for (int j = 0; j < 4; j++) acc[co][j] = 0.f;
    for (int ci = 0; ci < 3; ci++) {
#pragma unroll 1
        for (int kh = 0; kh < 9; kh++) {
            const float* row = &in_s[ci * 2548 + (h + kh) * 52 + w0];
            float in[12];
#pragma unroll
            for (int j = 0; j < 12; j++) in[j] = row[j];
#pragma unroll
            for (int co = 0; co < 8; co++) {
                const float* wr = &w_s[co * 243 + ci * 81 + kh * 9];
#pragma unroll
                for (int kw = 0; kw < 9; kw++) {
                    float wt = wr[kw];
#pragma unroll
                    for (int j = 0; j < 4; j++) acc[co][j] = fmaf(wt, in[kw + j], acc[co][j]);
                }
            }
        }
    }
#pragma unroll
    for (int j = 0; j < 4; j++) {
        int w = w0 + j;
        if (w < 41) {
            unsigned short pk[8];
#pragma unroll
            for (int co = 0; co < 8; co++) {
                float val = acc[co][j] + b_s[co];
                pk[co] = f2bf(val > 0.f ? val : 0.f);
            }
            *(int4*)&xh[((size_t)(b * 1681 + h * 41 + w)) * 32 + cog * 8] = *(int4*)pk;
        }
    }
}

// prim_w (64,32,9,9) fp32 -> Wb[tap=kh*9+kw][cog=4][co=16][ci=32] bf16
__global__ void k_wprep(const float* __restrict__ pw, unsigned short* __restrict__ Wb) {
    int idx = blockIdx.x * 256 + threadIdx.x;   // 81*2048 = 165888
    if (idx >= 165888) return;
    int ci = idx & 31, co = (idx >> 5) & 15, cog = (idx >> 9) & 3, tap = idx >> 11;
    Wb[idx] = f2bf(pw[((cog * 16 + co) * 32 + ci) * 81 + tap]);
}

// conv2 via implicit-GEMM MFMA: xh (NHWC bf16) -> u0(128,64,289) fp32 (+bias)
// block: (b, mgroup of 64 positions); 4 waves, wave wv = co-group wv.
__global__ __launch_bounds__(256) void k_conv2(const unsigned short* __restrict__ xh,
                                               const unsigned short* __restrict__ Wb,
                                               const float* __restrict__ pb,
                                               float* __restrict__ u0) {
    int b = blockIdx.x / 5, g = blockIdx.x % 5;
    int t = threadIdx.x, lane = t & 63, wv = t >> 6;
    int quad = lane >> 4, mloc = lane & 15;
    const unsigned short* xb = xh + (size_t)b * 53792;   // 1681*32
    int vbase[4];
#pragma unroll
    for (int mt = 0; mt < 4; mt++) {
        int p = g * 64 + mt * 16 + mloc;
        if (p > 288) p = 288;
        int h = p / 17, w = p % 17;
        vbase[mt] = (2 * h * 41 + 2 * w) * 32 + quad * 8;
    }
    f32x4 acc[4];
#pragma unroll
    for (int mt = 0; mt < 4; mt++)
#pragma unroll
        for (int r = 0; r < 4; r++) acc[mt][r] = 0.f;
    const unsigned short* wbase = Wb + ((size_t)wv * 16 + mloc) * 32 + quad * 8;
#pragma unroll 1
    for (int kh = 0; kh < 9; kh++) {
#pragma unroll 1
        for (int kw = 0; kw < 9; kw++) {
            int soff = (kh * 41 + kw) * 32;
            short8 bf = *(const short8*)(wbase + (size_t)(kh * 9 + kw) * 2048);
#pragma unroll
            for (int mt = 0; mt < 4; mt++) {
                short8 af = *(const short8*)(xb + vbase[mt] + soff);
                acc[mt] = __builtin_amdgcn_mfma_f32_16x16x32_bf16(af, bf, acc[mt], 0, 0, 0);
            }
        }
    }
    // epilogue: transpose through LDS so u0 keeps [b][co][hw] layout
    __shared__ float tile[64 * 65];
#pragma unroll
    for (int mt = 0; mt < 4; mt++)
#pragma unroll
        for (int r = 0; r < 4; r++)
            tile[(wv * 16 + mloc) * 65 + mt * 16 + quad * 4 + r] = acc[mt][r];
    __syncthreads();
    int co = t >> 2, p0 = (t & 3) * 16;
    float bias = pb[co];
#pragma unroll
    for (int j = 0; j < 16; j++) {
        int p = g * 64 + p0 + j;
        if (p < 289)
            u0[((size_t)(b * 64 + co)) * 289 + p] = tile[co * 65 + p0 + j] + bias;
    }
}

// per-(b,i) squash scale over 2312 routes (contiguous: channels i*8..i*8+7)
__global__ void k_sumsq(const float* __restrict__ u0, float* __restrict__ scale) {
    int bi = blockIdx.x;                     // b*8 + i
    const float* base = &u0[bi * 8 * 289];
    float sum = 0.f;
    for (int k = threadIdx.x; k < 2312; k += 256) { float v = base[k]; sum += v * v; }
#pragma unroll
    for (int d = 32; d; d >>= 1) sum += __shfl_xor(sum, d);
    __shared__ float red[4];
    if ((threadIdx.x & 63) == 0) red[threadIdx.x >> 6] = sum;
    __syncthreads();
    if (threadIdx.x == 0) {
        float sn = red[0] + red[1] + red[2] + red[3];
        scale[bi] = sn / ((1.f + sn) * sqrtf(sn));
    }
}

// build xT[r][i][b] = u0[b][i*8+j][hw] * scale[b,i]  (r = j*289+hw)
__global__ __launch_bounds__(256) void k_xt(const float* __restrict__ u0,
                                            const float* __restrict__ scale,
                                            float* __restrict__ xT) {
    int i = blockIdx.x >> 3, j = blockIdx.x & 7;
    int ch = i * 8 + j;
    __shared__ float tile[32 * 130];
    int t = threadIdx.x;
#pragma unroll 1
    for (int hw0 = 0; hw0 < 289; hw0 += 32) {
        int rem = 289 - hw0; if (rem > 32) rem = 32;
        __syncthreads();
        for (int k = t; k < 32 * 128; k += 256) {
            int bb = k >> 5, x = k & 31;
            if (x < rem)
                tile[x * 130 + bb] = u0[(bb * 64 + ch) * 289 + hw0 + x];
        }
        __syncthreads();
        for (int k = t; k < 32 * 128; k += 256) {
            int hwl = k >> 7, bb = k & 127;
            if (hwl < rem)
                xT[((size_t)((j * 289 + hw0 + hwl) * 8 + i)) * 128 + bb] =
                    tile[hwl * 130 + bb] * scale[bb * 8 + i];
        }
    }
}

// s partials (softmax fused): block (chunk,c) -> spart[chunk][c][o][b]
__global__ __launch_bounds__(256) void k_s(const float* __restrict__ xT,
                                           const float* __restrict__ W,
                                           const float* __restrict__ bij,
                                           float* __restrict__ spart) {
    int chunk = blockIdx.x / NC, c = blockIdx.x % NC;
    int r0 = chunk * RC;
    __shared__ float Wc[RC * 128];
    __shared__ float cs[RC];
    for (int k = threadIdx.x; k < RC * 128; k += 256) {
        int rr = k >> 7, kk = k & 127;
        Wc[k] = W[(size_t)(r0 + rr) * 1280 + c * 128 + kk];
    }
    if (threadIdx.x < RC) {
        int r = r0 + threadIdx.x;
        float x[NC], m = -1e30f;
#pragma unroll
        for (int k = 0; k < NC; k++) { x[k] = bij[r * NC + k]; m = fmaxf(m, x[k]); }
        float s = 0.f;
#pragma unroll
        for (int k = 0; k < NC; k++) { x[k] = expf(x[k] - m); s += x[k]; }
        cs[threadIdx.x] = x[c] / s;
    }
    __syncthreads();
    int bl = threadIdx.x & 63;
    int oq = threadIdx.x >> 6;       // wave-uniform
    float acc0[4] = {0.f, 0.f, 0.f, 0.f};
    float acc1[4] = {0.f, 0.f, 0.f, 0.f};
    for (int rr = 0; rr < RC; rr++) {
        const float* xrow = &xT[(size_t)(r0 + rr) * 8 * 128];
        float xa[8], xb[8];
#pragma unroll
        for (int i = 0; i < 8; i++) { xa[i] = xrow[i * 128 + bl]; xb[i] = xrow[i * 128 + bl + 64]; }
        float cr = cs[rr];
        const float* wrow = &Wc[rr * 128 + oq * 32];
#pragma unroll
        for (int oo = 0; oo < 4; oo++) {
            float4 wA = *(const float4*)&wrow[oo * 8];
            float4 wB = *(const float4*)&wrow[oo * 8 + 4];
            float d0 = wA.x * xa[0] + wA.y * xa[1] + wA.z * xa[2] + wA.w * xa[3]
                     + wB.x * xa[4] + wB.y * xa[5] + wB.z * xa[6] + wB.w * xa[7];
            float d1 = wA.x * xb[0] + wA.y * xb[1] + wA.z * xb[2] + wA.w * xb[3]
                     + wB.x * xb[4] + wB.y * xb[5] + wB.z * xb[6] + wB.w * xb[7];
            acc0[oo] = fmaf(cr, d0, acc0[oo]);
            acc1[oo] = fmaf(cr, d1, acc1[oo]);
        }
    }
    float* sp = &spart[((size_t)(chunk * NC + c) * 16) * 128];
#pragma unroll
    for (int oo = 0; oo < 4; oo++) {
        int o = oq * 4 + oo;
        sp[o * 128 + bl] = acc0[oo];
        sp[o * 128 + bl + 64] = acc1[oo];
    }
}

// reduce spart over chunks, squash over o -> v (and d_out[0:20480])
__global__ void k_v(const float* __restrict__ spart, float* __restrict__ v,
                    float* __restrict__ out) {
    int idx = blockIdx.x * 256 + threadIdx.x;     // (bc, o), o = low 4 bits
    int o = idx & 15;
    int bc = idx >> 4;
    int c = bc % NC, b = bc / NC;
    float s = 0.f;
    for (int k = 0; k < NCH; k++)
        s += spart[((size_t)(k * NC + c) * 16 + o) * 128 + b];
    float sq = s * s;
#pragma unroll
    for (int d = 1; d < 16; d <<= 1) sq += __shfl_xor(sq, d);
    float sn = sq;
    float vv = s * sn / ((1.f + sn) * sqrtf(sn));
    v[idx] = vv;
    out[idx] = vv;
}

// a[r,c] = 1/B * sum_{i,o} W[r,c,o,i] * (sum_b xT[r,i,b] * v[b,c,o]);  bij += a
__global__ __launch_bounds__(256) void k_a(const float* __restrict__ xT,
                                           const float* __restrict__ W,
                                           const float* __restrict__ v,
                                           float* __restrict__ bij) {
    int chunk = blockIdx.x / NC, c = blockIdx.x % NC;
    int r0 = chunk * RC;
    __shared__ float Vs[16 * 132];
    __shared__ float red[4];
    for (int k = threadIdx.x; k < 2048; k += 256) {
        int o = k & 15, b = k >> 4;
        Vs[o * 132 + b] = v[(b * NC + c) * 16 + o];
    }
    __syncthreads();
    int t = threadIdx.x;
    int half = t >> 7;
    int i = t & 7;
    int o = (t >> 3) & 15;
    const float* vr = &Vs[o * 132];
    for (int rs = 0; rs < NCH; rs++) {
        int r = r0 + rs * 2 + half;
        const float* xr = &xT[(size_t)(r * 8 + i) * 128];
        float g = 0.f;
#pragma unroll 8
        for (int bb = 0; bb < 128; bb += 4) {
            float4 xv = *(const float4*)&xr[bb];
            float4 vv = *(const float4*)&vr[bb];
            g = fmaf(xv.x, vv.x, g); g = fmaf(xv.y, vv.y, g);
            g = fmaf(xv.z, vv.z, g); g = fmaf(xv.w, vv.w, g);
        }
        float p = W[(size_t)r * 1280 + c * 128 + o * 8 + i] * g;
#pragma unroll
        for (int d = 1; d < 64; d <<= 1) p += __shfl_xor(p, d);
        if ((t & 63) == 0) red[t >> 6] = p;
        __syncthreads();
        if (t == 0)   bij[(r0 + rs * 2) * NC + c]     += (red[0] + red[1]) * 0.0078125f;
        if (t == 128) bij[(r0 + rs * 2 + 1) * NC + c] += (red[2] + red[3]) * 0.0078125f;
        __syncthreads();
    }
}

// head: h = tanh(v @ w1 + b1); logit = h @ w2 + b2; sigmoid
__global__ void k_head(const float* __restrict__ v, const float* __restrict__ w1,
                       const float* __restrict__ b1, const float* __restrict__ w2,
                       const float* __restrict__ b2, float* __restrict__ out) {
    int b = blockIdx.x / NC, c = blockIdx.x % NC;
    int t = threadIdx.x;
    float p = 0.f;
    if (t < 100) {
        float hs = b1[c * 100 + t];
        const float* vb = &v[(b * NC + c) * 16];
#pragma unroll
        for (int i = 0; i < 16; i++) hs = fmaf(vb[i], w1[(c * 16 + i) * 100 + t], hs);
        p = tanhf(hs) * w2[c * 100 + t];
    }
#pragma unroll
    for (int d = 1; d < 64; d <<= 1) p += __shfl_xor(p, d);
    __shared__ float red[2];
    if ((t & 63) == 0) red[t >> 6] = p;
    __syncthreads();
    if (t == 0) {
        float logit = red[0] + red[1] + b2[c];
        out[20480 + c * 128 + b] = 1.f / (1.f + expf(-logit));
    }
}

extern "C" void kernel_launch(void* const* d_in, const int* in_sizes, int n_in,
                              void* d_out, int out_size, void* d_ws, size_t ws_size,
                              hipStream_t stream) {
    const float* data   = (const float*)d_in[0];
    const float* conv_w = (const float*)d_in[1];
    const float* conv_b = (const float*)d_in[2];
    const float* prim_w = (const float*)d_in[3];
    const float* prim_b = (const float*)d_in[4];
    const float* Wd     = (const float*)d_in[5];
    const float* hw1    = (const float*)d_in[6];
    const float* hb1    = (const float*)d_in[7];
    const float* hw2    = (const float*)d_in[8];
    const float* hb2    = (const float*)d_in[9];
    float* ws = (float*)d_ws;
    unsigned short* xh = (unsigned short*)(ws + OFF_XH);
    float* u0    = ws + OFF_U0;
    float* xT    = ws + OFF_XT;
    float* scale = ws + OFF_SC;
    float* bij   = ws + OFF_BIJ;
    float* spart = ws + OFF_SP;
    float* v     = ws + OFF_V;
    unsigned short* Wb = (unsigned short*)(ws + OFF_WB);
    float* out = (float*)d_out;

    k_zero<<<(23120 + 255) / 256, 256, 0, stream>>>(bij, 23120);
    k_conv1<<<128 * 4, 512, 0, stream>>>(data, conv_w, conv_b, xh);
    k_wprep<<<648, 256, 0, stream>>>(prim_w, Wb);
    k_conv2<<<128 * 5, 256, 0, stream>>>(xh, Wb, prim_b, u0);
    k_sumsq<<<1024, 256, 0, stream>>>(u0, scale);
    k_xt<<<64, 256, 0, stream>>>(u0, scale, xT);
    for (int it = 0; it < 3; it++) {
        k_s<<<NCH * NC, 256, 0, stream>>>(xT, Wd, bij, spart);
        k_v<<<80, 256, 0, stream>>>(spart, v, out);
        if (it < 2) k_a<<<NCH * NC, 256, 0, stream>>>(xT, Wd, v, bij);
    }
    k_head<<<128 * NC, 128, 0, stream>>>(v, hw1, hb1, hw2, hb2, out);
}

// Round 4
// 550.264 us; speedup vs baseline: 2.4170x; 1.8356x over previous
//
#include <hip/hip_runtime.h>
#include <math.h>

#define BATCH 128
#define NR 2312          // 8*17*17 routes
#define RC 68            // route chunk
#define NCH 34           // NR / RC
#define NC 10            // caps
#define OC 16            // out ch
#define IC 8             // in ch

typedef short short8 __attribute__((ext_vector_type(8)));
typedef float f32x4 __attribute__((ext_vector_type(4)));

// ---- workspace layout (float-slot offsets) ----
#define OFF_XH    0                        // bf16[128][1681][32] = 6885376 bf16 = 3442688 floats
#define OFF_U0    3442688                  // 128*64*289 = 2367488
#define OFF_XT    5810176                  // 2312*8*128 = 2367488
#define OFF_SC    8177664                  // 1024
#define OFF_BIJ   8178688                  // 23120
#define OFF_SP    8201808                  // 34*10*16*128 = 696320
#define OFF_V     8898128                  // 20480
#define OFF_WB    8918608                  // bf16[81][4][16][32] = 165888 bf16 = 82944 floats
#define OFF_VT    9001552                  // 10*16*128 = 20480
// end: 9022032 floats = 36.1 MB

__device__ __forceinline__ unsigned short f2bf(float f) {
    unsigned int u = __float_as_uint(f);
    u = (u + 0x7FFFu + ((u >> 16) & 1u)) >> 16;   // RNE
    return (unsigned short)u;
}

__global__ void k_zero(float* __restrict__ p, int n) {
    int i = blockIdx.x * 256 + threadIdx.x;
    if (i < n) p[i] = 0.f;
}

// conv1 + bias + relu: data(128,3,49,49) -> xh bf16 NHWC [b][h*41+w][ci=32]
__global__ __launch_bounds__(512) void k_conv1(const float* __restrict__ data,
                                               const float* __restrict__ cw,
                                               const float* __restrict__ cb,
                                               unsigned short* __restrict__ xh) {
    int b = blockIdx.x >> 2, cog = blockIdx.x & 3;   // 8 out-ch per block
    __shared__ float in_s[3 * 49 * 52];
    __shared__ float w_s[8 * 243];
    __shared__ float b_s[8];
    for (int k = threadIdx.x; k < 3 * 49 * 49; k += 512) {
        int ci = k / 2401, rem = k % 2401;
        int r = rem / 49, cc = rem % 49;
        in_s[ci * 2548 + r * 52 + cc] = data[(b * 3 + ci) * 2401 + rem];
    }
    for (int k = threadIdx.x; k < 8 * 243; k += 512)
        w_s[k] = cw[cog * 8 * 243 + k];
    if (threadIdx.x < 8) b_s[threadIdx.x] = cb[cog * 8 + threadIdx.x];
    __syncthreads();
    int t = threadIdx.x;
    if (t >= 451) return;                 // 41 h * 11 w-groups
    int h = t / 11, w0 = (t % 11) * 4;
    float acc[8][4];
#pragma unroll
    for (int co = 0; co < 8; co++)
#pragma unroll
        for (int j = 0; j < 4; j++) acc[co][j] = 0.f;
    for (int ci = 0; ci < 3; ci++) {
#pragma unroll 1
        for (int kh = 0; kh < 9; kh++) {
            const float* row = &in_s[ci * 2548 + (h + kh) * 52 + w0];
            float in[12];
#pragma unroll
            for (int j = 0; j < 12; j++) in[j] = row[j];
#pragma unroll
            for (int co = 0; co < 8; co++) {
                const float* wr = &w_s[co * 243 + ci * 81 + kh * 9];
#pragma unroll
                for (int kw = 0; kw < 9; kw++) {
                    float wt = wr[kw];
#pragma unroll
                    for (int j = 0; j < 4; j++) acc[co][j] = fmaf(wt, in[kw + j], acc[co][j]);
                }
            }
        }
    }
#pragma unroll
    for (int j = 0; j < 4; j++) {
        int w = w0 + j;
        if (w < 41) {
            unsigned short pk[8];
#pragma unroll
            for (int co = 0; co < 8; co++) {
                float val = acc[co][j] + b_s[co];
                pk[co] = f2bf(val > 0.f ? val : 0.f);
            }
            *(int4*)&xh[((size_t)(b * 1681 + h * 41 + w)) * 32 + cog * 8] = *(int4*)pk;
        }
    }
}

// prim_w (64,32,9,9) fp32 -> Wb[tap=kh*9+kw][cog=4][co=16][ci=32] bf16
__global__ void k_wprep(const float* __restrict__ pw, unsigned short* __restrict__ Wb) {
    int idx = blockIdx.x * 256 + threadIdx.x;   // 81*2048 = 165888
    if (idx >= 165888) return;
    int ci = idx & 31, co = (idx >> 5) & 15, cog = (idx >> 9) & 3, tap = idx >> 11;
    Wb[idx] = f2bf(pw[((cog * 16 + co) * 32 + ci) * 81 + tap]);
}

// conv2 via implicit-GEMM MFMA: xh (NHWC bf16) -> u0(128,64,289) fp32 (+bias)
__global__ __launch_bounds__(256) void k_conv2(const unsigned short* __restrict__ xh,
                                               const unsigned short* __restrict__ Wb,
                                               const float* __restrict__ pb,
                                               float* __restrict__ u0) {
    int b = blockIdx.x / 5, g = blockIdx.x % 5;
    int t = threadIdx.x, lane = t & 63, wv = t >> 6;
    int quad = lane >> 4, mloc = lane & 15;
    const unsigned short* xb = xh + (size_t)b * 53792;   // 1681*32
    int vbase[4];
#pragma unroll
    for (int mt = 0; mt < 4; mt++) {
        int p = g * 64 + mt * 16 + mloc;
        if (p > 288) p = 288;
        int h = p / 17, w = p % 17;
        vbase[mt] = (2 * h * 41 + 2 * w) * 32 + quad * 8;
    }
    f32x4 acc[4];
#pragma unroll
    for (int mt = 0; mt < 4; mt++)
#pragma unroll
        for (int r = 0; r < 4; r++) acc[mt][r] = 0.f;
    const unsigned short* wbase = Wb + ((size_t)wv * 16 + mloc) * 32 + quad * 8;
#pragma unroll 1
    for (int kh = 0; kh < 9; kh++) {
#pragma unroll 1
        for (int kw = 0; kw < 9; kw++) {
            int soff = (kh * 41 + kw) * 32;
            short8 bf = *(const short8*)(wbase + (size_t)(kh * 9 + kw) * 2048);
#pragma unroll
            for (int mt = 0; mt < 4; mt++) {
                short8 af = *(const short8*)(xb + vbase[mt] + soff);
                acc[mt] = __builtin_amdgcn_mfma_f32_16x16x32_bf16(af, bf, acc[mt], 0, 0, 0);
            }
        }
    }
    // epilogue: transpose through LDS so u0 keeps [b][co][hw] layout
    __shared__ float tile[64 * 65];
#pragma unroll
    for (int mt = 0; mt < 4; mt++)
#pragma unroll
        for (int r = 0; r < 4; r++)
            tile[(wv * 16 + mloc) * 65 + mt * 16 + quad * 4 + r] = acc[mt][r];
    __syncthreads();
    int co = t >> 2, p0 = (t & 3) * 16;
    float bias = pb[co];
#pragma unroll
    for (int j = 0; j < 16; j++) {
        int p = g * 64 + p0 + j;
        if (p < 289)
            u0[((size_t)(b * 64 + co)) * 289 + p] = tile[co * 65 + p0 + j] + bias;
    }
}

// per-(b,i) squash scale over 2312 routes (contiguous: channels i*8..i*8+7)
__global__ void k_sumsq(const float* __restrict__ u0, float* __restrict__ scale) {
    int bi = blockIdx.x;                     // b*8 + i
    const float* base = &u0[bi * 8 * 289];
    float sum = 0.f;
    for (int k = threadIdx.x; k < 2312; k += 256) { float v = base[k]; sum += v * v; }
#pragma unroll
    for (int d = 32; d; d >>= 1) sum += __shfl_xor(sum, d);
    __shared__ float red[4];
    if ((threadIdx.x & 63) == 0) red[threadIdx.x >> 6] = sum;
    __syncthreads();
    if (threadIdx.x == 0) {
        float sn = red[0] + red[1] + red[2] + red[3];
        scale[bi] = sn / ((1.f + sn) * sqrtf(sn));
    }
}

// build xT[r][i][b] = u0[b][i*8+j][hw] * scale[b,i]  (r = j*289+hw)
__global__ __launch_bounds__(256) void k_xt(const float* __restrict__ u0,
                                            const float* __restrict__ scale,
                                            float* __restrict__ xT) {
    int i = blockIdx.x >> 3, j = blockIdx.x & 7;
    int ch = i * 8 + j;
    __shared__ float tile[32 * 130];
    int t = threadIdx.x;
#pragma unroll 1
    for (int hw0 = 0; hw0 < 289; hw0 += 32) {
        int rem = 289 - hw0; if (rem > 32) rem = 32;
        __syncthreads();
        for (int k = t; k < 32 * 128; k += 256) {
            int bb = k >> 5, x = k & 31;
            if (x < rem)
                tile[x * 130 + bb] = u0[(bb * 64 + ch) * 289 + hw0 + x];
        }
        __syncthreads();
        for (int k = t; k < 32 * 128; k += 256) {
            int hwl = k >> 7, bb = k & 127;
            if (hwl < rem)
                xT[((size_t)((j * 289 + hw0 + hwl) * 8 + i)) * 128 + bb] =
                    tile[hwl * 130 + bb] * scale[bb * 8 + i];
        }
    }
}

// s partials (softmax fused): block (chunk,c) -> spart[chunk][c][o][b]
__global__ __launch_bounds__(256) void k_s(const float* __restrict__ xT,
                                           const float* __restrict__ W,
                                           const float* __restrict__ bij,
                                           float* __restrict__ spart) {
    int chunk = blockIdx.x / NC, c = blockIdx.x % NC;
    int r0 = chunk * RC;
    __shared__ float Wc[RC * 128];
    __shared__ float cs[RC];
    for (int k = threadIdx.x; k < RC * 128; k += 256) {
        int rr = k >> 7, kk = k & 127;
        Wc[k] = W[(size_t)(r0 + rr) * 1280 + c * 128 + kk];
    }
    if (threadIdx.x < RC) {
        int r = r0 + threadIdx.x;
        float x[NC], m = -1e30f;
#pragma unroll
        for (int k = 0; k < NC; k++) { x[k] = bij[r * NC + k]; m = fmaxf(m, x[k]); }
        float s = 0.f;
#pragma unroll
        for (int k = 0; k < NC; k++) { x[k] = expf(x[k] - m); s += x[k]; }
        cs[threadIdx.x] = x[c] / s;
    }
    __syncthreads();
    int bl = threadIdx.x & 63;
    int oq = threadIdx.x >> 6;       // wave-uniform
    float acc0[4] = {0.f, 0.f, 0.f, 0.f};
    float acc1[4] = {0.f, 0.f, 0.f, 0.f};
    for (int rr = 0; rr < RC; rr++) {
        const float* xrow = &xT[(size_t)(r0 + rr) * 8 * 128];
        float xa[8], xb[8];
#pragma unroll
        for (int i = 0; i < 8; i++) { xa[i] = xrow[i * 128 + bl]; xb[i] = xrow[i * 128 + bl + 64]; }
        float cr = cs[rr];
        const float* wrow = &Wc[rr * 128 + oq * 32];
#pragma unroll
        for (int oo = 0; oo < 4; oo++) {
            float4 wA = *(const float4*)&wrow[oo * 8];
            float4 wB = *(const float4*)&wrow[oo * 8 + 4];
            float d0 = wA.x * xa[0] + wA.y * xa[1] + wA.z * xa[2] + wA.w * xa[3]
                     + wB.x * xa[4] + wB.y * xa[5] + wB.z * xa[6] + wB.w * xa[7];
            float d1 = wA.x * xb[0] + wA.y * xb[1] + wA.z * xb[2] + wA.w * xb[3]
                     + wB.x * xb[4] + wB.y * xb[5] + wB.z * xb[6] + wB.w * xb[7];
            acc0[oo] = fmaf(cr, d0, acc0[oo]);
            acc1[oo] = fmaf(cr, d1, acc1[oo]);
        }
    }
    float* sp = &spart[((size_t)(chunk * NC + c) * 16) * 128];
#pragma unroll
    for (int oo = 0; oo < 4; oo++) {
        int o = oq * 4 + oo;
        sp[o * 128 + bl] = acc0[oo];
        sp[o * 128 + bl + 64] = acc1[oo];
    }
}

// reduce spart over chunks, squash over o -> v, vT (and d_out[0:20480])
__global__ void k_v(const float* __restrict__ spart, float* __restrict__ v,
                    float* __restrict__ vT, float* __restrict__ out) {
    int idx = blockIdx.x * 256 + threadIdx.x;     // (bc, o), o = low 4 bits
    int o = idx & 15;
    int bc = idx >> 4;
    int c = bc % NC, b = bc / NC;
    float s = 0.f;
    for (int k = 0; k < NCH; k++)
        s += spart[((size_t)(k * NC + c) * 16 + o) * 128 + b];
    float sq = s * s;
#pragma unroll
    for (int d = 1; d < 16; d <<= 1) sq += __shfl_xor(sq, d);
    float sn = sq;
    float vv = s * sn / ((1.f + sn) * sqrtf(sn));
    v[idx] = vv;
    out[idx] = vv;
    vT[(c * 16 + o) * 128 + b] = vv;
}

// a[r,c] = 1/B * sum_{b,o} vT[c,o,b] * sum_i W[r,c,o,i]*xT[r,i,b];  bij += a
// one wave per (r,c): no LDS, no barriers, 23120 independent waves.
__global__ __launch_bounds__(256) void k_a(const float* __restrict__ xT,
                                           const float* __restrict__ W,
                                           const float* __restrict__ vT,
                                           float* __restrict__ bij) {
    int wv = threadIdx.x >> 6, lane = threadIdx.x & 63;
    int wid = __builtin_amdgcn_readfirstlane(blockIdx.x * 4 + wv);
    int r = wid / NC, c = wid - r * NC;
    const float* xr = &xT[(size_t)r * 1024];
    float x0[8], x1[8];
#pragma unroll
    for (int i = 0; i < 8; i++) { x0[i] = xr[i * 128 + lane]; x1[i] = xr[i * 128 + lane + 64]; }
    const float* wr = &W[(size_t)r * 1280 + c * 128];
    const float* vc = &vT[c * 2048];
    float acc = 0.f;
#pragma unroll
    for (int o = 0; o < 16; o++) {
        float w[8];
#pragma unroll
        for (int i = 0; i < 8; i++) w[i] = wr[o * 8 + i];
        float u0 = 0.f, u1 = 0.f;
#pragma unroll
        for (int i = 0; i < 8; i++) { u0 = fmaf(w[i], x0[i], u0); u1 = fmaf(w[i], x1[i], u1); }
        acc = fmaf(vc[o * 128 + lane], u0, acc);
        acc = fmaf(vc[o * 128 + lane + 64], u1, acc);
    }
#pragma unroll
    for (int d = 1; d < 64; d <<= 1) acc += __shfl_xor(acc, d);
    if (lane == 0) bij[wid] += acc * 0.0078125f;
}

// head: h = tanh(v @ w1 + b1); logit = h @ w2 + b2; sigmoid
__global__ void k_head(const float* __restrict__ v, const float* __restrict__ w1,
                       const float* __restrict__ b1, const float* __restrict__ w2,
                       const float* __restrict__ b2, float* __restrict__ out) {
    int b = blockIdx.x / NC, c = blockIdx.x % NC;
    int t = threadIdx.x;
    float p = 0.f;
    if (t < 100) {
        float hs = b1[c * 100 + t];
        const float* vb = &v[(b * NC + c) * 16];
#pragma unroll
        for (int i = 0; i < 16; i++) hs = fmaf(vb[i], w1[(c * 16 + i) * 100 + t], hs);
        p = tanhf(hs) * w2[c * 100 + t];
    }
#pragma unroll
    for (int d = 1; d < 64; d <<= 1) p += __shfl_xor(p, d);
    __shared__ float red[2];
    if ((t & 63) == 0) red[t >> 6] = p;
    __syncthreads();
    if (t == 0) {
        float logit = red[0] + red[1] + b2[c];
        out[20480 + c * 128 + b] = 1.f / (1.f + expf(-logit));
    }
}

extern "C" void kernel_launch(void* const* d_in, const int* in_sizes, int n_in,
                              void* d_out, int out_size, void* d_ws, size_t ws_size,
                              hipStream_t stream) {
    const float* data   = (const float*)d_in[0];
    const float* conv_w = (const float*)d_in[1];
    const float* conv_b = (const float*)d_in[2];
    const float* prim_w = (const float*)d_in[3];
    const float* prim_b = (const float*)d_in[4];
    const float* Wd     = (const float*)d_in[5];
    const float* hw1    = (const float*)d_in[6];
    const float* hb1    = (const float*)d_in[7];
    const float* hw2    = (const float*)d_in[8];
    const float* hb2    = (const float*)d_in[9];
    float* ws = (float*)d_ws;
    unsigned short* xh = (unsigned short*)(ws + OFF_XH);
    float* u0    = ws + OFF_U0;
    float* xT    = ws + OFF_XT;
    float* scale = ws + OFF_SC;
    float* bij   = ws + OFF_BIJ;
    float* spart = ws + OFF_SP;
    float* v     = ws + OFF_V;
    unsigned short* Wb = (unsigned short*)(ws + OFF_WB);
    float* vT    = ws + OFF_VT;
    float* out = (float*)d_out;

    k_zero<<<(23120 + 255) / 256, 256, 0, stream>>>(bij, 23120);
    k_conv1<<<128 * 4, 512, 0, stream>>>(data, conv_w, conv_b, xh);
    k_wprep<<<648, 256, 0, stream>>>(prim_w, Wb);
    k_conv2<<<128 * 5, 256, 0, stream>>>(xh, Wb, prim_b, u0);
    k_sumsq<<<1024, 256, 0, stream>>>(u0, scale);
    k_xt<<<64, 256, 0, stream>>>(u0, scale, xT);
    for (int it = 0; it < 3; it++) {
        k_s<<<NCH * NC, 256, 0, stream>>>(xT, Wd, bij, spart);
        k_v<<<80, 256, 0, stream>>>(spart, v, vT, out);
        if (it < 2) k_a<<<5780, 256, 0, stream>>>(xT, Wd, vT, bij);
    }
    k_head<<<128 * NC, 128, 0, stream>>>(v, hw1, hb1, hw2, hb2, out);
}

// Round 5
// 448.900 us; speedup vs baseline: 2.9628x; 1.2258x over previous
//
#include <hip/hip_runtime.h>
#include <math.h>

#define BATCH 128
#define NR 2312          // 8*17*17 routes
#define RC 68            // route chunk
#define NCH 34           // NR / RC
#define NC 10            // caps
#define OC 16            // out ch
#define IC 8             // in ch

typedef short short8 __attribute__((ext_vector_type(8)));
typedef float f32x4 __attribute__((ext_vector_type(4)));
typedef unsigned long long u64;

// ---- workspace layout (float-slot offsets) ----
#define OFF_XH    0                        // bf16[128][1681][32] = 6885376 bf16 = 3442688 floats
#define OFF_U0    3442688                  // 128*64*289 = 2367488
#define OFF_XT    5810176                  // 2312*8*128 = 2367488
#define OFF_SC    8177664                  // 1024
#define OFF_BIJ   8178688                  // 23120
#define OFF_SP    8201808                  // 34*10*16*128 = 696320
#define OFF_V     8898128                  // 20480
#define OFF_WB    8918608                  // bf16[81][4][16][32] = 165888 bf16 = 82944 floats
#define OFF_VT    9001552                  // 10*16*128 = 20480
// end: 9022032 floats = 36.1 MB

__device__ __forceinline__ unsigned short f2bf(float f) {
    unsigned int u = __float_as_uint(f);
    u = (u + 0x7FFFu + ((u >> 16) & 1u)) >> 16;   // RNE
    return (unsigned short)u;
}

__global__ void k_zero(float* __restrict__ p, int n) {
    int i = blockIdx.x * 256 + threadIdx.x;
    if (i < n) p[i] = 0.f;
}

// conv1 + bias + relu: data(128,3,49,49) -> xh bf16 NHWC [b][h*41+w][ci=32]
__global__ __launch_bounds__(512) void k_conv1(const float* __restrict__ data,
                                               const float* __restrict__ cw,
                                               const float* __restrict__ cb,
                                               unsigned short* __restrict__ xh) {
    int b = blockIdx.x >> 2, cog = blockIdx.x & 3;   // 8 out-ch per block
    __shared__ float in_s[3 * 49 * 52];
    __shared__ float w_s[8 * 243];
    __shared__ float b_s[8];
    for (int k = threadIdx.x; k < 3 * 49 * 49; k += 512) {
        int ci = k / 2401, rem = k % 2401;
        int r = rem / 49, cc = rem % 49;
        in_s[ci * 2548 + r * 52 + cc] = data[(b * 3 + ci) * 2401 + rem];
    }
    for (int k = threadIdx.x; k < 8 * 243; k += 512)
        w_s[k] = cw[cog * 8 * 243 + k];
    if (threadIdx.x < 8) b_s[threadIdx.x] = cb[cog * 8 + threadIdx.x];
    __syncthreads();
    int t = threadIdx.x;
    if (t >= 451) return;                 // 41 h * 11 w-groups
    int h = t / 11, w0 = (t % 11) * 4;
    float acc[8][4];
#pragma unroll
    for (int co = 0; co < 8; co++)
#pragma unroll
        for (int j = 0; j < 4; j++) acc[co][j] = 0.f;
    for (int ci = 0; ci < 3; ci++) {
#pragma unroll 1
        for (int kh = 0; kh < 9; kh++) {
            const float* row = &in_s[ci * 2548 + (h + kh) * 52 + w0];
            float in[12];
#pragma unroll
            for (int j = 0; j < 12; j++) in[j] = row[j];
#pragma unroll
            for (int co = 0; co < 8; co++) {
                const float* wr = &w_s[co * 243 + ci * 81 + kh * 9];
#pragma unroll
                for (int kw = 0; kw < 9; kw++) {
                    float wt = wr[kw];
#pragma unroll
                    for (int j = 0; j < 4; j++) acc[co][j] = fmaf(wt, in[kw + j], acc[co][j]);
                }
            }
        }
    }
#pragma unroll
    for (int j = 0; j < 4; j++) {
        int w = w0 + j;
        if (w < 41) {
            unsigned short pk[8];
#pragma unroll
            for (int co = 0; co < 8; co++) {
                float val = acc[co][j] + b_s[co];
                pk[co] = f2bf(val > 0.f ? val : 0.f);
            }
            *(int4*)&xh[((size_t)(b * 1681 + h * 41 + w)) * 32 + cog * 8] = *(int4*)pk;
        }
    }
}

// prim_w (64,32,9,9) fp32 -> Wb[tap=kh*9+kw][cog=4][co=16][ci=32] bf16
__global__ void k_wprep(const float* __restrict__ pw, unsigned short* __restrict__ Wb) {
    int idx = blockIdx.x * 256 + threadIdx.x;   // 81*2048 = 165888
    if (idx >= 165888) return;
    int ci = idx & 31, co = (idx >> 5) & 15, cog = (idx >> 9) & 3, tap = idx >> 11;
    Wb[idx] = f2bf(pw[((cog * 16 + co) * 32 + ci) * 81 + tap]);
}

// conv2 implicit-GEMM MFMA, LDS-staged input.
// block = (b, g of 64 positions); 8 waves = {half of 32 pos} x {co-group of 16}.
// LDS A-tile: [row][col][32ci + 4 pad] shorts (col stride 36 -> 2-way banks, 8B aligned)
__global__ __launch_bounds__(512) void k_conv2(const unsigned short* __restrict__ xh,
                                               const unsigned short* __restrict__ Wb,
                                               const float* __restrict__ pb,
                                               float* __restrict__ u0) {
    int b = blockIdx.x / 5, g = blockIdx.x % 5;
    int t = threadIdx.x, lane = t & 63, wv = t >> 6;
    int quad = lane >> 4, mloc = lane & 15;
    int cg = wv & 3, half = wv >> 2;
    __shared__ __align__(16) char lds[50184];     // max(17*41*36*2, 64*65*4)
    unsigned short* As = (unsigned short*)lds;
    const unsigned short* xb = xh + (size_t)b * 53792;   // 1681*32
    int p_hi = g * 64 + 63; if (p_hi > 288) p_hi = 288;
    int r0 = 2 * ((g * 64) / 17);
    int nrows = 2 * (p_hi / 17) + 9 - r0;         // <= 17
    // stage input strip: rows r0..r0+nrows-1, 41 cols x 32 shorts
    int nch = nrows * 164;                        // 8-short chunks: 41*4 per row
    for (int k = t; k < nch; k += 512) {
        int rl = k / 164, rem = k - rl * 164;
        int col = rem >> 2, ci8 = rem & 3;
        const u64* src = (const u64*)&xb[((r0 + rl) * 41 + col) * 32 + ci8 * 8];
        u64* dst = (u64*)&As[(rl * 41 + col) * 36 + ci8 * 8];
        dst[0] = src[0];
        dst[1] = src[1];
    }
    __syncthreads();
    int abase0, abase1;
    {
        int p = g * 64 + half * 32 + mloc;        // mt=0
        if (p > 288) p = 288;
        abase0 = ((2 * (p / 17) - r0) * 41 + 2 * (p % 17)) * 36 + quad * 8;
        p = g * 64 + half * 32 + 16 + mloc;       // mt=1
        if (p > 288) p = 288;
        abase1 = ((2 * (p / 17) - r0) * 41 + 2 * (p % 17)) * 36 + quad * 8;
    }
    const unsigned short* wbase = Wb + ((size_t)cg * 16 + mloc) * 32 + quad * 8;
    f32x4 acc0 = {0.f, 0.f, 0.f, 0.f}, acc1 = {0.f, 0.f, 0.f, 0.f};
#pragma unroll 1
    for (int kh = 0; kh < 9; kh++) {
        int rowoff = kh * (41 * 36);
        const unsigned short* wrow = wbase + (size_t)kh * 9 * 2048;
#pragma unroll
        for (int kw = 0; kw < 9; kw++) {
            short8 bf = *(const short8*)(wrow + (size_t)kw * 2048);
            int off = rowoff + kw * 36;
            union { short8 v; u64 q[2]; } a0, a1;
            a0.q[0] = *(const u64*)&As[abase0 + off];
            a0.q[1] = *(const u64*)&As[abase0 + off + 4];
            a1.q[0] = *(const u64*)&As[abase1 + off];
            a1.q[1] = *(const u64*)&As[abase1 + off + 4];
            acc0 = __builtin_amdgcn_mfma_f32_16x16x32_bf16(a0.v, bf, acc0, 0, 0, 0);
            acc1 = __builtin_amdgcn_mfma_f32_16x16x32_bf16(a1.v, bf, acc1, 0, 0, 0);
        }
    }
    __syncthreads();                              // done reading A-tile
    float* tile = (float*)lds;                    // 64 co x 65
#pragma unroll
    for (int r = 0; r < 4; r++) {
        tile[(cg * 16 + mloc) * 65 + half * 32 + quad * 4 + r] = acc0[r];
        tile[(cg * 16 + mloc) * 65 + half * 32 + 16 + quad * 4 + r] = acc1[r];
    }
    __syncthreads();
    int co = t >> 3, p0 = (t & 7) * 8;
    float bias = pb[co];
#pragma unroll
    for (int j = 0; j < 8; j++) {
        int p = g * 64 + p0 + j;
        if (p < 289)
            u0[((size_t)(b * 64 + co)) * 289 + p] = tile[co * 65 + p0 + j] + bias;
    }
}

// per-(b,i) squash scale over 2312 routes (contiguous: channels i*8..i*8+7)
__global__ void k_sumsq(const float* __restrict__ u0, float* __restrict__ scale) {
    int bi = blockIdx.x;                     // b*8 + i
    const float* base = &u0[bi * 8 * 289];
    float sum = 0.f;
    for (int k = threadIdx.x; k < 2312; k += 256) { float v = base[k]; sum += v * v; }
#pragma unroll
    for (int d = 32; d; d >>= 1) sum += __shfl_xor(sum, d);
    __shared__ float red[4];
    if ((threadIdx.x & 63) == 0) red[threadIdx.x >> 6] = sum;
    __syncthreads();
    if (threadIdx.x == 0) {
        float sn = red[0] + red[1] + red[2] + red[3];
        scale[bi] = sn / ((1.f + sn) * sqrtf(sn));
    }
}

// build xT[r][i][b] = u0[b][i*8+j][hw] * scale[b,i]  (r = j*289+hw)
__global__ __launch_bounds__(256) void k_xt(const float* __restrict__ u0,
                                            const float* __restrict__ scale,
                                            float* __restrict__ xT) {
    int i = blockIdx.x >> 3, j = blockIdx.x & 7;
    int ch = i * 8 + j;
    __shared__ float tile[32 * 130];
    int t = threadIdx.x;
#pragma unroll 1
    for (int hw0 = 0; hw0 < 289; hw0 += 32) {
        int rem = 289 - hw0; if (rem > 32) rem = 32;
        __syncthreads();
        for (int k = t; k < 32 * 128; k += 256) {
            int bb = k >> 5, x = k & 31;
            if (x < rem)
                tile[x * 130 + bb] = u0[(bb * 64 + ch) * 289 + hw0 + x];
        }
        __syncthreads();
        for (int k = t; k < 32 * 128; k += 256) {
            int hwl = k >> 7, bb = k & 127;
            if (hwl < rem)
                xT[((size_t)((j * 289 + hw0 + hwl) * 8 + i)) * 128 + bb] =
                    tile[hwl * 130 + bb] * scale[bb * 8 + i];
        }
    }
}

// s partials (softmax fused): block = (chunk,c,ohalf) -> spart[chunk][c][ohalf*8..+8][b]
__global__ __launch_bounds__(256) void k_s(const float* __restrict__ xT,
                                           const float* __restrict__ W,
                                           const float* __restrict__ bij,
                                           float* __restrict__ spart) {
    int bid = blockIdx.x;
    int oh = bid & 1;
    int cc = bid >> 1;
    int chunk = cc / NC, c = cc % NC;
    int r0 = chunk * RC;
    __shared__ float Wc[RC * 64];        // 17.4 KB: o-half columns
    __shared__ float cs[RC];
    for (int k = threadIdx.x; k < RC * 64; k += 256) {
        int rr = k >> 6, kk = k & 63;
        Wc[k] = W[(size_t)(r0 + rr) * 1280 + c * 128 + oh * 64 + kk];
    }
    if (threadIdx.x < RC) {
        int r = r0 + threadIdx.x;
        float x[NC], m = -1e30f;
#pragma unroll
        for (int k = 0; k < NC; k++) { x[k] = bij[r * NC + k]; m = fmaxf(m, x[k]); }
        float s = 0.f;
#pragma unroll
        for (int k = 0; k < NC; k++) { x[k] = expf(x[k] - m); s += x[k]; }
        cs[threadIdx.x] = x[c] / s;
    }
    __syncthreads();
    int bl = threadIdx.x & 63;
    int oq = threadIdx.x >> 6;       // wave-uniform: pair of o's
    float acc0[2] = {0.f, 0.f};
    float acc1[2] = {0.f, 0.f};
    for (int rr = 0; rr < RC; rr++) {
        const float* xrow = &xT[(size_t)(r0 + rr) * 8 * 128];
        float xa[8], xb[8];
#pragma unroll
        for (int i = 0; i < 8; i++) { xa[i] = xrow[i * 128 + bl]; xb[i] = xrow[i * 128 + bl + 64]; }
        float cr = cs[rr];
        const float* wrow = &Wc[rr * 64 + oq * 16];
#pragma unroll
        for (int oo = 0; oo < 2; oo++) {
            float4 wA = *(const float4*)&wrow[oo * 8];
            float4 wB = *(const float4*)&wrow[oo * 8 + 4];
            float d0 = wA.x * xa[0] + wA.y * xa[1] + wA.z * xa[2] + wA.w * xa[3]
                     + wB.x * xa[4] + wB.y * xa[5] + wB.z * xa[6] + wB.w * xa[7];
            float d1 = wA.x * xb[0] + wA.y * xb[1] + wA.z * xb[2] + wA.w * xb[3]
                     + wB.x * xb[4] + wB.y * xb[5] + wB.z * xb[6] + wB.w * xb[7];
            acc0[oo] = fmaf(cr, d0, acc0[oo]);
            acc1[oo] = fmaf(cr, d1, acc1[oo]);
        }
    }
    float* sp = &spart[((size_t)(chunk * NC + c) * 16) * 128];
#pragma unroll
    for (int oo = 0; oo < 2; oo++) {
        int o = oh * 8 + oq * 2 + oo;
        sp[o * 128 + bl] = acc0[oo];
        sp[o * 128 + bl + 64] = acc1[oo];
    }
}

// reduce spart over chunks, squash over o -> v, vT (and d_out[0:20480])
__global__ void k_v(const float* __restrict__ spart, float* __restrict__ v,
                    float* __restrict__ vT, float* __restrict__ out) {
    int idx = blockIdx.x * 256 + threadIdx.x;     // (bc, o), o = low 4 bits
    int o = idx & 15;
    int bc = idx >> 4;
    int c = bc % NC, b = bc / NC;
    float s = 0.f;
    for (int k = 0; k < NCH; k++)
        s += spart[((size_t)(k * NC + c) * 16 + o) * 128 + b];
    float sq = s * s;
#pragma unroll
    for (int d = 1; d < 16; d <<= 1) sq += __shfl_xor(sq, d);
    float sn = sq;
    float vv = s * sn / ((1.f + sn) * sqrtf(sn));
    v[idx] = vv;
    out[idx] = vv;
    vT[(c * 16 + o) * 128 + b] = vv;
}

// a[r,c] = 1/B * sum_{b,o} vT[c,o,b] * sum_i W[r,c,o,i]*xT[r,i,b];  bij += a
// one wave per (r,c): no LDS, no barriers.
__global__ __launch_bounds__(256) void k_a(const float* __restrict__ xT,
                                           const float* __restrict__ W,
                                           const float* __restrict__ vT,
                                           float* __restrict__ bij) {
    int wv = threadIdx.x >> 6, lane = threadIdx.x & 63;
    int wid = __builtin_amdgcn_readfirstlane(blockIdx.x * 4 + wv);
    int r = wid / NC, c = wid - r * NC;
    const float* xr = &xT[(size_t)r * 1024];
    float x0[8], x1[8];
#pragma unroll
    for (int i = 0; i < 8; i++) { x0[i] = xr[i * 128 + lane]; x1[i] = xr[i * 128 + lane + 64]; }
    const float* wr = &W[(size_t)r * 1280 + c * 128];
    const float* vc = &vT[c * 2048];
    float acc = 0.f;
#pragma unroll
    for (int o = 0; o < 16; o++) {
        float w[8];
#pragma unroll
        for (int i = 0; i < 8; i++) w[i] = wr[o * 8 + i];
        float u0 = 0.f, u1 = 0.f;
#pragma unroll
        for (int i = 0; i < 8; i++) { u0 = fmaf(w[i], x0[i], u0); u1 = fmaf(w[i], x1[i], u1); }
        acc = fmaf(vc[o * 128 + lane], u0, acc);
        acc = fmaf(vc[o * 128 + lane + 64], u1, acc);
    }
#pragma unroll
    for (int d = 1; d < 64; d <<= 1) acc += __shfl_xor(acc, d);
    if (lane == 0) bij[wid] += acc * 0.0078125f;
}

// head: h = tanh(v @ w1 + b1); logit = h @ w2 + b2; sigmoid
__global__ void k_head(const float* __restrict__ v, const float* __restrict__ w1,
                       const float* __restrict__ b1, const float* __restrict__ w2,
                       const float* __restrict__ b2, float* __restrict__ out) {
    int b = blockIdx.x / NC, c = blockIdx.x % NC;
    int t = threadIdx.x;
    float p = 0.f;
    if (t < 100) {
        float hs = b1[c * 100 + t];
        const float* vb = &v[(b * NC + c) * 16];
#pragma unroll
        for (int i = 0; i < 16; i++) hs = fmaf(vb[i], w1[(c * 16 + i) * 100 + t], hs);
        p = tanhf(hs) * w2[c * 100 + t];
    }
#pragma unroll
    for (int d = 1; d < 64; d <<= 1) p += __shfl_xor(p, d);
    __shared__ float red[2];
    if ((t & 63) == 0) red[t >> 6] = p;
    __syncthreads();
    if (t == 0) {
        float logit = red[0] + red[1] + b2[c];
        out[20480 + c * 128 + b] = 1.f / (1.f + expf(-logit));
    }
}

extern "C" void kernel_launch(void* const* d_in, const int* in_sizes, int n_in,
                              void* d_out, int out_size, void* d_ws, size_t ws_size,
                              hipStream_t stream) {
    const float* data   = (const float*)d_in[0];
    const float* conv_w = (const float*)d_in[1];
    const float* conv_b = (const float*)d_in[2];
    const float* prim_w = (const float*)d_in[3];
    const float* prim_b = (const float*)d_in[4];
    const float* Wd     = (const float*)d_in[5];
    const float* hw1    = (const float*)d_in[6];
    const float* hb1    = (const float*)d_in[7];
    const float* hw2    = (const float*)d_in[8];
    const float* hb2    = (const float*)d_in[9];
    float* ws = (float*)d_ws;
    unsigned short* xh = (unsigned short*)(ws + OFF_XH);
    float* u0    = ws + OFF_U0;
    float* xT    = ws + OFF_XT;
    float* scale = ws + OFF_SC;
    float* bij   = ws + OFF_BIJ;
    float* spart = ws + OFF_SP;
    float* v     = ws + OFF_V;
    unsigned short* Wb = (unsigned short*)(ws + OFF_WB);
    float* vT    = ws + OFF_VT;
    float* out = (float*)d_out;

    k_zero<<<(23120 + 255) / 256, 256, 0, stream>>>(bij, 23120);
    k_conv1<<<128 * 4, 512, 0, stream>>>(data, conv_w, conv_b, xh);
    k_wprep<<<648, 256, 0, stream>>>(prim_w, Wb);
    k_conv2<<<128 * 5, 512, 0, stream>>>(xh, Wb, prim_b, u0);
    k_sumsq<<<1024, 256, 0, stream>>>(u0, scale);
    k_xt<<<64, 256, 0, stream>>>(u0, scale, xT);
    for (int it = 0; it < 3; it++) {
        k_s<<<NCH * NC * 2, 256, 0, stream>>>(xT, Wd, bij, spart);
        k_v<<<80, 256, 0, stream>>>(spart, v, vT, out);
        if (it < 2) k_a<<<5780, 256, 0, stream>>>(xT, Wd, vT, bij);
    }
    k_head<<<128 * NC, 128, 0, stream>>>(v, hw1, hb1, hw2, hb2, out);
}

// Round 6
// 379.447 us; speedup vs baseline: 3.5050x; 1.1830x over previous
//
#include <hip/hip_runtime.h>
#include <math.h>

#define BATCH 128
#define NR 2312          // 8*17*17 routes
#define RC 68            // route chunk
#define NCH 34           // NR / RC
#define NC 10            // caps
#define OC 16            // out ch
#define IC 8             // in ch

typedef short short8 __attribute__((ext_vector_type(8)));
typedef float f32x4 __attribute__((ext_vector_type(4)));
typedef unsigned long long u64;

// ---- workspace layout (float-slot offsets) ----
#define OFF_XH    0                        // bf16[128][1681][32] = 6885376 bf16 = 3442688 floats
#define OFF_U0    3442688                  // 128*64*289 = 2367488
#define OFF_XT    5810176                  // 2312*8*128 = 2367488
#define OFF_SC    8177664                  // 1024
#define OFF_BIJ   8178688                  // 23120
#define OFF_SP    8201808                  // 34*10*16*128 = 696320
#define OFF_V     8898128                  // 20480
#define OFF_WB    8918608                  // bf16[81][4][16][32] = 165888 bf16 = 82944 floats
#define OFF_VT    9001552                  // 10*16*128 = 20480
// end: 9022032 floats = 36.1 MB

__device__ __forceinline__ unsigned short f2bf(float f) {
    unsigned int u = __float_as_uint(f);
    u = (u + 0x7FFFu + ((u >> 16) & 1u)) >> 16;   // RNE
    return (unsigned short)u;
}

__global__ void k_zero(float* __restrict__ p, int n) {
    int i = blockIdx.x * 256 + threadIdx.x;
    if (i < n) p[i] = 0.f;
}

// conv1 + bias + relu: data(128,3,49,49) -> xh bf16 NHWC [b][h*41+w][ci=32]
__global__ __launch_bounds__(512) void k_conv1(const float* __restrict__ data,
                                               const float* __restrict__ cw,
                                               const float* __restrict__ cb,
                                               unsigned short* __restrict__ xh) {
    int b = blockIdx.x >> 2, cog = blockIdx.x & 3;   // 8 out-ch per block
    __shared__ float in_s[3 * 49 * 52];
    __shared__ float w_s[8 * 243];
    __shared__ float b_s[8];
    for (int k = threadIdx.x; k < 3 * 49 * 49; k += 512) {
        int ci = k / 2401, rem = k % 2401;
        int r = rem / 49, cc = rem % 49;
        in_s[ci * 2548 + r * 52 + cc] = data[(b * 3 + ci) * 2401 + rem];
    }
    for (int k = threadIdx.x; k < 8 * 243; k += 512)
        w_s[k] = cw[cog * 8 * 243 + k];
    if (threadIdx.x < 8) b_s[threadIdx.x] = cb[cog * 8 + threadIdx.x];
    __syncthreads();
    int t = threadIdx.x;
    if (t >= 451) return;                 // 41 h * 11 w-groups
    int h = t / 11, w0 = (t % 11) * 4;
    float acc[8][4];
#pragma unroll
    for (int co = 0; co < 8; co++)
#pragma unroll
        for (int j = 0; j < 4; j++) acc[co][j] = 0.f;
    for (int ci = 0; ci < 3; ci++) {
#pragma unroll 1
        for (int kh = 0; kh < 9; kh++) {
            const float* row = &in_s[ci * 2548 + (h + kh) * 52 + w0];
            float in[12];
#pragma unroll
            for (int j = 0; j < 12; j++) in[j] = row[j];
#pragma unroll
            for (int co = 0; co < 8; co++) {
                const float* wr = &w_s[co * 243 + ci * 81 + kh * 9];
#pragma unroll
                for (int kw = 0; kw < 9; kw++) {
                    float wt = wr[kw];
#pragma unroll
                    for (int j = 0; j < 4; j++) acc[co][j] = fmaf(wt, in[kw + j], acc[co][j]);
                }
            }
        }
    }
#pragma unroll
    for (int j = 0; j < 4; j++) {
        int w = w0 + j;
        if (w < 41) {
            unsigned short pk[8];
#pragma unroll
            for (int co = 0; co < 8; co++) {
                float val = acc[co][j] + b_s[co];
                pk[co] = f2bf(val > 0.f ? val : 0.f);
            }
            *(int4*)&xh[((size_t)(b * 1681 + h * 41 + w)) * 32 + cog * 8] = *(int4*)pk;
        }
    }
}

// prim_w (64,32,9,9) fp32 -> Wb[tap=kh*9+kw][cog=4][co=16][ci=32] bf16
__global__ void k_wprep(const float* __restrict__ pw, unsigned short* __restrict__ Wb) {
    int idx = blockIdx.x * 256 + threadIdx.x;   // 81*2048 = 165888
    if (idx >= 165888) return;
    int ci = idx & 31, co = (idx >> 5) & 15, cog = (idx >> 9) & 3, tap = idx >> 11;
    Wb[idx] = f2bf(pw[((cog * 16 + co) * 32 + ci) * 81 + tap]);
}

// conv2 implicit-GEMM MFMA, LDS-staged input.
__global__ __launch_bounds__(512) void k_conv2(const unsigned short* __restrict__ xh,
                                               const unsigned short* __restrict__ Wb,
                                               const float* __restrict__ pb,
                                               float* __restrict__ u0) {
    int b = blockIdx.x / 5, g = blockIdx.x % 5;
    int t = threadIdx.x, lane = t & 63, wv = t >> 6;
    int quad = lane >> 4, mloc = lane & 15;
    int cg = wv & 3, half = wv >> 2;
    __shared__ __align__(16) char lds[50184];     // max(17*41*36*2, 64*65*4)
    unsigned short* As = (unsigned short*)lds;
    const unsigned short* xb = xh + (size_t)b * 53792;   // 1681*32
    int p_hi = g * 64 + 63; if (p_hi > 288) p_hi = 288;
    int r0 = 2 * ((g * 64) / 17);
    int nrows = 2 * (p_hi / 17) + 9 - r0;         // <= 17
    int nch = nrows * 164;                        // 8-short chunks: 41*4 per row
    for (int k = t; k < nch; k += 512) {
        int rl = k / 164, rem = k - rl * 164;
        int col = rem >> 2, ci8 = rem & 3;
        const u64* src = (const u64*)&xb[((r0 + rl) * 41 + col) * 32 + ci8 * 8];
        u64* dst = (u64*)&As[(rl * 41 + col) * 36 + ci8 * 8];
        dst[0] = src[0];
        dst[1] = src[1];
    }
    __syncthreads();
    int abase0, abase1;
    {
        int p = g * 64 + half * 32 + mloc;        // mt=0
        if (p > 288) p = 288;
        abase0 = ((2 * (p / 17) - r0) * 41 + 2 * (p % 17)) * 36 + quad * 8;
        p = g * 64 + half * 32 + 16 + mloc;       // mt=1
        if (p > 288) p = 288;
        abase1 = ((2 * (p / 17) - r0) * 41 + 2 * (p % 17)) * 36 + quad * 8;
    }
    const unsigned short* wbase = Wb + ((size_t)cg * 16 + mloc) * 32 + quad * 8;
    f32x4 acc0 = {0.f, 0.f, 0.f, 0.f}, acc1 = {0.f, 0.f, 0.f, 0.f};
#pragma unroll 1
    for (int kh = 0; kh < 9; kh++) {
        int rowoff = kh * (41 * 36);
        const unsigned short* wrow = wbase + (size_t)kh * 9 * 2048;
#pragma unroll
        for (int kw = 0; kw < 9; kw++) {
            short8 bf = *(const short8*)(wrow + (size_t)kw * 2048);
            int off = rowoff + kw * 36;
            union { short8 v; u64 q[2]; } a0, a1;
            a0.q[0] = *(const u64*)&As[abase0 + off];
            a0.q[1] = *(const u64*)&As[abase0 + off + 4];
            a1.q[0] = *(const u64*)&As[abase1 + off];
            a1.q[1] = *(const u64*)&As[abase1 + off + 4];
            acc0 = __builtin_amdgcn_mfma_f32_16x16x32_bf16(a0.v, bf, acc0, 0, 0, 0);
            acc1 = __builtin_amdgcn_mfma_f32_16x16x32_bf16(a1.v, bf, acc1, 0, 0, 0);
        }
    }
    __syncthreads();                              // done reading A-tile
    float* tile = (float*)lds;                    // 64 co x 65
#pragma unroll
    for (int r = 0; r < 4; r++) {
        tile[(cg * 16 + mloc) * 65 + half * 32 + quad * 4 + r] = acc0[r];
        tile[(cg * 16 + mloc) * 65 + half * 32 + 16 + quad * 4 + r] = acc1[r];
    }
    __syncthreads();
    int co = t >> 3, p0 = (t & 7) * 8;
    float bias = pb[co];
#pragma unroll
    for (int j = 0; j < 8; j++) {
        int p = g * 64 + p0 + j;
        if (p < 289)
            u0[((size_t)(b * 64 + co)) * 289 + p] = tile[co * 65 + p0 + j] + bias;
    }
}

// per-(b,i) squash scale over 2312 routes (contiguous: channels i*8..i*8+7)
__global__ void k_sumsq(const float* __restrict__ u0, float* __restrict__ scale) {
    int bi = blockIdx.x;                     // b*8 + i
    const float* base = &u0[bi * 8 * 289];
    float sum = 0.f;
    for (int k = threadIdx.x; k < 2312; k += 256) { float v = base[k]; sum += v * v; }
#pragma unroll
    for (int d = 32; d; d >>= 1) sum += __shfl_xor(sum, d);
    __shared__ float red[4];
    if ((threadIdx.x & 63) == 0) red[threadIdx.x >> 6] = sum;
    __syncthreads();
    if (threadIdx.x == 0) {
        float sn = red[0] + red[1] + red[2] + red[3];
        scale[bi] = sn / ((1.f + sn) * sqrtf(sn));
    }
}

// build xT[r][i][b] = u0[b][i*8+j][hw] * scale[b,i]  (r = j*289+hw)
// block = (i, j, hw-tile of 32); grid 640 — one tile per block, no serial loop.
__global__ __launch_bounds__(256) void k_xt(const float* __restrict__ u0,
                                            const float* __restrict__ scale,
                                            float* __restrict__ xT) {
    int tid = blockIdx.x;
    int tile_i = tid / 10, hwt = tid % 10;
    int i = tile_i >> 3, j = tile_i & 7;
    int ch = i * 8 + j;
    int hw0 = hwt * 32;
    int rem = 289 - hw0; if (rem > 32) rem = 32;
    __shared__ float tile[32 * 130];
    int t = threadIdx.x;
    for (int k = t; k < 32 * 128; k += 256) {
        int bb = k >> 5, x = k & 31;
        if (x < rem)
            tile[x * 130 + bb] = u0[(bb * 64 + ch) * 289 + hw0 + x];
    }
    __syncthreads();
    for (int k = t; k < 32 * 128; k += 256) {
        int hwl = k >> 7, bb = k & 127;
        if (hwl < rem)
            xT[((size_t)((j * 289 + hw0 + hwl) * 8 + i)) * 128 + bb] =
                tile[hwl * 130 + bb] * scale[bb * 8 + i];
    }
}

// s partials (softmax fused): block = (chunk,c,ohalf) -> spart[chunk][c][ohalf*8..+8][b]
__global__ __launch_bounds__(256) void k_s(const float* __restrict__ xT,
                                           const float* __restrict__ W,
                                           const float* __restrict__ bij,
                                           float* __restrict__ spart) {
    int bid = blockIdx.x;
    int oh = bid & 1;
    int cc = bid >> 1;
    int chunk = cc / NC, c = cc % NC;
    int r0 = chunk * RC;
    __shared__ float Wc[RC * 64];        // 17.4 KB: o-half columns
    __shared__ float cs[RC];
    for (int k = threadIdx.x; k < RC * 64; k += 256) {
        int rr = k >> 6, kk = k & 63;
        Wc[k] = W[(size_t)(r0 + rr) * 1280 + c * 128 + oh * 64 + kk];
    }
    if (threadIdx.x < RC) {
        int r = r0 + threadIdx.x;
        float x[NC], m = -1e30f;
#pragma unroll
        for (int k = 0; k < NC; k++) { x[k] = bij[r * NC + k]; m = fmaxf(m, x[k]); }
        float s = 0.f;
#pragma unroll
        for (int k = 0; k < NC; k++) { x[k] = expf(x[k] - m); s += x[k]; }
        cs[threadIdx.x] = x[c] / s;
    }
    __syncthreads();
    int bl = threadIdx.x & 63;
    int oq = threadIdx.x >> 6;       // wave-uniform: pair of o's
    float acc0[2] = {0.f, 0.f};
    float acc1[2] = {0.f, 0.f};
    for (int rr = 0; rr < RC; rr++) {
        const float* xrow = &xT[(size_t)(r0 + rr) * 8 * 128];
        float xa[8], xb[8];
#pragma unroll
        for (int i = 0; i < 8; i++) { xa[i] = xrow[i * 128 + bl]; xb[i] = xrow[i * 128 + bl + 64]; }
        float cr = cs[rr];
        const float* wrow = &Wc[rr * 64 + oq * 16];
#pragma unroll
        for (int oo = 0; oo < 2; oo++) {
            float4 wA = *(const float4*)&wrow[oo * 8];
            float4 wB = *(const float4*)&wrow[oo * 8 + 4];
            float d0 = wA.x * xa[0] + wA.y * xa[1] + wA.z * xa[2] + wA.w * xa[3]
                     + wB.x * xa[4] + wB.y * xa[5] + wB.z * xa[6] + wB.w * xa[7];
            float d1 = wA.x * xb[0] + wA.y * xb[1] + wA.z * xb[2] + wA.w * xb[3]
                     + wB.x * xb[4] + wB.y * xb[5] + wB.z * xb[6] + wB.w * xb[7];
            acc0[oo] = fmaf(cr, d0, acc0[oo]);
            acc1[oo] = fmaf(cr, d1, acc1[oo]);
        }
    }
    float* sp = &spart[((size_t)(chunk * NC + c) * 16) * 128];
#pragma unroll
    for (int oo = 0; oo < 2; oo++) {
        int o = oh * 8 + oq * 2 + oo;
        sp[o * 128 + bl] = acc0[oo];
        sp[o * 128 + bl + 64] = acc1[oo];
    }
}

// reduce spart over chunks, squash over o -> v, vT (and d_out[0:20480])
__global__ void k_v(const float* __restrict__ spart, float* __restrict__ v,
                    float* __restrict__ vT, float* __restrict__ out) {
    int idx = blockIdx.x * 256 + threadIdx.x;     // (bc, o), o = low 4 bits
    int o = idx & 15;
    int bc = idx >> 4;
    int c = bc % NC, b = bc / NC;
    float s = 0.f;
    for (int k = 0; k < NCH; k++)
        s += spart[((size_t)(k * NC + c) * 16 + o) * 128 + b];
    float sq = s * s;
#pragma unroll
    for (int d = 1; d < 16; d <<= 1) sq += __shfl_xor(sq, d);
    float sn = sq;
    float vv = s * sn / ((1.f + sn) * sqrtf(sn));
    v[idx] = vv;
    out[idx] = vv;
    vT[(c * 16 + o) * 128 + b] = vv;
}

// a[r,c] = 1/B * sum_{b,o} vT[c,o,b] * sum_i W[r,c,o,i]*xT[r,i,b];  bij += a
// one wave per (r,c): no LDS, no barriers.
__global__ __launch_bounds__(256) void k_a(const float* __restrict__ xT,
                                           const float* __restrict__ W,
                                           const float* __restrict__ vT,
                                           float* __restrict__ bij) {
    int wv = threadIdx.x >> 6, lane = threadIdx.x & 63;
    int wid = __builtin_amdgcn_readfirstlane(blockIdx.x * 4 + wv);
    int r = wid / NC, c = wid - r * NC;
    const float* xr = &xT[(size_t)r * 1024];
    float x0[8], x1[8];
#pragma unroll
    for (int i = 0; i < 8; i++) { x0[i] = xr[i * 128 + lane]; x1[i] = xr[i * 128 + lane + 64]; }
    const float* wr = &W[(size_t)r * 1280 + c * 128];
    const float* vc = &vT[c * 2048];
    float acc = 0.f;
#pragma unroll
    for (int o = 0; o < 16; o++) {
        float w[8];
#pragma unroll
        for (int i = 0; i < 8; i++) w[i] = wr[o * 8 + i];
        float u0 = 0.f, u1 = 0.f;
#pragma unroll
        for (int i = 0; i < 8; i++) { u0 = fmaf(w[i], x0[i], u0); u1 = fmaf(w[i], x1[i], u1); }
        acc = fmaf(vc[o * 128 + lane], u0, acc);
        acc = fmaf(vc[o * 128 + lane + 64], u1, acc);
    }
#pragma unroll
    for (int d = 1; d < 64; d <<= 1) acc += __shfl_xor(acc, d);
    if (lane == 0) bij[wid] += acc * 0.0078125f;
}

// head: h = tanh(v @ w1 + b1); logit = h @ w2 + b2; sigmoid
__global__ void k_head(const float* __restrict__ v, const float* __restrict__ w1,
                       const float* __restrict__ b1, const float* __restrict__ w2,
                       const float* __restrict__ b2, float* __restrict__ out) {
    int b = blockIdx.x / NC, c = blockIdx.x % NC;
    int t = threadIdx.x;
    float p = 0.f;
    if (t < 100) {
        float hs = b1[c * 100 + t];
        const float* vb = &v[(b * NC + c) * 16];
#pragma unroll
        for (int i = 0; i < 16; i++) hs = fmaf(vb[i], w1[(c * 16 + i) * 100 + t], hs);
        p = tanhf(hs) * w2[c * 100 + t];
    }
#pragma unroll
    for (int d = 1; d < 64; d <<= 1) p += __shfl_xor(p, d);
    __shared__ float red[2];
    if ((t & 63) == 0) red[t >> 6] = p;
    __syncthreads();
    if (t == 0) {
        float logit = red[0] + red[1] + b2[c];
        out[20480 + c * 128 + b] = 1.f / (1.f + expf(-logit));
    }
}

extern "C" void kernel_launch(void* const* d_in, const int* in_sizes, int n_in,
                              void* d_out, int out_size, void* d_ws, size_t ws_size,
                              hipStream_t stream) {
    const float* data   = (const float*)d_in[0];
    const float* conv_w = (const float*)d_in[1];
    const float* conv_b = (const float*)d_in[2];
    const float* prim_w = (const float*)d_in[3];
    const float* prim_b = (const float*)d_in[4];
    const float* Wd     = (const float*)d_in[5];
    const float* hw1    = (const float*)d_in[6];
    const float* hb1    = (const float*)d_in[7];
    const float* hw2    = (const float*)d_in[8];
    const float* hb2    = (const float*)d_in[9];
    float* ws = (float*)d_ws;
    unsigned short* xh = (unsigned short*)(ws + OFF_XH);
    float* u0    = ws + OFF_U0;
    float* xT    = ws + OFF_XT;
    float* scale = ws + OFF_SC;
    float* bij   = ws + OFF_BIJ;
    float* spart = ws + OFF_SP;
    float* v     = ws + OFF_V;
    unsigned short* Wb = (unsigned short*)(ws + OFF_WB);
    float* vT    = ws + OFF_VT;
    float* out = (float*)d_out;

    k_zero<<<(23120 + 255) / 256, 256, 0, stream>>>(bij, 23120);
    k_conv1<<<128 * 4, 512, 0, stream>>>(data, conv_w, conv_b, xh);
    k_wprep<<<648, 256, 0, stream>>>(prim_w, Wb);
    k_conv2<<<128 * 5, 512, 0, stream>>>(xh, Wb, prim_b, u0);
    k_sumsq<<<1024, 256, 0, stream>>>(u0, scale);
    k_xt<<<640, 256, 0, stream>>>(u0, scale, xT);
    for (int it = 0; it < 3; it++) {
        k_s<<<NCH * NC * 2, 256, 0, stream>>>(xT, Wd, bij, spart);
        k_v<<<80, 256, 0, stream>>>(spart, v, vT, out);
        if (it < 2) k_a<<<5780, 256, 0, stream>>>(xT, Wd, vT, bij);
    }
    k_head<<<128 * NC, 128, 0, stream>>>(v, hw1, hb1, hw2, hb2, out);
}

// Round 7
// 364.225 us; speedup vs baseline: 3.6515x; 1.0418x over previous
//
#include <hip/hip_runtime.h>
#include <math.h>

#define BATCH 128
#define NR 2312          // 8*17*17 routes
#define RC 68            // route chunk
#define NCH 34           // NR / RC
#define NC 10            // caps
#define OC 16            // out ch
#define IC 8             // in ch
#define K1 352           // conv1 padded K: (ci*9+kh)*12 + kw

typedef short short8 __attribute__((ext_vector_type(8)));
typedef float f32x4 __attribute__((ext_vector_type(4)));
typedef unsigned long long u64;

// ---- workspace layout (float-slot offsets) ----
#define OFF_XH    0                        // bf16[128][1681][32] = 3442688 floats
#define OFF_U0    3442688                  // 128*64*289 = 2367488
#define OFF_XT    5810176                  // 2312*8*128 = 2367488
#define OFF_SC    8177664                  // 1024
#define OFF_BIJ   8178688                  // 23120
#define OFF_SP    8201808                  // 34*10*16*128 = 696320
#define OFF_V     8898128                  // 20480
#define OFF_WB    8918608                  // bf16[81][4][16][32] = 82944 floats
#define OFF_VT    9001552                  // 10*16*128 = 20480
#define OFF_W1    9022032                  // bf16[32][352] = 5632 floats
// end: 9027664 floats = 36.1 MB

__device__ __forceinline__ unsigned short f2bf(float f) {
    unsigned int u = __float_as_uint(f);
    u = (u + 0x7FFFu + ((u >> 16) & 1u)) >> 16;   // RNE
    return (unsigned short)u;
}

__global__ void k_zero(float* __restrict__ p, int n) {
    int i = blockIdx.x * 256 + threadIdx.x;
    if (i < n) p[i] = 0.f;
}

// conv_w (32,3,9,9) fp32 -> W1 bf16 [co=32][k=352], k=(ci*9+kh)*12+kw, pads 0
__global__ void k_w1prep(const float* __restrict__ cw, unsigned short* __restrict__ W1) {
    int idx = blockIdx.x * 256 + threadIdx.x;    // 32*352 = 11264
    if (idx >= 32 * K1) return;
    int co = idx / K1, k = idx - co * K1;
    int g = k / 12, kw = k - g * 12;
    float v = (kw < 9 && g < 27) ? cw[((co * 3 + g / 9) * 9 + (g % 9)) * 9 + kw] : 0.f;
    W1[idx] = f2bf(v);
}

// conv1 via im2col-in-LDS MFMA: data fp32 -> xh bf16 [b][p][co=32] (+bias+relu)
// block = (b, tile of 64 positions); 4 waves, wave = m-subtile of 16.
__global__ __launch_bounds__(256) void k_conv1m(const float* __restrict__ data,
                                                const unsigned short* __restrict__ W1,
                                                const float* __restrict__ cb,
                                                unsigned short* __restrict__ xh) {
    int b = blockIdx.x / 27, g64 = blockIdx.x % 27;
    int p0 = g64 * 64;
    int t = threadIdx.x, lane = t & 63, wv = t >> 6;
    int quad = lane >> 4, mloc = lane & 15;
    __shared__ __align__(16) unsigned short As[64 * K1];   // 45 KB
    // zero-init (pads must be finite: W1 pad is 0, 0*0=0)
    u64* az = (u64*)As;
    for (int k = t; k < 64 * K1 / 4; k += 256) az[k] = 0ull;
    __syncthreads();
    // stage: task (g wave-uniform, m = lane)
#pragma unroll 1
    for (int it = 0; it < 7; it++) {
        int g = wv + it * 4;
        if (g < 27) {
            int m = lane;
            int p = p0 + m; if (p > 1680) p = 1680;
            int h = p / 41, w = p - h * 41;
            int ci = g / 9, kh = g - ci * 9;
            const float* src = &data[((b * 3 + ci) * 49 + (h + kh)) * 49 + w];
            unsigned short pk[12];
#pragma unroll
            for (int kw = 0; kw < 9; kw++) pk[kw] = f2bf(src[kw]);
            pk[9] = 0; pk[10] = 0; pk[11] = 0;
            u64* dst = (u64*)&As[m * K1 + g * 12];
            const u64* s = (const u64*)pk;
            dst[0] = s[0]; dst[1] = s[1]; dst[2] = s[2];
        }
    }
    __syncthreads();
    f32x4 acc0 = {0.f, 0.f, 0.f, 0.f}, acc1 = {0.f, 0.f, 0.f, 0.f};
    const unsigned short* wp0 = &W1[(size_t)mloc * K1 + quad * 8];
    const unsigned short* wp1 = &W1[(size_t)(16 + mloc) * K1 + quad * 8];
    const unsigned short* ap = &As[(wv * 16 + mloc) * K1 + quad * 8];
#pragma unroll 1
    for (int kc = 0; kc < 11; kc++) {
        short8 af = *(const short8*)(ap + kc * 32);
        short8 b0 = *(const short8*)(wp0 + kc * 32);
        short8 b1 = *(const short8*)(wp1 + kc * 32);
        acc0 = __builtin_amdgcn_mfma_f32_16x16x32_bf16(af, b0, acc0, 0, 0, 0);
        acc1 = __builtin_amdgcn_mfma_f32_16x16x32_bf16(af, b1, acc1, 0, 0, 0);
    }
    __syncthreads();
    unsigned short* tile = As;                    // reuse: [64 m][40]
    float bias0 = cb[mloc], bias1 = cb[16 + mloc];
#pragma unroll
    for (int r = 0; r < 4; r++) {
        int m = wv * 16 + quad * 4 + r;
        float v0 = acc0[r] + bias0; v0 = v0 > 0.f ? v0 : 0.f;
        float v1 = acc1[r] + bias1; v1 = v1 > 0.f ? v1 : 0.f;
        tile[m * 40 + mloc] = f2bf(v0);
        tile[m * 40 + 16 + mloc] = f2bf(v1);
    }
    __syncthreads();
    int m = t >> 2, part = t & 3;
    int p = p0 + m;
    if (p < 1681)
        *(int4*)&xh[((size_t)(b * 1681 + p)) * 32 + part * 8] =
            *(const int4*)&tile[m * 40 + part * 8];
}

// prim_w (64,32,9,9) fp32 -> Wb[tap=kh*9+kw][cog=4][co=16][ci=32] bf16
__global__ void k_wprep(const float* __restrict__ pw, unsigned short* __restrict__ Wb) {
    int idx = blockIdx.x * 256 + threadIdx.x;   // 81*2048 = 165888
    if (idx >= 165888) return;
    int ci = idx & 31, co = (idx >> 5) & 15, cog = (idx >> 9) & 3, tap = idx >> 11;
    Wb[idx] = f2bf(pw[((cog * 16 + co) * 32 + ci) * 81 + tap]);
}

// conv2 implicit-GEMM MFMA, LDS-staged input.
__global__ __launch_bounds__(512) void k_conv2(const unsigned short* __restrict__ xh,
                                               const unsigned short* __restrict__ Wb,
                                               const float* __restrict__ pb,
                                               float* __restrict__ u0) {
    int b = blockIdx.x / 5, g = blockIdx.x % 5;
    int t = threadIdx.x, lane = t & 63, wv = t >> 6;
    int quad = lane >> 4, mloc = lane & 15;
    int cg = wv & 3, half = wv >> 2;
    __shared__ __align__(16) char lds[50184];     // max(17*41*36*2, 64*65*4)
    unsigned short* As = (unsigned short*)lds;
    const unsigned short* xb = xh + (size_t)b * 53792;   // 1681*32
    int p_hi = g * 64 + 63; if (p_hi > 288) p_hi = 288;
    int r0 = 2 * ((g * 64) / 17);
    int nrows = 2 * (p_hi / 17) + 9 - r0;         // <= 17
    int nch = nrows * 164;                        // 8-short chunks: 41*4 per row
    for (int k = t; k < nch; k += 512) {
        int rl = k / 164, rem = k - rl * 164;
        int col = rem >> 2, ci8 = rem & 3;
        const u64* src = (const u64*)&xb[((r0 + rl) * 41 + col) * 32 + ci8 * 8];
        u64* dst = (u64*)&As[(rl * 41 + col) * 36 + ci8 * 8];
        dst[0] = src[0];
        dst[1] = src[1];
    }
    __syncthreads();
    int abase0, abase1;
    {
        int p = g * 64 + half * 32 + mloc;        // mt=0
        if (p > 288) p = 288;
        abase0 = ((2 * (p / 17) - r0) * 41 + 2 * (p % 17)) * 36 + quad * 8;
        p = g * 64 + half * 32 + 16 + mloc;       // mt=1
        if (p > 288) p = 288;
        abase1 = ((2 * (p / 17) - r0) * 41 + 2 * (p % 17)) * 36 + quad * 8;
    }
    const unsigned short* wbase = Wb + ((size_t)cg * 16 + mloc) * 32 + quad * 8;
    f32x4 acc0 = {0.f, 0.f, 0.f, 0.f}, acc1 = {0.f, 0.f, 0.f, 0.f};
#pragma unroll 1
    for (int kh = 0; kh < 9; kh++) {
        int rowoff = kh * (41 * 36);
        const unsigned short* wrow = wbase + (size_t)kh * 9 * 2048;
#pragma unroll
        for (int kw = 0; kw < 9; kw++) {
            short8 bf = *(const short8*)(wrow + (size_t)kw * 2048);
            int off = rowoff + kw * 36;
            union { short8 v; u64 q[2]; } a0, a1;
            a0.q[0] = *(const u64*)&As[abase0 + off];
            a0.q[1] = *(const u64*)&As[abase0 + off + 4];
            a1.q[0] = *(const u64*)&As[abase1 + off];
            a1.q[1] = *(const u64*)&As[abase1 + off + 4];
            acc0 = __builtin_amdgcn_mfma_f32_16x16x32_bf16(a0.v, bf, acc0, 0, 0, 0);
            acc1 = __builtin_amdgcn_mfma_f32_16x16x32_bf16(a1.v, bf, acc1, 0, 0, 0);
        }
    }
    __syncthreads();                              // done reading A-tile
    float* tile = (float*)lds;                    // 64 co x 65
#pragma unroll
    for (int r = 0; r < 4; r++) {
        tile[(cg * 16 + mloc) * 65 + half * 32 + quad * 4 + r] = acc0[r];
        tile[(cg * 16 + mloc) * 65 + half * 32 + 16 + quad * 4 + r] = acc1[r];
    }
    __syncthreads();
    int co = t >> 3, p0 = (t & 7) * 8;
    float bias = pb[co];
#pragma unroll
    for (int j = 0; j < 8; j++) {
        int p = g * 64 + p0 + j;
        if (p < 289)
            u0[((size_t)(b * 64 + co)) * 289 + p] = tile[co * 65 + p0 + j] + bias;
    }
}

// per-(b,i) squash scale over 2312 routes (contiguous: channels i*8..i*8+7)
__global__ void k_sumsq(const float* __restrict__ u0, float* __restrict__ scale) {
    int bi = blockIdx.x;                     // b*8 + i
    const float* base = &u0[bi * 8 * 289];
    float sum = 0.f;
    for (int k = threadIdx.x; k < 2312; k += 256) { float v = base[k]; sum += v * v; }
#pragma unroll
    for (int d = 32; d; d >>= 1) sum += __shfl_xor(sum, d);
    __shared__ float red[4];
    if ((threadIdx.x & 63) == 0) red[threadIdx.x >> 6] = sum;
    __syncthreads();
    if (threadIdx.x == 0) {
        float sn = red[0] + red[1] + red[2] + red[3];
        scale[bi] = sn / ((1.f + sn) * sqrtf(sn));
    }
}

// build xT[r][i][b] = u0[b][i*8+j][hw] * scale[b,i]  (r = j*289+hw)
__global__ __launch_bounds__(256) void k_xt(const float* __restrict__ u0,
                                            const float* __restrict__ scale,
                                            float* __restrict__ xT) {
    int tid = blockIdx.x;
    int tile_i = tid / 10, hwt = tid % 10;
    int i = tile_i >> 3, j = tile_i & 7;
    int ch = i * 8 + j;
    int hw0 = hwt * 32;
    int rem = 289 - hw0; if (rem > 32) rem = 32;
    __shared__ float tile[32 * 130];
    int t = threadIdx.x;
    for (int k = t; k < 32 * 128; k += 256) {
        int bb = k >> 5, x = k & 31;
        if (x < rem)
            tile[x * 130 + bb] = u0[(bb * 64 + ch) * 289 + hw0 + x];
    }
    __syncthreads();
    for (int k = t; k < 32 * 128; k += 256) {
        int hwl = k >> 7, bb = k & 127;
        if (hwl < rem)
            xT[((size_t)((j * 289 + hw0 + hwl) * 8 + i)) * 128 + bb] =
                tile[hwl * 130 + bb] * scale[bb * 8 + i];
    }
}

// s partials (softmax fused): block = (chunk,c,ohalf) -> spart[chunk][c][ohalf*8..+8][b]
__global__ __launch_bounds__(256) void k_s(const float* __restrict__ xT,
                                           const float* __restrict__ W,
                                           const float* __restrict__ bij,
                                           float* __restrict__ spart) {
    int bid = blockIdx.x;
    int oh = bid & 1;
    int cc = bid >> 1;
    int chunk = cc / NC, c = cc % NC;
    int r0 = chunk * RC;
    __shared__ float Wc[RC * 64];        // 17.4 KB: o-half columns
    __shared__ float cs[RC];
    for (int k = threadIdx.x; k < RC * 64; k += 256) {
        int rr = k >> 6, kk = k & 63;
        Wc[k] = W[(size_t)(r0 + rr) * 1280 + c * 128 + oh * 64 + kk];
    }
    if (threadIdx.x < RC) {
        int r = r0 + threadIdx.x;
        float x[NC], m = -1e30f;
#pragma unroll
        for (int k = 0; k < NC; k++) { x[k] = bij[r * NC + k]; m = fmaxf(m, x[k]); }
        float s = 0.f;
#pragma unroll
        for (int k = 0; k < NC; k++) { x[k] = expf(x[k] - m); s += x[k]; }
        cs[threadIdx.x] = x[c] / s;
    }
    __syncthreads();
    int bl = threadIdx.x & 63;
    int oq = threadIdx.x >> 6;       // wave-uniform: pair of o's
    float acc0[2] = {0.f, 0.f};
    float acc1[2] = {0.f, 0.f};
    for (int rr = 0; rr < RC; rr++) {
        const float* xrow = &xT[(size_t)(r0 + rr) * 8 * 128];
        float xa[8], xb[8];
#pragma unroll
        for (int i = 0; i < 8; i++) { xa[i] = xrow[i * 128 + bl]; xb[i] = xrow[i * 128 + bl + 64]; }
        float cr = cs[rr];
        const float* wrow = &Wc[rr * 64 + oq * 16];
#pragma unroll
        for (int oo = 0; oo < 2; oo++) {
            float4 wA = *(const float4*)&wrow[oo * 8];
            float4 wB = *(const float4*)&wrow[oo * 8 + 4];
            float d0 = wA.x * xa[0] + wA.y * xa[1] + wA.z * xa[2] + wA.w * xa[3]
                     + wB.x * xa[4] + wB.y * xa[5] + wB.z * xa[6] + wB.w * xa[7];
            float d1 = wA.x * xb[0] + wA.y * xb[1] + wA.z * xb[2] + wA.w * xb[3]
                     + wB.x * xb[4] + wB.y * xb[5] + wB.z * xb[6] + wB.w * xb[7];
            acc0[oo] = fmaf(cr, d0, acc0[oo]);
            acc1[oo] = fmaf(cr, d1, acc1[oo]);
        }
    }
    float* sp = &spart[((size_t)(chunk * NC + c) * 16) * 128];
#pragma unroll
    for (int oo = 0; oo < 2; oo++) {
        int o = oh * 8 + oq * 2 + oo;
        sp[o * 128 + bl] = acc0[oo];
        sp[o * 128 + bl + 64] = acc1[oo];
    }
}

// reduce spart over chunks, squash over o -> v, vT (and d_out[0:20480])
__global__ void k_v(const float* __restrict__ spart, float* __restrict__ v,
                    float* __restrict__ vT, float* __restrict__ out) {
    int idx = blockIdx.x * 256 + threadIdx.x;     // (bc, o), o = low 4 bits
    int o = idx & 15;
    int bc = idx >> 4;
    int c = bc % NC, b = bc / NC;
    float s = 0.f;
    for (int k = 0; k < NCH; k++)
        s += spart[((size_t)(k * NC + c) * 16 + o) * 128 + b];
    float sq = s * s;
#pragma unroll
    for (int d = 1; d < 16; d <<= 1) sq += __shfl_xor(sq, d);
    float sn = sq;
    float vv = s * sn / ((1.f + sn) * sqrtf(sn));
    v[idx] = vv;
    out[idx] = vv;
    vT[(c * 16 + o) * 128 + b] = vv;
}

// a[r,c] = 1/B * sum_{b,o} vT[c,o,b] * sum_i W[r,c,o,i]*xT[r,i,b];  bij += a
__global__ __launch_bounds__(256) void k_a(const float* __restrict__ xT,
                                           const float* __restrict__ W,
                                           const float* __restrict__ vT,
                                           float* __restrict__ bij) {
    int wv = threadIdx.x >> 6, lane = threadIdx.x & 63;
    int wid = __builtin_amdgcn_readfirstlane(blockIdx.x * 4 + wv);
    int r = wid / NC, c = wid - r * NC;
    const float* xr = &xT[(size_t)r * 1024];
    float x0[8], x1[8];
#pragma unroll
    for (int i = 0; i < 8; i++) { x0[i] = xr[i * 128 + lane]; x1[i] = xr[i * 128 + lane + 64]; }
    const float* wr = &W[(size_t)r * 1280 + c * 128];
    const float* vc = &vT[c * 2048];
    float acc = 0.f;
#pragma unroll
    for (int o = 0; o < 16; o++) {
        float w[8];
#pragma unroll
        for (int i = 0; i < 8; i++) w[i] = wr[o * 8 + i];
        float u0 = 0.f, u1 = 0.f;
#pragma unroll
        for (int i = 0; i < 8; i++) { u0 = fmaf(w[i], x0[i], u0); u1 = fmaf(w[i], x1[i], u1); }
        acc = fmaf(vc[o * 128 + lane], u0, acc);
        acc = fmaf(vc[o * 128 + lane + 64], u1, acc);
    }
#pragma unroll
    for (int d = 1; d < 64; d <<= 1) acc += __shfl_xor(acc, d);
    if (lane == 0) bij[wid] += acc * 0.0078125f;
}

// head: h = tanh(v @ w1 + b1); logit = h @ w2 + b2; sigmoid
__global__ void k_head(const float* __restrict__ v, const float* __restrict__ w1,
                       const float* __restrict__ b1, const float* __restrict__ w2,
                       const float* __restrict__ b2, float* __restrict__ out) {
    int b = blockIdx.x / NC, c = blockIdx.x % NC;
    int t = threadIdx.x;
    float p = 0.f;
    if (t < 100) {
        float hs = b1[c * 100 + t];
        const float* vb = &v[(b * NC + c) * 16];
#pragma unroll
        for (int i = 0; i < 16; i++) hs = fmaf(vb[i], w1[(c * 16 + i) * 100 + t], hs);
        p = tanhf(hs) * w2[c * 100 + t];
    }
#pragma unroll
    for (int d = 1; d < 64; d <<= 1) p += __shfl_xor(p, d);
    __shared__ float red[2];
    if ((t & 63) == 0) red[t >> 6] = p;
    __syncthreads();
    if (t == 0) {
        float logit = red[0] + red[1] + b2[c];
        out[20480 + c * 128 + b] = 1.f / (1.f + expf(-logit));
    }
}

extern "C" void kernel_launch(void* const* d_in, const int* in_sizes, int n_in,
                              void* d_out, int out_size, void* d_ws, size_t ws_size,
                              hipStream_t stream) {
    const float* data   = (const float*)d_in[0];
    const float* conv_w = (const float*)d_in[1];
    const float* conv_b = (const float*)d_in[2];
    const float* prim_w = (const float*)d_in[3];
    const float* prim_b = (const float*)d_in[4];
    const float* Wd     = (const float*)d_in[5];
    const float* hw1    = (const float*)d_in[6];
    const float* hb1    = (const float*)d_in[7];
    const float* hw2    = (const float*)d_in[8];
    const float* hb2    = (const float*)d_in[9];
    float* ws = (float*)d_ws;
    unsigned short* xh = (unsigned short*)(ws + OFF_XH);
    float* u0    = ws + OFF_U0;
    float* xT    = ws + OFF_XT;
    float* scale = ws + OFF_SC;
    float* bij   = ws + OFF_BIJ;
    float* spart = ws + OFF_SP;
    float* v     = ws + OFF_V;
    unsigned short* Wb = (unsigned short*)(ws + OFF_WB);
    float* vT    = ws + OFF_VT;
    unsigned short* W1 = (unsigned short*)(ws + OFF_W1);
    float* out = (float*)d_out;

    k_zero<<<(23120 + 255) / 256, 256, 0, stream>>>(bij, 23120);
    k_w1prep<<<44, 256, 0, stream>>>(conv_w, W1);
    k_wprep<<<648, 256, 0, stream>>>(prim_w, Wb);
    k_conv1m<<<128 * 27, 256, 0, stream>>>(data, W1, conv_b, xh);
    k_conv2<<<128 * 5, 512, 0, stream>>>(xh, Wb, prim_b, u0);
    k_sumsq<<<1024, 256, 0, stream>>>(u0, scale);
    k_xt<<<640, 256, 0, stream>>>(u0, scale, xT);
    for (int it = 0; it < 3; it++) {
        k_s<<<NCH * NC * 2, 256, 0, stream>>>(xT, Wd, bij, spart);
        k_v<<<80, 256, 0, stream>>>(spart, v, vT, out);
        if (it < 2) k_a<<<5780, 256, 0, stream>>>(xT, Wd, vT, bij);
    }
    k_head<<<128 * NC, 128, 0, stream>>>(v, hw1, hb1, hw2, hb2, out);
}

// Round 8
// 362.317 us; speedup vs baseline: 3.6708x; 1.0053x over previous
//
#include <hip/hip_runtime.h>
#include <math.h>

#define BATCH 128
#define NR 2312          // 8*17*17 routes
#define RC 68            // route chunk
#define NCH 34           // NR / RC
#define NC 10            // caps
#define OC 16            // out ch
#define IC 8             // in ch
#define K1 352           // conv1 padded K: (ci*9+kh)*12 + kw

typedef short short8 __attribute__((ext_vector_type(8)));
typedef float f32x4 __attribute__((ext_vector_type(4)));
typedef unsigned long long u64;

// ---- workspace layout (float-slot offsets) ----
#define OFF_XH    0                        // bf16[128][1681][32] = 3442688 floats
#define OFF_U0    3442688                  // 128*64*289 = 2367488
#define OFF_XT    5810176                  // 2312*8*128 = 2367488
#define OFF_SC    8177664                  // 1024
#define OFF_BIJ   8178688                  // 23120
#define OFF_SP    8201808                  // 34*10*16*128 = 696320
#define OFF_V     8898128                  // 20480
#define OFF_WB    8918608                  // bf16[81][4][16][32] = 82944 floats
#define OFF_VT    9001552                  // 10*16*128 = 20480
#define OFF_W1    9022032                  // bf16[32][352] = 5632 floats
// end: 9027664 floats = 36.1 MB

__device__ __forceinline__ unsigned short f2bf(float f) {
    unsigned int u = __float_as_uint(f);
    u = (u + 0x7FFFu + ((u >> 16) & 1u)) >> 16;   // RNE
    return (unsigned short)u;
}

__global__ void k_zero(float* __restrict__ p, int n) {
    int i = blockIdx.x * 256 + threadIdx.x;
    if (i < n) p[i] = 0.f;
}

// conv_w (32,3,9,9) fp32 -> W1 bf16 [co=32][k=352], k=(ci*9+kh)*12+kw, pads 0
__global__ void k_w1prep(const float* __restrict__ cw, unsigned short* __restrict__ W1) {
    int idx = blockIdx.x * 256 + threadIdx.x;    // 32*352 = 11264
    if (idx >= 32 * K1) return;
    int co = idx / K1, k = idx - co * K1;
    int g = k / 12, kw = k - g * 12;
    float v = (kw < 9 && g < 27) ? cw[((co * 3 + g / 9) * 9 + (g % 9)) * 9 + kw] : 0.f;
    W1[idx] = f2bf(v);
}

// conv1 via im2col-in-LDS MFMA: data fp32 -> xh bf16 [b][p][co=32] (+bias+relu)
// A-tile LDS layout is k-major chunked: As64[c][m], c = k/4 (u64 chunks).
//   write: lane m -> addr (c*64+m)*8 : 8B lane stride, conflict-free
//   read:  A-frag = chunks kc*8+quad*2, +1 : 16 contiguous lanes * 8B, conflict-free
__global__ __launch_bounds__(256) void k_conv1m(const float* __restrict__ data,
                                                const unsigned short* __restrict__ W1,
                                                const float* __restrict__ cb,
                                                unsigned short* __restrict__ xh) {
    int b = blockIdx.x / 27, g64 = blockIdx.x % 27;
    int p0 = g64 * 64;
    int t = threadIdx.x, lane = t & 63, wv = t >> 6;
    int quad = lane >> 4, mloc = lane & 15;
    __shared__ __align__(16) unsigned short As[88 * 64 * 4];   // 45056 B
    u64* ab = (u64*)As;
    // zero tail chunks c=81..87 (K pad region); disjoint from staged c=0..80
    for (int k = 81 * 64 + t; k < 88 * 64; k += 256) ab[k] = 0ull;
    // stage: wave-uniform g = (ci,kh), lane = m
#pragma unroll 1
    for (int it = 0; it < 7; it++) {
        int g = wv + it * 4;
        if (g < 27) {
            int m = lane;
            int p = p0 + m; if (p > 1680) p = 1680;
            int h = p / 41, w = p - h * 41;
            int ci = g / 9, kh = g - ci * 9;
            const float* src = &data[((b * 3 + ci) * 49 + (h + kh)) * 49 + w];
            unsigned short pk[12];
#pragma unroll
            for (int kw = 0; kw < 9; kw++) pk[kw] = f2bf(src[kw]);
            pk[9] = 0; pk[10] = 0; pk[11] = 0;
            const u64* s = (const u64*)pk;
            ab[(3 * g + 0) * 64 + m] = s[0];
            ab[(3 * g + 1) * 64 + m] = s[1];
            ab[(3 * g + 2) * 64 + m] = s[2];
        }
    }
    __syncthreads();
    f32x4 acc0 = {0.f, 0.f, 0.f, 0.f}, acc1 = {0.f, 0.f, 0.f, 0.f};
    const unsigned short* wp0 = &W1[(size_t)mloc * K1 + quad * 8];
    const unsigned short* wp1 = &W1[(size_t)(16 + mloc) * K1 + quad * 8];
    int mrow = wv * 16 + mloc;
#pragma unroll 1
    for (int kc = 0; kc < 11; kc++) {
        int c = kc * 8 + quad * 2;
        union { short8 v; u64 q[2]; } af;
        af.q[0] = ab[c * 64 + mrow];
        af.q[1] = ab[(c + 1) * 64 + mrow];
        short8 b0 = *(const short8*)(wp0 + kc * 32);
        short8 b1 = *(const short8*)(wp1 + kc * 32);
        acc0 = __builtin_amdgcn_mfma_f32_16x16x32_bf16(af.v, b0, acc0, 0, 0, 0);
        acc1 = __builtin_amdgcn_mfma_f32_16x16x32_bf16(af.v, b1, acc1, 0, 0, 0);
    }
    __syncthreads();
    unsigned short* tile = As;                    // reuse: [64 m][40]
    float bias0 = cb[mloc], bias1 = cb[16 + mloc];
#pragma unroll
    for (int r = 0; r < 4; r++) {
        int m = wv * 16 + quad * 4 + r;
        float v0 = acc0[r] + bias0; v0 = v0 > 0.f ? v0 : 0.f;
        float v1 = acc1[r] + bias1; v1 = v1 > 0.f ? v1 : 0.f;
        tile[m * 40 + mloc] = f2bf(v0);
        tile[m * 40 + 16 + mloc] = f2bf(v1);
    }
    __syncthreads();
    int m = t >> 2, part = t & 3;
    int p = p0 + m;
    if (p < 1681)
        *(int4*)&xh[((size_t)(b * 1681 + p)) * 32 + part * 8] =
            *(const int4*)&tile[m * 40 + part * 8];
}

// prim_w (64,32,9,9) fp32 -> Wb[tap=kh*9+kw][cog=4][co=16][ci=32] bf16
__global__ void k_wprep(const float* __restrict__ pw, unsigned short* __restrict__ Wb) {
    int idx = blockIdx.x * 256 + threadIdx.x;   // 81*2048 = 165888
    if (idx >= 165888) return;
    int ci = idx & 31, co = (idx >> 5) & 15, cog = (idx >> 9) & 3, tap = idx >> 11;
    Wb[idx] = f2bf(pw[((cog * 16 + co) * 32 + ci) * 81 + tap]);
}

// conv2 implicit-GEMM MFMA, LDS-staged input.
__global__ __launch_bounds__(512) void k_conv2(const unsigned short* __restrict__ xh,
                                               const unsigned short* __restrict__ Wb,
                                               const float* __restrict__ pb,
                                               float* __restrict__ u0) {
    int b = blockIdx.x / 5, g = blockIdx.x % 5;
    int t = threadIdx.x, lane = t & 63, wv = t >> 6;
    int quad = lane >> 4, mloc = lane & 15;
    int cg = wv & 3, half = wv >> 2;
    __shared__ __align__(16) char lds[50184];     // max(17*41*36*2, 64*65*4)
    unsigned short* As = (unsigned short*)lds;
    const unsigned short* xb = xh + (size_t)b * 53792;   // 1681*32
    int p_hi = g * 64 + 63; if (p_hi > 288) p_hi = 288;
    int r0 = 2 * ((g * 64) / 17);
    int nrows = 2 * (p_hi / 17) + 9 - r0;         // <= 17
    int nch = nrows * 164;                        // 8-short chunks: 41*4 per row
    for (int k = t; k < nch; k += 512) {
        int rl = k / 164, rem = k - rl * 164;
        int col = rem >> 2, ci8 = rem & 3;
        const u64* src = (const u64*)&xb[((r0 + rl) * 41 + col) * 32 + ci8 * 8];
        u64* dst = (u64*)&As[(rl * 41 + col) * 36 + ci8 * 8];
        dst[0] = src[0];
        dst[1] = src[1];
    }
    __syncthreads();
    int abase0, abase1;
    {
        int p = g * 64 + half * 32 + mloc;        // mt=0
        if (p > 288) p = 288;
        abase0 = ((2 * (p / 17) - r0) * 41 + 2 * (p % 17)) * 36 + quad * 8;
        p = g * 64 + half * 32 + 16 + mloc;       // mt=1
        if (p > 288) p = 288;
        abase1 = ((2 * (p / 17) - r0) * 41 + 2 * (p % 17)) * 36 + quad * 8;
    }
    const unsigned short* wbase = Wb + ((size_t)cg * 16 + mloc) * 32 + quad * 8;
    f32x4 acc0 = {0.f, 0.f, 0.f, 0.f}, acc1 = {0.f, 0.f, 0.f, 0.f};
#pragma unroll 1
    for (int kh = 0; kh < 9; kh++) {
        int rowoff = kh * (41 * 36);
        const unsigned short* wrow = wbase + (size_t)kh * 9 * 2048;
#pragma unroll
        for (int kw = 0; kw < 9; kw++) {
            short8 bf = *(const short8*)(wrow + (size_t)kw * 2048);
            int off = rowoff + kw * 36;
            union { short8 v; u64 q[2]; } a0, a1;
            a0.q[0] = *(const u64*)&As[abase0 + off];
            a0.q[1] = *(const u64*)&As[abase0 + off + 4];
            a1.q[0] = *(const u64*)&As[abase1 + off];
            a1.q[1] = *(const u64*)&As[abase1 + off + 4];
            acc0 = __builtin_amdgcn_mfma_f32_16x16x32_bf16(a0.v, bf, acc0, 0, 0, 0);
            acc1 = __builtin_amdgcn_mfma_f32_16x16x32_bf16(a1.v, bf, acc1, 0, 0, 0);
        }
    }
    __syncthreads();                              // done reading A-tile
    float* tile = (float*)lds;                    // 64 co x 65
#pragma unroll
    for (int r = 0; r < 4; r++) {
        tile[(cg * 16 + mloc) * 65 + half * 32 + quad * 4 + r] = acc0[r];
        tile[(cg * 16 + mloc) * 65 + half * 32 + 16 + quad * 4 + r] = acc1[r];
    }
    __syncthreads();
    int co = t >> 3, p0 = (t & 7) * 8;
    float bias = pb[co];
#pragma unroll
    for (int j = 0; j < 8; j++) {
        int p = g * 64 + p0 + j;
        if (p < 289)
            u0[((size_t)(b * 64 + co)) * 289 + p] = tile[co * 65 + p0 + j] + bias;
    }
}

// per-(b,i) squash scale over 2312 routes (contiguous: channels i*8..i*8+7)
__global__ void k_sumsq(const float* __restrict__ u0, float* __restrict__ scale) {
    int bi = blockIdx.x;                     // b*8 + i
    const float* base = &u0[bi * 8 * 289];
    float sum = 0.f;
    for (int k = threadIdx.x; k < 2312; k += 256) { float v = base[k]; sum += v * v; }
#pragma unroll
    for (int d = 32; d; d >>= 1) sum += __shfl_xor(sum, d);
    __shared__ float red[4];
    if ((threadIdx.x & 63) == 0) red[threadIdx.x >> 6] = sum;
    __syncthreads();
    if (threadIdx.x == 0) {
        float sn = red[0] + red[1] + red[2] + red[3];
        scale[bi] = sn / ((1.f + sn) * sqrtf(sn));
    }
}

// build xT[r][i][b] = u0[b][i*8+j][hw] * scale[b,i]  (r = j*289+hw)
__global__ __launch_bounds__(256) void k_xt(const float* __restrict__ u0,
                                            const float* __restrict__ scale,
                                            float* __restrict__ xT) {
    int tid = blockIdx.x;
    int tile_i = tid / 10, hwt = tid % 10;
    int i = tile_i >> 3, j = tile_i & 7;
    int ch = i * 8 + j;
    int hw0 = hwt * 32;
    int rem = 289 - hw0; if (rem > 32) rem = 32;
    __shared__ float tile[32 * 130];
    int t = threadIdx.x;
    for (int k = t; k < 32 * 128; k += 256) {
        int bb = k >> 5, x = k & 31;
        if (x < rem)
            tile[x * 130 + bb] = u0[(bb * 64 + ch) * 289 + hw0 + x];
    }
    __syncthreads();
    for (int k = t; k < 32 * 128; k += 256) {
        int hwl = k >> 7, bb = k & 127;
        if (hwl < rem)
            xT[((size_t)((j * 289 + hw0 + hwl) * 8 + i)) * 128 + bb] =
                tile[hwl * 130 + bb] * scale[bb * 8 + i];
    }
}

// s partials (softmax fused): block = (chunk,c,ohalf) -> spart[chunk][c][ohalf*8..+8][b]
__global__ __launch_bounds__(256) void k_s(const float* __restrict__ xT,
                                           const float* __restrict__ W,
                                           const float* __restrict__ bij,
                                           float* __restrict__ spart) {
    int bid = blockIdx.x;
    int oh = bid & 1;
    int cc = bid >> 1;
    int chunk = cc / NC, c = cc % NC;
    int r0 = chunk * RC;
    __shared__ float Wc[RC * 64];        // 17.4 KB: o-half columns
    __shared__ float cs[RC];
    for (int k = threadIdx.x; k < RC * 64; k += 256) {
        int rr = k >> 6, kk = k & 63;
        Wc[k] = W[(size_t)(r0 + rr) * 1280 + c * 128 + oh * 64 + kk];
    }
    if (threadIdx.x < RC) {
        int r = r0 + threadIdx.x;
        float x[NC], m = -1e30f;
#pragma unroll
        for (int k = 0; k < NC; k++) { x[k] = bij[r * NC + k]; m = fmaxf(m, x[k]); }
        float s = 0.f;
#pragma unroll
        for (int k = 0; k < NC; k++) { x[k] = expf(x[k] - m); s += x[k]; }
        cs[threadIdx.x] = x[c] / s;
    }
    __syncthreads();
    int bl = threadIdx.x & 63;
    int oq = threadIdx.x >> 6;       // wave-uniform: pair of o's
    float acc0[2] = {0.f, 0.f};
    float acc1[2] = {0.f, 0.f};
    for (int rr = 0; rr < RC; rr++) {
        const float* xrow = &xT[(size_t)(r0 + rr) * 8 * 128];
        float xa[8], xb[8];
#pragma unroll
        for (int i = 0; i < 8; i++) { xa[i] = xrow[i * 128 + bl]; xb[i] = xrow[i * 128 + bl + 64]; }
        float cr = cs[rr];
        const float* wrow = &Wc[rr * 64 + oq * 16];
#pragma unroll
        for (int oo = 0; oo < 2; oo++) {
            float4 wA = *(const float4*)&wrow[oo * 8];
            float4 wB = *(const float4*)&wrow[oo * 8 + 4];
            float d0 = wA.x * xa[0] + wA.y * xa[1] + wA.z * xa[2] + wA.w * xa[3]
                     + wB.x * xa[4] + wB.y * xa[5] + wB.z * xa[6] + wB.w * xa[7];
            float d1 = wA.x * xb[0] + wA.y * xb[1] + wA.z * xb[2] + wA.w * xb[3]
                     + wB.x * xb[4] + wB.y * xb[5] + wB.z * xb[6] + wB.w * xb[7];
            acc0[oo] = fmaf(cr, d0, acc0[oo]);
            acc1[oo] = fmaf(cr, d1, acc1[oo]);
        }
    }
    float* sp = &spart[((size_t)(chunk * NC + c) * 16) * 128];
#pragma unroll
    for (int oo = 0; oo < 2; oo++) {
        int o = oh * 8 + oq * 2 + oo;
        sp[o * 128 + bl] = acc0[oo];
        sp[o * 128 + bl + 64] = acc1[oo];
    }
}

// reduce spart over chunks, squash over o -> v, vT (and d_out[0:20480])
__global__ void k_v(const float* __restrict__ spart, float* __restrict__ v,
                    float* __restrict__ vT, float* __restrict__ out) {
    int idx = blockIdx.x * 256 + threadIdx.x;     // (bc, o), o = low 4 bits
    int o = idx & 15;
    int bc = idx >> 4;
    int c = bc % NC, b = bc / NC;
    float s = 0.f;
    for (int k = 0; k < NCH; k++)
        s += spart[((size_t)(k * NC + c) * 16 + o) * 128 + b];
    float sq = s * s;
#pragma unroll
    for (int d = 1; d < 16; d <<= 1) sq += __shfl_xor(sq, d);
    float sn = sq;
    float vv = s * sn / ((1.f + sn) * sqrtf(sn));
    v[idx] = vv;
    out[idx] = vv;
    vT[(c * 16 + o) * 128 + b] = vv;
}

// a[r,c] = 1/B * sum_{b,o} vT[c,o,b] * sum_i W[r,c,o,i]*xT[r,i,b];  bij += a
__global__ __launch_bounds__(256) void k_a(const float* __restrict__ xT,
                                           const float* __restrict__ W,
                                           const float* __restrict__ vT,
                                           float* __restrict__ bij) {
    int wv = threadIdx.x >> 6, lane = threadIdx.x & 63;
    int wid = __builtin_amdgcn_readfirstlane(blockIdx.x * 4 + wv);
    int r = wid / NC, c = wid - r * NC;
    const float* xr = &xT[(size_t)r * 1024];
    float x0[8], x1[8];
#pragma unroll
    for (int i = 0; i < 8; i++) { x0[i] = xr[i * 128 + lane]; x1[i] = xr[i * 128 + lane + 64]; }
    const float* wr = &W[(size_t)r * 1280 + c * 128];
    const float* vc = &vT[c * 2048];
    float acc = 0.f;
#pragma unroll
    for (int o = 0; o < 16; o++) {
        float w[8];
#pragma unroll
        for (int i = 0; i < 8; i++) w[i] = wr[o * 8 + i];
        float u0 = 0.f, u1 = 0.f;
#pragma unroll
        for (int i = 0; i < 8; i++) { u0 = fmaf(w[i], x0[i], u0); u1 = fmaf(w[i], x1[i], u1); }
        acc = fmaf(vc[o * 128 + lane], u0, acc);
        acc = fmaf(vc[o * 128 + lane + 64], u1, acc);
    }
#pragma unroll
    for (int d = 1; d < 64; d <<= 1) acc += __shfl_xor(acc, d);
    if (lane == 0) bij[wid] += acc * 0.0078125f;
}

// head: h = tanh(v @ w1 + b1); logit = h @ w2 + b2; sigmoid
__global__ void k_head(const float* __restrict__ v, const float* __restrict__ w1,
                       const float* __restrict__ b1, const float* __restrict__ w2,
                       const float* __restrict__ b2, float* __restrict__ out) {
    int b = blockIdx.x / NC, c = blockIdx.x % NC;
    int t = threadIdx.x;
    float p = 0.f;
    if (t < 100) {
        float hs = b1[c * 100 + t];
        const float* vb = &v[(b * NC + c) * 16];
#pragma unroll
        for (int i = 0; i < 16; i++) hs = fmaf(vb[i], w1[(c * 16 + i) * 100 + t], hs);
        p = tanhf(hs) * w2[c * 100 + t];
    }
#pragma unroll
    for (int d = 1; d < 64; d <<= 1) p += __shfl_xor(p, d);
    __shared__ float red[2];
    if ((t & 63) == 0) red[t >> 6] = p;
    __syncthreads();
    if (t == 0) {
        float logit = red[0] + red[1] + b2[c];
        out[20480 + c * 128 + b] = 1.f / (1.f + expf(-logit));
    }
}

extern "C" void kernel_launch(void* const* d_in, const int* in_sizes, int n_in,
                              void* d_out, int out_size, void* d_ws, size_t ws_size,
                              hipStream_t stream) {
    const float* data   = (const float*)d_in[0];
    const float* conv_w = (const float*)d_in[1];
    const float* conv_b = (const float*)d_in[2];
    const float* prim_w = (const float*)d_in[3];
    const float* prim_b = (const float*)d_in[4];
    const float* Wd     = (const float*)d_in[5];
    const float* hw1    = (const float*)d_in[6];
    const float* hb1    = (const float*)d_in[7];
    const float* hw2    = (const float*)d_in[8];
    const float* hb2    = (const float*)d_in[9];
    float* ws = (float*)d_ws;
    unsigned short* xh = (unsigned short*)(ws + OFF_XH);
    float* u0    = ws + OFF_U0;
    float* xT    = ws + OFF_XT;
    float* scale = ws + OFF_SC;
    float* bij   = ws + OFF_BIJ;
    float* spart = ws + OFF_SP;
    float* v     = ws + OFF_V;
    unsigned short* Wb = (unsigned short*)(ws + OFF_WB);
    float* vT    = ws + OFF_VT;
    unsigned short* W1 = (unsigned short*)(ws + OFF_W1);
    float* out = (float*)d_out;

    k_zero<<<(23120 + 255) / 256, 256, 0, stream>>>(bij, 23120);
    k_w1prep<<<44, 256, 0, stream>>>(conv_w, W1);
    k_wprep<<<648, 256, 0, stream>>>(prim_w, Wb);
    k_conv1m<<<128 * 27, 256, 0, stream>>>(data, W1, conv_b, xh);
    k_conv2<<<128 * 5, 512, 0, stream>>>(xh, Wb, prim_b, u0);
    k_sumsq<<<1024, 256, 0, stream>>>(u0, scale);
    k_xt<<<640, 256, 0, stream>>>(u0, scale, xT);
    for (int it = 0; it < 3; it++) {
        k_s<<<NCH * NC * 2, 256, 0, stream>>>(xT, Wd, bij, spart);
        k_v<<<80, 256, 0, stream>>>(spart, v, vT, out);
        if (it < 2) k_a<<<5780, 256, 0, stream>>>(xT, Wd, vT, bij);
    }
    k_head<<<128 * NC, 128, 0, stream>>>(v, hw1, hb1, hw2, hb2, out);
}

// Round 9
// 342.958 us; speedup vs baseline: 3.8780x; 1.0564x over previous
//
#include <hip/hip_runtime.h>
#include <math.h>

#define BATCH 128
#define NR 2312          // 8*17*17 routes
#define RC 68            // route chunk
#define NCH 34           // NR / RC
#define NC 10            // caps
#define OC 16            // out ch
#define IC 8             // in ch
#define K1 352           // conv1 padded K: (ci*9+kh)*12 + kw

typedef short short8 __attribute__((ext_vector_type(8)));
typedef float f32x4 __attribute__((ext_vector_type(4)));
typedef unsigned long long u64;

// ---- workspace layout (float-slot offsets) ----
#define OFF_XH    0                        // bf16[128][1681][32] = 3442688 floats
#define OFF_U0    3442688                  // 128*64*289 = 2367488
#define OFF_XT    5810176                  // 2312*8*128 = 2367488
#define OFF_SC    8177664                  // 1024 (raw sum-of-squares per (b,i))
#define OFF_BIJ   8178688                  // 23120
#define OFF_SP    8201808                  // 34*10*16*128 = 696320
#define OFF_V     8898128                  // 20480
#define OFF_WB    8918608                  // bf16[81][4][16][32] = 82944 floats
#define OFF_VT    9001552                  // 10*16*128 = 20480
#define OFF_W1    9022032                  // bf16[32][352] = 5632 floats
// end: 9027664 floats = 36.1 MB

__device__ __forceinline__ unsigned short f2bf(float f) {
    unsigned int u = __float_as_uint(f);
    u = (u + 0x7FFFu + ((u >> 16) & 1u)) >> 16;   // RNE
    return (unsigned short)u;
}

// fused prep: Wb (conv2 weights bf16), bij zero, scale zero, W1 (conv1 weights bf16)
__global__ void k_prep(const float* __restrict__ cw, const float* __restrict__ pw,
                       unsigned short* __restrict__ W1, unsigned short* __restrict__ Wb,
                       float* __restrict__ bij, float* __restrict__ scale) {
    int idx = blockIdx.x * 256 + threadIdx.x;
    if (idx < 165888) {
        int ci = idx & 31, co = (idx >> 5) & 15, cog = (idx >> 9) & 3, tap = idx >> 11;
        Wb[idx] = f2bf(pw[((cog * 16 + co) * 32 + ci) * 81 + tap]);
        return;
    }
    idx -= 165888;
    if (idx < 23120) { bij[idx] = 0.f; return; }
    idx -= 23120;
    if (idx < 1024) { scale[idx] = 0.f; return; }
    idx -= 1024;
    if (idx < 32 * K1) {
        int co = idx / K1, k = idx - co * K1;
        int g = k / 12, kw = k - g * 12;
        float v = (kw < 9 && g < 27) ? cw[((co * 3 + g / 9) * 9 + (g % 9)) * 9 + kw] : 0.f;
        W1[idx] = f2bf(v);
    }
}

// conv1 via im2col-in-LDS MFMA: data fp32 -> xh bf16 [b][p][co=32] (+bias+relu)
// 8 waves: wave = (msub 0..3) x (co-half 0..1), 1 MFMA accumulator each.
// A-tile LDS k-major chunked: As64[c][m], c = k/4 (u64 chunks) — conflict-free.
__global__ __launch_bounds__(512) void k_conv1m(const float* __restrict__ data,
                                                const unsigned short* __restrict__ W1,
                                                const float* __restrict__ cb,
                                                unsigned short* __restrict__ xh) {
    int b = blockIdx.x / 27, g64 = blockIdx.x % 27;
    int p0 = g64 * 64;
    int t = threadIdx.x, lane = t & 63, wv = t >> 6;      // wv 0..7
    int quad = lane >> 4, mloc = lane & 15;
    int msub = wv & 3, chh = wv >> 2;
    __shared__ __align__(16) unsigned short As[88 * 64 * 4];   // 45056 B
    u64* ab = (u64*)As;
    // zero tail chunks c=81..87 (K pad region)
    for (int k = 81 * 64 + t; k < 88 * 64; k += 512) ab[k] = 0ull;
    // stage: wave-uniform g = (ci,kh), lane = m  (4 rounds over 27 tasks)
#pragma unroll 1
    for (int it = 0; it < 4; it++) {
        int g = wv + it * 8;
        if (g < 27) {
            int m = lane;
            int p = p0 + m; if (p > 1680) p = 1680;
            int h = p / 41, w = p - h * 41;
            int ci = g / 9, kh = g - ci * 9;
            const float* src = &data[((b * 3 + ci) * 49 + (h + kh)) * 49 + w];
            unsigned short pk[12];
#pragma unroll
            for (int kw = 0; kw < 9; kw++) pk[kw] = f2bf(src[kw]);
            pk[9] = 0; pk[10] = 0; pk[11] = 0;
            const u64* s = (const u64*)pk;
            ab[(3 * g + 0) * 64 + m] = s[0];
            ab[(3 * g + 1) * 64 + m] = s[1];
            ab[(3 * g + 2) * 64 + m] = s[2];
        }
    }
    __syncthreads();
    f32x4 acc = {0.f, 0.f, 0.f, 0.f};
    const unsigned short* wp = &W1[(size_t)(chh * 16 + mloc) * K1 + quad * 8];
    int mrow = msub * 16 + mloc;
#pragma unroll 1
    for (int kc = 0; kc < 11; kc++) {
        int c = kc * 8 + quad * 2;
        union { short8 v; u64 q[2]; } af;
        af.q[0] = ab[c * 64 + mrow];
        af.q[1] = ab[(c + 1) * 64 + mrow];
        short8 bfr = *(const short8*)(wp + kc * 32);
        acc = __builtin_amdgcn_mfma_f32_16x16x32_bf16(af.v, bfr, acc, 0, 0, 0);
    }
    __syncthreads();
    unsigned short* tile = As;                    // reuse: [64 m][40]
    float bias = cb[chh * 16 + mloc];
#pragma unroll
    for (int r = 0; r < 4; r++) {
        int m = msub * 16 + quad * 4 + r;
        float v0 = acc[r] + bias; v0 = v0 > 0.f ? v0 : 0.f;
        tile[m * 40 + chh * 16 + mloc] = f2bf(v0);
    }
    __syncthreads();
    if (t < 256) {
        int m = t >> 2, part = t & 3;
        int p = p0 + m;
        if (p < 1681)
            *(int4*)&xh[((size_t)(b * 1681 + p)) * 32 + part * 8] =
                *(const int4*)&tile[m * 40 + part * 8];
    }
}

// conv2 implicit-GEMM MFMA, LDS-staged input. Epilogue also accumulates
// per-(b,i) sum-of-squares into scale[] via one atomicAdd per wave.
__global__ __launch_bounds__(512) void k_conv2(const unsigned short* __restrict__ xh,
                                               const unsigned short* __restrict__ Wb,
                                               const float* __restrict__ pb,
                                               float* __restrict__ u0,
                                               float* __restrict__ scale) {
    int b = blockIdx.x / 5, g = blockIdx.x % 5;
    int t = threadIdx.x, lane = t & 63, wv = t >> 6;
    int quad = lane >> 4, mloc = lane & 15;
    int cg = wv & 3, half = wv >> 2;
    __shared__ __align__(16) char lds[50184];     // max(17*41*36*2, 64*65*4)
    unsigned short* As = (unsigned short*)lds;
    const unsigned short* xb = xh + (size_t)b * 53792;   // 1681*32
    int p_hi = g * 64 + 63; if (p_hi > 288) p_hi = 288;
    int r0 = 2 * ((g * 64) / 17);
    int nrows = 2 * (p_hi / 17) + 9 - r0;         // <= 17
    int nch = nrows * 164;                        // 8-short chunks: 41*4 per row
    for (int k = t; k < nch; k += 512) {
        int rl = k / 164, rem = k - rl * 164;
        int col = rem >> 2, ci8 = rem & 3;
        const u64* src = (const u64*)&xb[((r0 + rl) * 41 + col) * 32 + ci8 * 8];
        u64* dst = (u64*)&As[(rl * 41 + col) * 36 + ci8 * 8];
        dst[0] = src[0];
        dst[1] = src[1];
    }
    __syncthreads();
    int abase0, abase1;
    {
        int p = g * 64 + half * 32 + mloc;        // mt=0
        if (p > 288) p = 288;
        abase0 = ((2 * (p / 17) - r0) * 41 + 2 * (p % 17)) * 36 + quad * 8;
        p = g * 64 + half * 32 + 16 + mloc;       // mt=1
        if (p > 288) p = 288;
        abase1 = ((2 * (p / 17) - r0) * 41 + 2 * (p % 17)) * 36 + quad * 8;
    }
    const unsigned short* wbase = Wb + ((size_t)cg * 16 + mloc) * 32 + quad * 8;
    f32x4 acc0 = {0.f, 0.f, 0.f, 0.f}, acc1 = {0.f, 0.f, 0.f, 0.f};
#pragma unroll 1
    for (int kh = 0; kh < 9; kh++) {
        int rowoff = kh * (41 * 36);
        const unsigned short* wrow = wbase + (size_t)kh * 9 * 2048;
#pragma unroll
        for (int kw = 0; kw < 9; kw++) {
            short8 bf = *(const short8*)(wrow + (size_t)kw * 2048);
            int off = rowoff + kw * 36;
            union { short8 v; u64 q[2]; } a0, a1;
            a0.q[0] = *(const u64*)&As[abase0 + off];
            a0.q[1] = *(const u64*)&As[abase0 + off + 4];
            a1.q[0] = *(const u64*)&As[abase1 + off];
            a1.q[1] = *(const u64*)&As[abase1 + off + 4];
            acc0 = __builtin_amdgcn_mfma_f32_16x16x32_bf16(a0.v, bf, acc0, 0, 0, 0);
            acc1 = __builtin_amdgcn_mfma_f32_16x16x32_bf16(a1.v, bf, acc1, 0, 0, 0);
        }
    }
    __syncthreads();                              // done reading A-tile
    float* tile = (float*)lds;                    // 64 co x 65
#pragma unroll
    for (int r = 0; r < 4; r++) {
        tile[(cg * 16 + mloc) * 65 + half * 32 + quad * 4 + r] = acc0[r];
        tile[(cg * 16 + mloc) * 65 + half * 32 + 16 + quad * 4 + r] = acc1[r];
    }
    __syncthreads();
    int co = t >> 3, p0 = (t & 7) * 8;
    float bias = pb[co];
    float ssum = 0.f;
#pragma unroll
    for (int j = 0; j < 8; j++) {
        int p = g * 64 + p0 + j;
        if (p < 289) {
            float val = tile[co * 65 + p0 + j] + bias;
            u0[((size_t)(b * 64 + co)) * 289 + p] = val;
            ssum += val * val;
        }
    }
    // wave wv covers co = wv*8..wv*8+7  ->  i = wv
#pragma unroll
    for (int d = 1; d < 64; d <<= 1) ssum += __shfl_xor(ssum, d);
    if (lane == 0) atomicAdd(&scale[b * 8 + wv], ssum);
}

// build xT[r][i][b] = u0[b][i*8+j][hw] * squash_scale(b,i)  (r = j*289+hw)
__global__ __launch_bounds__(256) void k_xt(const float* __restrict__ u0,
                                            const float* __restrict__ scale,
                                            float* __restrict__ xT) {
    int tid = blockIdx.x;
    int tile_i = tid / 10, hwt = tid % 10;
    int i = tile_i >> 3, j = tile_i & 7;
    int ch = i * 8 + j;
    int hw0 = hwt * 32;
    int rem = 289 - hw0; if (rem > 32) rem = 32;
    __shared__ float tile[32 * 130];
    __shared__ float sc_s[128];
    int t = threadIdx.x;
    if (t < 128) {
        float sn = scale[t * 8 + i];
        sc_s[t] = sn / ((1.f + sn) * sqrtf(sn));
    }
    for (int k = t; k < 32 * 128; k += 256) {
        int bb = k >> 5, x = k & 31;
        if (x < rem)
            tile[x * 130 + bb] = u0[(bb * 64 + ch) * 289 + hw0 + x];
    }
    __syncthreads();
    for (int k = t; k < 32 * 128; k += 256) {
        int hwl = k >> 7, bb = k & 127;
        if (hwl < rem)
            xT[((size_t)((j * 289 + hw0 + hwl) * 8 + i)) * 128 + bb] =
                tile[hwl * 130 + bb] * sc_s[bb];
    }
}

// s partials (softmax fused): block = (chunk,c,ohalf) -> spart[chunk][c][ohalf*8..+8][b]
__global__ __launch_bounds__(256) void k_s(const float* __restrict__ xT,
                                           const float* __restrict__ W,
                                           const float* __restrict__ bij,
                                           float* __restrict__ spart) {
    int bid = blockIdx.x;
    int oh = bid & 1;
    int cc = bid >> 1;
    int chunk = cc / NC, c = cc % NC;
    int r0 = chunk * RC;
    __shared__ float Wc[RC * 64];        // 17.4 KB: o-half columns
    __shared__ float cs[RC];
    for (int k = threadIdx.x; k < RC * 64; k += 256) {
        int rr = k >> 6, kk = k & 63;
        Wc[k] = W[(size_t)(r0 + rr) * 1280 + c * 128 + oh * 64 + kk];
    }
    if (threadIdx.x < RC) {
        int r = r0 + threadIdx.x;
        float x[NC], m = -1e30f;
#pragma unroll
        for (int k = 0; k < NC; k++) { x[k] = bij[r * NC + k]; m = fmaxf(m, x[k]); }
        float s = 0.f;
#pragma unroll
        for (int k = 0; k < NC; k++) { x[k] = expf(x[k] - m); s += x[k]; }
        cs[threadIdx.x] = x[c] / s;
    }
    __syncthreads();
    int bl = threadIdx.x & 63;
    int oq = threadIdx.x >> 6;       // wave-uniform: pair of o's
    float acc0[2] = {0.f, 0.f};
    float acc1[2] = {0.f, 0.f};
    for (int rr = 0; rr < RC; rr++) {
        const float* xrow = &xT[(size_t)(r0 + rr) * 8 * 128];
        float xa[8], xb[8];
#pragma unroll
        for (int i = 0; i < 8; i++) { xa[i] = xrow[i * 128 + bl]; xb[i] = xrow[i * 128 + bl + 64]; }
        float cr = cs[rr];
        const float* wrow = &Wc[rr * 64 + oq * 16];
#pragma unroll
        for (int oo = 0; oo < 2; oo++) {
            float4 wA = *(const float4*)&wrow[oo * 8];
            float4 wB = *(const float4*)&wrow[oo * 8 + 4];
            float d0 = wA.x * xa[0] + wA.y * xa[1] + wA.z * xa[2] + wA.w * xa[3]
                     + wB.x * xa[4] + wB.y * xa[5] + wB.z * xa[6] + wB.w * xa[7];
            float d1 = wA.x * xb[0] + wA.y * xb[1] + wA.z * xb[2] + wA.w * xb[3]
                     + wB.x * xb[4] + wB.y * xb[5] + wB.z * xb[6] + wB.w * xb[7];
            acc0[oo] = fmaf(cr, d0, acc0[oo]);
            acc1[oo] = fmaf(cr, d1, acc1[oo]);
        }
    }
    float* sp = &spart[((size_t)(chunk * NC + c) * 16) * 128];
#pragma unroll
    for (int oo = 0; oo < 2; oo++) {
        int o = oh * 8 + oq * 2 + oo;
        sp[o * 128 + bl] = acc0[oo];
        sp[o * 128 + bl + 64] = acc1[oo];
    }
}

// reduce spart, squash -> v, vT, out; optional fused head on last iteration
__global__ void k_v(const float* __restrict__ spart, float* __restrict__ v,
                    float* __restrict__ vT, float* __restrict__ out,
                    const float* __restrict__ w1, const float* __restrict__ b1,
                    const float* __restrict__ w2, const float* __restrict__ b2,
                    int do_head) {
    int t = threadIdx.x;
    int idx = blockIdx.x * 256 + t;               // (bc, o), o = low 4 bits
    int o = idx & 15;
    int bc = idx >> 4;
    int c = bc % NC, b = bc / NC;
    float s = 0.f;
    for (int k = 0; k < NCH; k++)
        s += spart[((size_t)(k * NC + c) * 16 + o) * 128 + b];
    float sq = s * s;
#pragma unroll
    for (int d = 1; d < 16; d <<= 1) sq += __shfl_xor(sq, d);
    float sn = sq;
    float vv = s * sn / ((1.f + sn) * sqrtf(sn));
    v[idx] = vv;
    out[idx] = vv;
    vT[(c * 16 + o) * 128 + b] = vv;
    if (do_head) {
        __shared__ float vs[256];
        vs[t] = vv;
        __syncthreads();
        int g = t >> 4, q = t & 15;
        const float* vg = &vs[g * 16];
        float partial = 0.f;
#pragma unroll 1
        for (int k = q; k < 100; k += 16) {
            float hs = b1[c * 100 + k];
#pragma unroll
            for (int i = 0; i < 16; i++) hs = fmaf(vg[i], w1[(c * 16 + i) * 100 + k], hs);
            partial += tanhf(hs) * w2[c * 100 + k];
        }
#pragma unroll
        for (int d = 1; d < 16; d <<= 1) partial += __shfl_xor(partial, d, 16);
        if (q == 0)
            out[20480 + c * 128 + b] = 1.f / (1.f + expf(-(partial + b2[c])));
    }
}

// a[r,c] = 1/B * sum_{b,o} vT[c,o,b] * sum_i W[r,c,o,i]*xT[r,i,b];  bij += a
__global__ __launch_bounds__(256) void k_a(const float* __restrict__ xT,
                                           const float* __restrict__ W,
                                           const float* __restrict__ vT,
                                           float* __restrict__ bij) {
    int wv = threadIdx.x >> 6, lane = threadIdx.x & 63;
    int wid = __builtin_amdgcn_readfirstlane(blockIdx.x * 4 + wv);
    int r = wid / NC, c = wid - r * NC;
    const float* xr = &xT[(size_t)r * 1024];
    float x0[8], x1[8];
#pragma unroll
    for (int i = 0; i < 8; i++) { x0[i] = xr[i * 128 + lane]; x1[i] = xr[i * 128 + lane + 64]; }
    const float* wr = &W[(size_t)r * 1280 + c * 128];
    const float* vc = &vT[c * 2048];
    float acc = 0.f;
#pragma unroll
    for (int o = 0; o < 16; o++) {
        float w[8];
#pragma unroll
        for (int i = 0; i < 8; i++) w[i] = wr[o * 8 + i];
        float u0 = 0.f, u1 = 0.f;
#pragma unroll
        for (int i = 0; i < 8; i++) { u0 = fmaf(w[i], x0[i], u0); u1 = fmaf(w[i], x1[i], u1); }
        acc = fmaf(vc[o * 128 + lane], u0, acc);
        acc = fmaf(vc[o * 128 + lane + 64], u1, acc);
    }
#pragma unroll
    for (int d = 1; d < 64; d <<= 1) acc += __shfl_xor(acc, d);
    if (lane == 0) bij[wid] += acc * 0.0078125f;
}

extern "C" void kernel_launch(void* const* d_in, const int* in_sizes, int n_in,
                              void* d_out, int out_size, void* d_ws, size_t ws_size,
                              hipStream_t stream) {
    const float* data   = (const float*)d_in[0];
    const float* conv_w = (const float*)d_in[1];
    const float* conv_b = (const float*)d_in[2];
    const float* prim_w = (const float*)d_in[3];
    const float* prim_b = (const float*)d_in[4];
    const float* Wd     = (const float*)d_in[5];
    const float* hw1    = (const float*)d_in[6];
    const float* hb1    = (const float*)d_in[7];
    const float* hw2    = (const float*)d_in[8];
    const float* hb2    = (const float*)d_in[9];
    float* ws = (float*)d_ws;
    unsigned short* xh = (unsigned short*)(ws + OFF_XH);
    float* u0    = ws + OFF_U0;
    float* xT    = ws + OFF_XT;
    float* scale = ws + OFF_SC;
    float* bij   = ws + OFF_BIJ;
    float* spart = ws + OFF_SP;
    float* v     = ws + OFF_V;
    unsigned short* Wb = (unsigned short*)(ws + OFF_WB);
    float* vT    = ws + OFF_VT;
    unsigned short* W1 = (unsigned short*)(ws + OFF_W1);
    float* out = (float*)d_out;

    k_prep<<<787, 256, 0, stream>>>(conv_w, prim_w, W1, Wb, bij, scale);
    k_conv1m<<<128 * 27, 512, 0, stream>>>(data, W1, conv_b, xh);
    k_conv2<<<128 * 5, 512, 0, stream>>>(xh, Wb, prim_b, u0, scale);
    k_xt<<<640, 256, 0, stream>>>(u0, scale, xT);
    for (int it = 0; it < 3; it++) {
        k_s<<<NCH * NC * 2, 256, 0, stream>>>(xT, Wd, bij, spart);
        k_v<<<80, 256, 0, stream>>>(spart, v, vT, out, hw1, hb1, hw2, hb2,
                                    it == 2 ? 1 : 0);
        if (it < 2) k_a<<<5780, 256, 0, stream>>>(xT, Wd, vT, bij);
    }
}

// Round 10
// 298.788 us; speedup vs baseline: 4.4513x; 1.1478x over previous
//
#include <hip/hip_runtime.h>
#include <math.h>

#define BATCH 128
#define NR 2312          // 8*17*17 routes
#define RC 34            // route chunk (k_s)
#define NCH 68           // NR / RC
#define NC 10            // caps
#define OC 16            // out ch
#define IC 8             // in ch
#define K1 352           // conv1 padded K: (ci*9+kh)*12 + kw

typedef short short8 __attribute__((ext_vector_type(8)));
typedef float f32x4 __attribute__((ext_vector_type(4)));
typedef unsigned long long u64;

// ---- workspace layout (float-slot offsets) ----
#define OFF_XH    0                        // bf16[128][1681][32] = 3442688 floats
#define OFF_U0    3442688                  // 128*64*289 = 2367488
#define OFF_XTB   5810176                  // bf16[2320][128][8] = 1187840 floats (8 r pad)
#define OFF_SC    6998016                  // 1024 (raw sum-of-squares per (b,i))
#define OFF_BIJ   6999040                  // 23120
#define OFF_SP    7022160                  // 68*10*16*128 = 1392640
#define OFF_V     8414800                  // 20480
#define OFF_WB    8435280                  // bf16[81][4][16][32] = 82944 floats
#define OFF_VT    8518224                  // 10*16*128 = 20480
#define OFF_W1    8538704                  // bf16[32][352] = 5632 floats
// end: 8544336 floats = 34.2 MB

__device__ __forceinline__ unsigned short f2bf(float f) {
    unsigned int u = __float_as_uint(f);
    u = (u + 0x7FFFu + ((u >> 16) & 1u)) >> 16;   // RNE
    return (unsigned short)u;
}
__device__ __forceinline__ float bf2f(unsigned short h) {
    return __uint_as_float(((unsigned int)h) << 16);
}

// fused prep: Wb (conv2 weights bf16), bij zero, scale zero, W1 (conv1 weights bf16)
__global__ void k_prep(const float* __restrict__ cw, const float* __restrict__ pw,
                       unsigned short* __restrict__ W1, unsigned short* __restrict__ Wb,
                       float* __restrict__ bij, float* __restrict__ scale) {
    int idx = blockIdx.x * 256 + threadIdx.x;
    if (idx < 165888) {
        int ci = idx & 31, co = (idx >> 5) & 15, cog = (idx >> 9) & 3, tap = idx >> 11;
        Wb[idx] = f2bf(pw[((cog * 16 + co) * 32 + ci) * 81 + tap]);
        return;
    }
    idx -= 165888;
    if (idx < 23120) { bij[idx] = 0.f; return; }
    idx -= 23120;
    if (idx < 1024) { scale[idx] = 0.f; return; }
    idx -= 1024;
    if (idx < 32 * K1) {
        int co = idx / K1, k = idx - co * K1;
        int g = k / 12, kw = k - g * 12;
        float v = (kw < 9 && g < 27) ? cw[((co * 3 + g / 9) * 9 + (g % 9)) * 9 + kw] : 0.f;
        W1[idx] = f2bf(v);
    }
}

// conv1 via im2col-in-LDS MFMA: data fp32 -> xh bf16 [b][p][co=32] (+bias+relu)
__global__ __launch_bounds__(512) void k_conv1m(const float* __restrict__ data,
                                                const unsigned short* __restrict__ W1,
                                                const float* __restrict__ cb,
                                                unsigned short* __restrict__ xh) {
    int b = blockIdx.x / 27, g64 = blockIdx.x % 27;
    int p0 = g64 * 64;
    int t = threadIdx.x, lane = t & 63, wv = t >> 6;      // wv 0..7
    int quad = lane >> 4, mloc = lane & 15;
    int msub = wv & 3, chh = wv >> 2;
    __shared__ __align__(16) unsigned short As[88 * 64 * 4];   // 45056 B
    u64* ab = (u64*)As;
    for (int k = 81 * 64 + t; k < 88 * 64; k += 512) ab[k] = 0ull;
#pragma unroll 1
    for (int it = 0; it < 4; it++) {
        int g = wv + it * 8;
        if (g < 27) {
            int m = lane;
            int p = p0 + m; if (p > 1680) p = 1680;
            int h = p / 41, w = p - h * 41;
            int ci = g / 9, kh = g - ci * 9;
            const float* src = &data[((b * 3 + ci) * 49 + (h + kh)) * 49 + w];
            unsigned short pk[12];
#pragma unroll
            for (int kw = 0; kw < 9; kw++) pk[kw] = f2bf(src[kw]);
            pk[9] = 0; pk[10] = 0; pk[11] = 0;
            const u64* s = (const u64*)pk;
            ab[(3 * g + 0) * 64 + m] = s[0];
            ab[(3 * g + 1) * 64 + m] = s[1];
            ab[(3 * g + 2) * 64 + m] = s[2];
        }
    }
    __syncthreads();
    f32x4 acc = {0.f, 0.f, 0.f, 0.f};
    const unsigned short* wp = &W1[(size_t)(chh * 16 + mloc) * K1 + quad * 8];
    int mrow = msub * 16 + mloc;
#pragma unroll 1
    for (int kc = 0; kc < 11; kc++) {
        int c = kc * 8 + quad * 2;
        union { short8 v; u64 q[2]; } af;
        af.q[0] = ab[c * 64 + mrow];
        af.q[1] = ab[(c + 1) * 64 + mrow];
        short8 bfr = *(const short8*)(wp + kc * 32);
        acc = __builtin_amdgcn_mfma_f32_16x16x32_bf16(af.v, bfr, acc, 0, 0, 0);
    }
    __syncthreads();
    unsigned short* tile = As;                    // reuse: [64 m][40]
    float bias = cb[chh * 16 + mloc];
#pragma unroll
    for (int r = 0; r < 4; r++) {
        int m = msub * 16 + quad * 4 + r;
        float v0 = acc[r] + bias; v0 = v0 > 0.f ? v0 : 0.f;
        tile[m * 40 + chh * 16 + mloc] = f2bf(v0);
    }
    __syncthreads();
    if (t < 256) {
        int m = t >> 2, part = t & 3;
        int p = p0 + m;
        if (p < 1681)
            *(int4*)&xh[((size_t)(b * 1681 + p)) * 32 + part * 8] =
                *(const int4*)&tile[m * 40 + part * 8];
    }
}

// conv2 implicit-GEMM MFMA, LDS-staged input; epilogue accumulates sumsq into scale.
__global__ __launch_bounds__(512) void k_conv2(const unsigned short* __restrict__ xh,
                                               const unsigned short* __restrict__ Wb,
                                               const float* __restrict__ pb,
                                               float* __restrict__ u0,
                                               float* __restrict__ scale) {
    int b = blockIdx.x / 5, g = blockIdx.x % 5;
    int t = threadIdx.x, lane = t & 63, wv = t >> 6;
    int quad = lane >> 4, mloc = lane & 15;
    int cg = wv & 3, half = wv >> 2;
    __shared__ __align__(16) char lds[50184];     // max(17*41*36*2, 64*65*4)
    unsigned short* As = (unsigned short*)lds;
    const unsigned short* xb = xh + (size_t)b * 53792;   // 1681*32
    int p_hi = g * 64 + 63; if (p_hi > 288) p_hi = 288;
    int r0 = 2 * ((g * 64) / 17);
    int nrows = 2 * (p_hi / 17) + 9 - r0;         // <= 17
    int nch = nrows * 164;                        // 8-short chunks: 41*4 per row
    for (int k = t; k < nch; k += 512) {
        int rl = k / 164, rem = k - rl * 164;
        int col = rem >> 2, ci8 = rem & 3;
        const u64* src = (const u64*)&xb[((r0 + rl) * 41 + col) * 32 + ci8 * 8];
        u64* dst = (u64*)&As[(rl * 41 + col) * 36 + ci8 * 8];
        dst[0] = src[0];
        dst[1] = src[1];
    }
    __syncthreads();
    int abase0, abase1;
    {
        int p = g * 64 + half * 32 + mloc;        // mt=0
        if (p > 288) p = 288;
        abase0 = ((2 * (p / 17) - r0) * 41 + 2 * (p % 17)) * 36 + quad * 8;
        p = g * 64 + half * 32 + 16 + mloc;       // mt=1
        if (p > 288) p = 288;
        abase1 = ((2 * (p / 17) - r0) * 41 + 2 * (p % 17)) * 36 + quad * 8;
    }
    const unsigned short* wbase = Wb + ((size_t)cg * 16 + mloc) * 32 + quad * 8;
    f32x4 acc0 = {0.f, 0.f, 0.f, 0.f}, acc1 = {0.f, 0.f, 0.f, 0.f};
#pragma unroll 1
    for (int kh = 0; kh < 9; kh++) {
        int rowoff = kh * (41 * 36);
        const unsigned short* wrow = wbase + (size_t)kh * 9 * 2048;
#pragma unroll
        for (int kw = 0; kw < 9; kw++) {
            short8 bf = *(const short8*)(wrow + (size_t)kw * 2048);
            int off = rowoff + kw * 36;
            union { short8 v; u64 q[2]; } a0, a1;
            a0.q[0] = *(const u64*)&As[abase0 + off];
            a0.q[1] = *(const u64*)&As[abase0 + off + 4];
            a1.q[0] = *(const u64*)&As[abase1 + off];
            a1.q[1] = *(const u64*)&As[abase1 + off + 4];
            acc0 = __builtin_amdgcn_mfma_f32_16x16x32_bf16(a0.v, bf, acc0, 0, 0, 0);
            acc1 = __builtin_amdgcn_mfma_f32_16x16x32_bf16(a1.v, bf, acc1, 0, 0, 0);
        }
    }
    __syncthreads();                              // done reading A-tile
    float* tile = (float*)lds;                    // 64 co x 65
#pragma unroll
    for (int r = 0; r < 4; r++) {
        tile[(cg * 16 + mloc) * 65 + half * 32 + quad * 4 + r] = acc0[r];
        tile[(cg * 16 + mloc) * 65 + half * 32 + 16 + quad * 4 + r] = acc1[r];
    }
    __syncthreads();
    int co = t >> 3, p0 = (t & 7) * 8;
    float bias = pb[co];
    float ssum = 0.f;
#pragma unroll
    for (int j = 0; j < 8; j++) {
        int p = g * 64 + p0 + j;
        if (p < 289) {
            float val = tile[co * 65 + p0 + j] + bias;
            u0[((size_t)(b * 64 + co)) * 289 + p] = val;
            ssum += val * val;
        }
    }
#pragma unroll
    for (int d = 1; d < 64; d <<= 1) ssum += __shfl_xor(ssum, d);
    if (lane == 0) atomicAdd(&scale[b * 8 + wv], ssum);
}

// build xTb[r][b][i] (bf16) = u0[b][i*8+j][hw] * squash_scale(b,i)  (r = j*289+hw)
__global__ __launch_bounds__(256) void k_xt(const float* __restrict__ u0,
                                            const float* __restrict__ scale,
                                            unsigned short* __restrict__ xTb) {
    int tid = blockIdx.x;
    int tile_i = tid / 10, hwt = tid % 10;
    int i = tile_i >> 3, j = tile_i & 7;
    int ch = i * 8 + j;
    int hw0 = hwt * 32;
    int rem = 289 - hw0; if (rem > 32) rem = 32;
    __shared__ float tile[32 * 130];
    __shared__ float sc_s[128];
    int t = threadIdx.x;
    if (t < 128) {
        float sn = scale[t * 8 + i];
        sc_s[t] = sn / ((1.f + sn) * sqrtf(sn));
    }
    for (int k = t; k < 32 * 128; k += 256) {
        int bb = k >> 5, x = k & 31;
        if (x < rem)
            tile[x * 130 + bb] = u0[(bb * 64 + ch) * 289 + hw0 + x];
    }
    __syncthreads();
    for (int k = t; k < 32 * 128; k += 256) {
        int hwl = k >> 7, bb = k & 127;
        if (hwl < rem)
            xTb[((size_t)((j * 289 + hw0 + hwl)) * 128 + bb) * 8 + i] =
                f2bf(tile[hwl * 130 + bb] * sc_s[bb]);
    }
}

// s partials via MFMA (softmax fused): block (chunk of 34 r, c)
// A[o][k]=cs_r*W bf16 in LDS (stride 296 shorts = 20 dwords mod 32: conflict-free);
// B = xTb direct 16B frags. K = 272 padded to 288 (A pad rows zero).
__global__ __launch_bounds__(256) void k_s(const unsigned short* __restrict__ xTb,
                                           const float* __restrict__ W,
                                           const float* __restrict__ bij,
                                           float* __restrict__ spart) {
    int chunk = blockIdx.x / NC, c = blockIdx.x % NC;
    int r0 = chunk * RC;
    __shared__ __align__(16) unsigned short As[16 * 296];   // 9472 B
    __shared__ float cs[RC];
    int t = threadIdx.x;
    { int o = t >> 4, kk = t & 15; As[o * 296 + 272 + kk] = 0; }  // zero pad k 272..287
    if (t < RC) {
        int r = r0 + t;
        float x[NC], m = -1e30f;
#pragma unroll
        for (int k = 0; k < NC; k++) { x[k] = bij[r * NC + k]; m = fmaxf(m, x[k]); }
        float s = 0.f;
#pragma unroll
        for (int k = 0; k < NC; k++) { x[k] = expf(x[k] - m); s += x[k]; }
        cs[t] = x[c] / s;
    }
    __syncthreads();
    // stage A: task k -> (rr = k>>4, o = k&15), 8 i's each
    for (int k = t; k < RC * 16; k += 256) {
        int rr = k >> 4, o = k & 15;
        const float* wsrc = &W[(size_t)(r0 + rr) * 1280 + c * 128 + o * 8];
        float cr = cs[rr];
        unsigned short pk[8];
#pragma unroll
        for (int i = 0; i < 8; i++) pk[i] = f2bf(wsrc[i] * cr);
        *(int4*)&As[o * 296 + rr * 8] = *(const int4*)pk;
    }
    __syncthreads();
    int lane = t & 63, wv = t >> 6;
    int quad = lane >> 4, mloc = lane & 15;
    int n0 = wv * 32;
    f32x4 acc0 = {0.f, 0.f, 0.f, 0.f}, acc1 = {0.f, 0.f, 0.f, 0.f};
    const unsigned short* ap = &As[mloc * 296 + quad * 8];
#pragma unroll
    for (int kc = 0; kc < 9; kc++) {
        short8 af = *(const short8*)(ap + kc * 32);
        const unsigned short* bb = &xTb[(size_t)(r0 + kc * 4 + quad) * 1024];
        short8 b0 = *(const short8*)(bb + (n0 + mloc) * 8);
        short8 b1 = *(const short8*)(bb + (n0 + 16 + mloc) * 8);
        acc0 = __builtin_amdgcn_mfma_f32_16x16x32_bf16(af, b0, acc0, 0, 0, 0);
        acc1 = __builtin_amdgcn_mfma_f32_16x16x32_bf16(af, b1, acc1, 0, 0, 0);
    }
    float* sp = &spart[(size_t)(chunk * NC + c) * 16 * 128];
#pragma unroll
    for (int r = 0; r < 4; r++) {
        int o = quad * 4 + r;
        sp[o * 128 + n0 + mloc] = acc0[r];
        sp[o * 128 + n0 + 16 + mloc] = acc1[r];
    }
}

// reduce spart, squash -> v, vT, out; optional fused head on last iteration
__global__ void k_v(const float* __restrict__ spart, float* __restrict__ v,
                    float* __restrict__ vT, float* __restrict__ out,
                    const float* __restrict__ w1, const float* __restrict__ b1,
                    const float* __restrict__ w2, const float* __restrict__ b2,
                    int do_head) {
    int t = threadIdx.x;
    int idx = blockIdx.x * 256 + t;               // (bc, o), o = low 4 bits
    int o = idx & 15;
    int bc = idx >> 4;
    int c = bc % NC, b = bc / NC;
    float s = 0.f;
    for (int k = 0; k < NCH; k++)
        s += spart[((size_t)(k * NC + c) * 16 + o) * 128 + b];
    float sq = s * s;
#pragma unroll
    for (int d = 1; d < 16; d <<= 1) sq += __shfl_xor(sq, d);
    float sn = sq;
    float vv = s * sn / ((1.f + sn) * sqrtf(sn));
    v[idx] = vv;
    out[idx] = vv;
    vT[(c * 16 + o) * 128 + b] = vv;
    if (do_head) {
        __shared__ float vs[256];
        vs[t] = vv;
        __syncthreads();
        int g = t >> 4, q = t & 15;
        const float* vg = &vs[g * 16];
        float partial = 0.f;
#pragma unroll 1
        for (int k = q; k < 100; k += 16) {
            float hs = b1[c * 100 + k];
#pragma unroll
            for (int i = 0; i < 16; i++) hs = fmaf(vg[i], w1[(c * 16 + i) * 100 + k], hs);
            partial += tanhf(hs) * w2[c * 100 + k];
        }
#pragma unroll
        for (int d = 1; d < 16; d <<= 1) partial += __shfl_xor(partial, d, 16);
        if (q == 0)
            out[20480 + c * 128 + b] = 1.f / (1.f + expf(-(partial + b2[c])));
    }
}

// a[r,c] = 1/B * sum_{b,o} vT[c,o,b] * sum_i W[r,c,o,i]*xTb[r,b,i];  bij += a
__global__ __launch_bounds__(256) void k_a(const unsigned short* __restrict__ xTb,
                                           const float* __restrict__ W,
                                           const float* __restrict__ vT,
                                           float* __restrict__ bij) {
    int wv = threadIdx.x >> 6, lane = threadIdx.x & 63;
    int wid = __builtin_amdgcn_readfirstlane(blockIdx.x * 4 + wv);
    int r = wid / NC, c = wid - r * NC;
    const unsigned short* xr = &xTb[(size_t)r * 1024];
    union { short8 v; unsigned short u[8]; } s0, s1;
    s0.v = *(const short8*)(xr + lane * 8);
    s1.v = *(const short8*)(xr + (lane + 64) * 8);
    float x0[8], x1[8];
#pragma unroll
    for (int i = 0; i < 8; i++) { x0[i] = bf2f(s0.u[i]); x1[i] = bf2f(s1.u[i]); }
    const float* wr = &W[(size_t)r * 1280 + c * 128];
    const float* vc = &vT[c * 2048];
    float acc = 0.f;
#pragma unroll
    for (int o = 0; o < 16; o++) {
        float w[8];
#pragma unroll
        for (int i = 0; i < 8; i++) w[i] = wr[o * 8 + i];
        float u0 = 0.f, u1 = 0.f;
#pragma unroll
        for (int i = 0; i < 8; i++) { u0 = fmaf(w[i], x0[i], u0); u1 = fmaf(w[i], x1[i], u1); }
        acc = fmaf(vc[o * 128 + lane], u0, acc);
        acc = fmaf(vc[o * 128 + lane + 64], u1, acc);
    }
#pragma unroll
    for (int d = 1; d < 64; d <<= 1) acc += __shfl_xor(acc, d);
    if (lane == 0) bij[wid] += acc * 0.0078125f;
}

extern "C" void kernel_launch(void* const* d_in, const int* in_sizes, int n_in,
                              void* d_out, int out_size, void* d_ws, size_t ws_size,
                              hipStream_t stream) {
    const float* data   = (const float*)d_in[0];
    const float* conv_w = (const float*)d_in[1];
    const float* conv_b = (const float*)d_in[2];
    const float* prim_w = (const float*)d_in[3];
    const float* prim_b = (const float*)d_in[4];
    const float* Wd     = (const float*)d_in[5];
    const float* hw1    = (const float*)d_in[6];
    const float* hb1    = (const float*)d_in[7];
    const float* hw2    = (const float*)d_in[8];
    const float* hb2    = (const float*)d_in[9];
    float* ws = (float*)d_ws;
    unsigned short* xh  = (unsigned short*)(ws + OFF_XH);
    float* u0    = ws + OFF_U0;
    unsigned short* xTb = (unsigned short*)(ws + OFF_XTB);
    float* scale = ws + OFF_SC;
    float* bij   = ws + OFF_BIJ;
    float* spart = ws + OFF_SP;
    float* v     = ws + OFF_V;
    unsigned short* Wb  = (unsigned short*)(ws + OFF_WB);
    float* vT    = ws + OFF_VT;
    unsigned short* W1  = (unsigned short*)(ws + OFF_W1);
    float* out = (float*)d_out;

    k_prep<<<787, 256, 0, stream>>>(conv_w, prim_w, W1, Wb, bij, scale);
    k_conv1m<<<128 * 27, 512, 0, stream>>>(data, W1, conv_b, xh);
    k_conv2<<<128 * 5, 512, 0, stream>>>(xh, Wb, prim_b, u0, scale);
    k_xt<<<640, 256, 0, stream>>>(u0, scale, xTb);
    for (int it = 0; it < 3; it++) {
        k_s<<<NCH * NC, 256, 0, stream>>>(xTb, Wd, bij, spart);
        k_v<<<80, 256, 0, stream>>>(spart, v, vT, out, hw1, hb1, hw2, hb2,
                                    it == 2 ? 1 : 0);
        if (it < 2) k_a<<<5780, 256, 0, stream>>>(xTb, Wd, vT, bij);
    }
}

// Round 11
// 235.158 us; speedup vs baseline: 5.6557x; 1.2706x over previous
//
#include <hip/hip_runtime.h>
#include <math.h>

#define BATCH 128
#define NR 2312          // 8*17*17 routes
#define RC 34            // route chunk (k_s)
#define NCH 68           // NR / RC
#define NC 10            // caps
#define OC 16            // out ch
#define IC 8             // in ch
#define K1 352           // conv1 padded K: (ci*9+kh)*12 + kw

typedef short short8 __attribute__((ext_vector_type(8)));
typedef float f32x4 __attribute__((ext_vector_type(4)));
typedef unsigned long long u64;

// ---- workspace layout (float-slot offsets) ----
#define OFF_XH    0                        // bf16[128][1681][32] = 3442688 floats
#define OFF_U0    3442688                  // 128*64*289 = 2367488
#define OFF_XTB   5810176                  // bf16[2320][128][8] = 1187840 floats (8 r pad)
#define OFF_SC    6998016                  // 1024 (raw sum-of-squares per (b,i))
#define OFF_BIJ   6999040                  // 23120
#define OFF_SP    7022160                  // 68*10*128*16 = 1392640, layout [ch][c][b][o]
#define OFF_V     8414800                  // 20480
#define OFF_WB    8435280                  // bf16[81][4][16][32] = 82944 floats
#define OFF_VT    8518224                  // 10*16*128 = 20480
#define OFF_W1    8538704                  // bf16[32][352] = 5632 floats
// end: 8544336 floats = 34.2 MB

__device__ __forceinline__ unsigned short f2bf(float f) {
    unsigned int u = __float_as_uint(f);
    u = (u + 0x7FFFu + ((u >> 16) & 1u)) >> 16;   // RNE
    return (unsigned short)u;
}
__device__ __forceinline__ float bf2f(unsigned short h) {
    return __uint_as_float(((unsigned int)h) << 16);
}

// fused prep: Wb (conv2 weights bf16), bij zero, scale zero, W1 (conv1 weights bf16)
__global__ void k_prep(const float* __restrict__ cw, const float* __restrict__ pw,
                       unsigned short* __restrict__ W1, unsigned short* __restrict__ Wb,
                       float* __restrict__ bij, float* __restrict__ scale) {
    int idx = blockIdx.x * 256 + threadIdx.x;
    if (idx < 165888) {
        int ci = idx & 31, co = (idx >> 5) & 15, cog = (idx >> 9) & 3, tap = idx >> 11;
        Wb[idx] = f2bf(pw[((cog * 16 + co) * 32 + ci) * 81 + tap]);
        return;
    }
    idx -= 165888;
    if (idx < 23120) { bij[idx] = 0.f; return; }
    idx -= 23120;
    if (idx < 1024) { scale[idx] = 0.f; return; }
    idx -= 1024;
    if (idx < 32 * K1) {
        int co = idx / K1, k = idx - co * K1;
        int g = k / 12, kw = k - g * 12;
        float v = (kw < 9 && g < 27) ? cw[((co * 3 + g / 9) * 9 + (g % 9)) * 9 + kw] : 0.f;
        W1[idx] = f2bf(v);
    }
}

// conv1 via im2col-in-LDS MFMA: data fp32 -> xh bf16 [b][p][co=32] (+bias+relu)
__global__ __launch_bounds__(512) void k_conv1m(const float* __restrict__ data,
                                                const unsigned short* __restrict__ W1,
                                                const float* __restrict__ cb,
                                                unsigned short* __restrict__ xh) {
    int b = blockIdx.x / 27, g64 = blockIdx.x % 27;
    int p0 = g64 * 64;
    int t = threadIdx.x, lane = t & 63, wv = t >> 6;      // wv 0..7
    int quad = lane >> 4, mloc = lane & 15;
    int msub = wv & 3, chh = wv >> 2;
    __shared__ __align__(16) unsigned short As[88 * 64 * 4];   // 45056 B
    u64* ab = (u64*)As;
    for (int k = 81 * 64 + t; k < 88 * 64; k += 512) ab[k] = 0ull;
#pragma unroll 1
    for (int it = 0; it < 4; it++) {
        int g = wv + it * 8;
        if (g < 27) {
            int m = lane;
            int p = p0 + m; if (p > 1680) p = 1680;
            int h = p / 41, w = p - h * 41;
            int ci = g / 9, kh = g - ci * 9;
            const float* src = &data[((b * 3 + ci) * 49 + (h + kh)) * 49 + w];
            unsigned short pk[12];
#pragma unroll
            for (int kw = 0; kw < 9; kw++) pk[kw] = f2bf(src[kw]);
            pk[9] = 0; pk[10] = 0; pk[11] = 0;
            const u64* s = (const u64*)pk;
            ab[(3 * g + 0) * 64 + m] = s[0];
            ab[(3 * g + 1) * 64 + m] = s[1];
            ab[(3 * g + 2) * 64 + m] = s[2];
        }
    }
    __syncthreads();
    f32x4 acc = {0.f, 0.f, 0.f, 0.f};
    const unsigned short* wp = &W1[(size_t)(chh * 16 + mloc) * K1 + quad * 8];
    int mrow = msub * 16 + mloc;
#pragma unroll 1
    for (int kc = 0; kc < 11; kc++) {
        int c = kc * 8 + quad * 2;
        union { short8 v; u64 q[2]; } af;
        af.q[0] = ab[c * 64 + mrow];
        af.q[1] = ab[(c + 1) * 64 + mrow];
        short8 bfr = *(const short8*)(wp + kc * 32);
        acc = __builtin_amdgcn_mfma_f32_16x16x32_bf16(af.v, bfr, acc, 0, 0, 0);
    }
    __syncthreads();
    unsigned short* tile = As;                    // reuse: [64 m][40]
    float bias = cb[chh * 16 + mloc];
#pragma unroll
    for (int r = 0; r < 4; r++) {
        int m = msub * 16 + quad * 4 + r;
        float v0 = acc[r] + bias; v0 = v0 > 0.f ? v0 : 0.f;
        tile[m * 40 + chh * 16 + mloc] = f2bf(v0);
    }
    __syncthreads();
    if (t < 256) {
        int m = t >> 2, part = t & 3;
        int p = p0 + m;
        if (p < 1681)
            *(int4*)&xh[((size_t)(b * 1681 + p)) * 32 + part * 8] =
                *(const int4*)&tile[m * 40 + part * 8];
    }
}

// conv2 implicit-GEMM MFMA. A-tile parity-split: per row, even cols at entry
// e=col/2 (0..20), odd cols at e=21+col/2 (21..40). Output positions (stride-2
// cols) are stride-1 in e -> mloc lane stride 18 dwords (gcd 2 with 32): 4-way max.
__global__ __launch_bounds__(512) void k_conv2(const unsigned short* __restrict__ xh,
                                               const unsigned short* __restrict__ Wb,
                                               const float* __restrict__ pb,
                                               float* __restrict__ u0,
                                               float* __restrict__ scale) {
    int b = blockIdx.x / 5, g = blockIdx.x % 5;
    int t = threadIdx.x, lane = t & 63, wv = t >> 6;
    int quad = lane >> 4, mloc = lane & 15;
    int cg = wv & 3, half = wv >> 2;
    __shared__ __align__(16) char lds[50184];     // max(17*41*36*2, 64*65*4)
    unsigned short* As = (unsigned short*)lds;
    const unsigned short* xb = xh + (size_t)b * 53792;   // 1681*32
    int p_hi = g * 64 + 63; if (p_hi > 288) p_hi = 288;
    int r0 = 2 * ((g * 64) / 17);
    int nrows = 2 * (p_hi / 17) + 9 - r0;         // <= 17
    int nch = nrows * 164;                        // 8-short chunks: 41*4 per row
    for (int k = t; k < nch; k += 512) {
        int rl = k / 164, rem = k - rl * 164;
        int col = rem >> 2, ci8 = rem & 3;
        int e = (col & 1) ? 21 + (col >> 1) : (col >> 1);
        const u64* src = (const u64*)&xb[((r0 + rl) * 41 + col) * 32 + ci8 * 8];
        u64* dst = (u64*)&As[(rl * 41 + e) * 36 + ci8 * 8];
        dst[0] = src[0];
        dst[1] = src[1];
    }
    __syncthreads();
    int abase0, abase1;
    {
        int p = g * 64 + half * 32 + mloc;        // mt=0
        if (p > 288) p = 288;
        abase0 = ((2 * (p / 17) - r0) * 41 + (p % 17)) * 36 + quad * 8;
        p = g * 64 + half * 32 + 16 + mloc;       // mt=1
        if (p > 288) p = 288;
        abase1 = ((2 * (p / 17) - r0) * 41 + (p % 17)) * 36 + quad * 8;
    }
    const unsigned short* wbase = Wb + ((size_t)cg * 16 + mloc) * 32 + quad * 8;
    f32x4 acc0 = {0.f, 0.f, 0.f, 0.f}, acc1 = {0.f, 0.f, 0.f, 0.f};
#pragma unroll 1
    for (int kh = 0; kh < 9; kh++) {
        const unsigned short* wrow = wbase + (size_t)kh * 9 * 2048;
#pragma unroll
        for (int kw = 0; kw < 9; kw++) {
            short8 bf = *(const short8*)(wrow + (size_t)kw * 2048);
            int c0 = (kw & 1) ? 21 + (kw >> 1) : (kw >> 1);
            int off = (kh * 41 + c0) * 36;
            union { short8 v; u64 q[2]; } a0, a1;
            a0.q[0] = *(const u64*)&As[abase0 + off];
            a0.q[1] = *(const u64*)&As[abase0 + off + 4];
            a1.q[0] = *(const u64*)&As[abase1 + off];
            a1.q[1] = *(const u64*)&As[abase1 + off + 4];
            acc0 = __builtin_amdgcn_mfma_f32_16x16x32_bf16(a0.v, bf, acc0, 0, 0, 0);
            acc1 = __builtin_amdgcn_mfma_f32_16x16x32_bf16(a1.v, bf, acc1, 0, 0, 0);
        }
    }
    __syncthreads();                              // done reading A-tile
    float* tile = (float*)lds;                    // 64 co x 65
#pragma unroll
    for (int r = 0; r < 4; r++) {
        tile[(cg * 16 + mloc) * 65 + half * 32 + quad * 4 + r] = acc0[r];
        tile[(cg * 16 + mloc) * 65 + half * 32 + 16 + quad * 4 + r] = acc1[r];
    }
    __syncthreads();
    int co = t >> 3, p0 = (t & 7) * 8;
    float bias = pb[co];
    float ssum = 0.f;
#pragma unroll
    for (int j = 0; j < 8; j++) {
        int p = g * 64 + p0 + j;
        if (p < 289) {
            float val = tile[co * 65 + p0 + j] + bias;
            u0[((size_t)(b * 64 + co)) * 289 + p] = val;
            ssum += val * val;
        }
    }
#pragma unroll
    for (int d = 1; d < 64; d <<= 1) ssum += __shfl_xor(ssum, d);
    if (lane == 0) atomicAdd(&scale[b * 8 + wv], ssum);
}

// build xTb[r][b][i] (bf16) = u0[b][i*8+j][hw] * squash_scale(b,i)  (r = j*289+hw)
__global__ __launch_bounds__(256) void k_xt(const float* __restrict__ u0,
                                            const float* __restrict__ scale,
                                            unsigned short* __restrict__ xTb) {
    int tid = blockIdx.x;
    int tile_i = tid / 10, hwt = tid % 10;
    int i = tile_i >> 3, j = tile_i & 7;
    int ch = i * 8 + j;
    int hw0 = hwt * 32;
    int rem = 289 - hw0; if (rem > 32) rem = 32;
    __shared__ float tile[32 * 130];
    __shared__ float sc_s[128];
    int t = threadIdx.x;
    if (t < 128) {
        float sn = scale[t * 8 + i];
        sc_s[t] = sn / ((1.f + sn) * sqrtf(sn));
    }
    for (int k = t; k < 32 * 128; k += 256) {
        int bb = k >> 5, x = k & 31;
        if (x < rem)
            tile[x * 130 + bb] = u0[(bb * 64 + ch) * 289 + hw0 + x];
    }
    __syncthreads();
    for (int k = t; k < 32 * 128; k += 256) {
        int hwl = k >> 7, bb = k & 127;
        if (hwl < rem)
            xTb[((size_t)((j * 289 + hw0 + hwl)) * 128 + bb) * 8 + i] =
                f2bf(tile[hwl * 130 + bb] * sc_s[bb]);
    }
}

// s partials via MFMA (softmax fused): block (chunk of 34 r, c)
// spart layout: [chunk][c][b][o]
__global__ __launch_bounds__(256) void k_s(const unsigned short* __restrict__ xTb,
                                           const float* __restrict__ W,
                                           const float* __restrict__ bij,
                                           float* __restrict__ spart) {
    int chunk = blockIdx.x / NC, c = blockIdx.x % NC;
    int r0 = chunk * RC;
    __shared__ __align__(16) unsigned short As[16 * 296];   // 9472 B
    __shared__ float cs[RC];
    int t = threadIdx.x;
    { int o = t >> 4, kk = t & 15; As[o * 296 + 272 + kk] = 0; }  // zero pad k 272..287
    if (t < RC) {
        int r = r0 + t;
        float x[NC], m = -1e30f;
#pragma unroll
        for (int k = 0; k < NC; k++) { x[k] = bij[r * NC + k]; m = fmaxf(m, x[k]); }
        float s = 0.f;
#pragma unroll
        for (int k = 0; k < NC; k++) { x[k] = expf(x[k] - m); s += x[k]; }
        cs[t] = x[c] / s;
    }
    __syncthreads();
    for (int k = t; k < RC * 16; k += 256) {
        int rr = k >> 4, o = k & 15;
        const float* wsrc = &W[(size_t)(r0 + rr) * 1280 + c * 128 + o * 8];
        float cr = cs[rr];
        unsigned short pk[8];
#pragma unroll
        for (int i = 0; i < 8; i++) pk[i] = f2bf(wsrc[i] * cr);
        *(int4*)&As[o * 296 + rr * 8] = *(const int4*)pk;
    }
    __syncthreads();
    int lane = t & 63, wv = t >> 6;
    int quad = lane >> 4, mloc = lane & 15;
    int n0 = wv * 32;
    f32x4 acc0 = {0.f, 0.f, 0.f, 0.f}, acc1 = {0.f, 0.f, 0.f, 0.f};
    const unsigned short* ap = &As[mloc * 296 + quad * 8];
#pragma unroll
    for (int kc = 0; kc < 9; kc++) {
        short8 af = *(const short8*)(ap + kc * 32);
        const unsigned short* bb = &xTb[(size_t)(r0 + kc * 4 + quad) * 1024];
        short8 b0 = *(const short8*)(bb + (n0 + mloc) * 8);
        short8 b1 = *(const short8*)(bb + (n0 + 16 + mloc) * 8);
        acc0 = __builtin_amdgcn_mfma_f32_16x16x32_bf16(af, b0, acc0, 0, 0, 0);
        acc1 = __builtin_amdgcn_mfma_f32_16x16x32_bf16(af, b1, acc1, 0, 0, 0);
    }
    float* sp = &spart[(size_t)(chunk * NC + c) * 2048];   // [b][o]
    *(f32x4*)&sp[(n0 + mloc) * 16 + quad * 4] = acc0;
    *(f32x4*)&sp[(n0 + 16 + mloc) * 16 + quad * 4] = acc1;
}

// reduce spart over chunks, squash -> v, vT, out; fused head on last iteration.
// grid 1280 = (b,c); 256 thr = 16 chunk-lanes x 16 o.
__global__ __launch_bounds__(256) void k_v(const float* __restrict__ spart,
                    float* __restrict__ v, float* __restrict__ vT,
                    float* __restrict__ out,
                    const float* __restrict__ w1, const float* __restrict__ b1,
                    const float* __restrict__ w2, const float* __restrict__ b2,
                    int do_head) {
    int b = blockIdx.x / NC, c = blockIdx.x % NC;
    int t = threadIdx.x;
    int cl = t >> 4, o = t & 15;
    float s = 0.f;
#pragma unroll 1
    for (int ch = cl; ch < NCH; ch += 16)
        s += spart[((size_t)(ch * NC + c) * 128 + b) * 16 + o];
    // combine the wave's 4 chunk-lanes
    s += __shfl_xor(s, 16);
    s += __shfl_xor(s, 32);
    __shared__ float red[4][16];
    __shared__ float hred[2];
    if ((t & 63) < 16) red[t >> 6][t & 15] = s;
    __syncthreads();
    if (t < 16) {
        float sum = red[0][t] + red[1][t] + red[2][t] + red[3][t];
        float sq = sum * sum;
#pragma unroll
        for (int d = 1; d < 16; d <<= 1) sq += __shfl_xor(sq, d);
        float vv = sum * sq / ((1.f + sq) * sqrtf(sq));
        int idx = (b * NC + c) * 16 + t;
        v[idx] = vv;
        out[idx] = vv;
        vT[(c * 16 + t) * 128 + b] = vv;
        red[0][t] = vv;
    }
    if (do_head) {
        __syncthreads();
        float partial = 0.f;
        if (t < 100) {
            float hs = b1[c * 100 + t];
#pragma unroll
            for (int i = 0; i < 16; i++) hs = fmaf(red[0][i], w1[(c * 16 + i) * 100 + t], hs);
            partial = tanhf(hs) * w2[c * 100 + t];
        }
#pragma unroll
        for (int d = 1; d < 64; d <<= 1) partial += __shfl_xor(partial, d);
        if ((t & 63) == 0 && t < 128) hred[t >> 6] = partial;
        __syncthreads();
        if (t == 0)
            out[20480 + c * 128 + b] = 1.f / (1.f + expf(-(hred[0] + hred[1] + b2[c])));
    }
}

// a[r,c] = 1/B * sum_{b,o} vT[c,o,b] * sum_i W[r,c,o,i]*xTb[r,b,i];  bij += a
__global__ __launch_bounds__(256) void k_a(const unsigned short* __restrict__ xTb,
                                           const float* __restrict__ W,
                                           const float* __restrict__ vT,
                                           float* __restrict__ bij) {
    int wv = threadIdx.x >> 6, lane = threadIdx.x & 63;
    int wid = __builtin_amdgcn_readfirstlane(blockIdx.x * 4 + wv);
    int r = wid / NC, c = wid - r * NC;
    const unsigned short* xr = &xTb[(size_t)r * 1024];
    union { short8 v; unsigned short u[8]; } s0, s1;
    s0.v = *(const short8*)(xr + lane * 8);
    s1.v = *(const short8*)(xr + (lane + 64) * 8);
    float x0[8], x1[8];
#pragma unroll
    for (int i = 0; i < 8; i++) { x0[i] = bf2f(s0.u[i]); x1[i] = bf2f(s1.u[i]); }
    const float* wr = &W[(size_t)r * 1280 + c * 128];
    const float* vc = &vT[c * 2048];
    float acc = 0.f;
#pragma unroll
    for (int o = 0; o < 16; o++) {
        float w[8];
#pragma unroll
        for (int i = 0; i < 8; i++) w[i] = wr[o * 8 + i];
        float u0 = 0.f, u1 = 0.f;
#pragma unroll
        for (int i = 0; i < 8; i++) { u0 = fmaf(w[i], x0[i], u0); u1 = fmaf(w[i], x1[i], u1); }
        acc = fmaf(vc[o * 128 + lane], u0, acc);
        acc = fmaf(vc[o * 128 + lane + 64], u1, acc);
    }
#pragma unroll
    for (int d = 1; d < 64; d <<= 1) acc += __shfl_xor(acc, d);
    if (lane == 0) bij[wid] += acc * 0.0078125f;
}

extern "C" void kernel_launch(void* const* d_in, const int* in_sizes, int n_in,
                              void* d_out, int out_size, void* d_ws, size_t ws_size,
                              hipStream_t stream) {
    const float* data   = (const float*)d_in[0];
    const float* conv_w = (const float*)d_in[1];
    const float* conv_b = (const float*)d_in[2];
    const float* prim_w = (const float*)d_in[3];
    const float* prim_b = (const float*)d_in[4];
    const float* Wd     = (const float*)d_in[5];
    const float* hw1    = (const float*)d_in[6];
    const float* hb1    = (const float*)d_in[7];
    const float* hw2    = (const float*)d_in[8];
    const float* hb2    = (const float*)d_in[9];
    float* ws = (float*)d_ws;
    unsigned short* xh  = (unsigned short*)(ws + OFF_XH);
    float* u0    = ws + OFF_U0;
    unsigned short* xTb = (unsigned short*)(ws + OFF_XTB);
    float* scale = ws + OFF_SC;
    float* bij   = ws + OFF_BIJ;
    float* spart = ws + OFF_SP;
    float* v     = ws + OFF_V;
    unsigned short* Wb  = (unsigned short*)(ws + OFF_WB);
    float* vT    = ws + OFF_VT;
    unsigned short* W1  = (unsigned short*)(ws + OFF_W1);
    float* out = (float*)d_out;

    k_prep<<<787, 256, 0, stream>>>(conv_w, prim_w, W1, Wb, bij, scale);
    k_conv1m<<<128 * 27, 512, 0, stream>>>(data, W1, conv_b, xh);
    k_conv2<<<128 * 5, 512, 0, stream>>>(xh, Wb, prim_b, u0, scale);
    k_xt<<<640, 256, 0, stream>>>(u0, scale, xTb);
    for (int it = 0; it < 3; it++) {
        k_s<<<NCH * NC, 256, 0, stream>>>(xTb, Wd, bij, spart);
        k_v<<<128 * NC, 256, 0, stream>>>(spart, v, vT, out, hw1, hb1, hw2, hb2,
                                          it == 2 ? 1 : 0);
        if (it < 2) k_a<<<5780, 256, 0, stream>>>(xTb, Wd, vT, bij);
    }
}

// Round 12
// 234.030 us; speedup vs baseline: 5.6830x; 1.0048x over previous
//
#include <hip/hip_runtime.h>
#include <math.h>

#define BATCH 128
#define NR 2312          // 8*17*17 routes
#define RC 34            // route chunk (k_s)
#define NCH 68           // NR / RC
#define NC 10            // caps
#define K1 352           // conv1 padded K: (ci*9+kh)*12 + kw

typedef short short8 __attribute__((ext_vector_type(8)));
typedef float f32x4 __attribute__((ext_vector_type(4)));
typedef unsigned long long u64;

// ---- workspace layout (float-slot offsets) ----
#define OFF_XH    0                        // bf16[128][1681][32] = 3442688 floats
#define OFF_XTB   3442688                  // bf16[2320][128][8] = 1187840 floats (8 r pad)
#define OFF_SC    4630528                  // 1024 (raw sum-of-squares per (b,i))
#define OFF_BIJ   4631552                  // 23120
#define OFF_SP    4654672                  // 68*10*128*16 = 1392640, layout [ch][c][b][o]
#define OFF_V     6047312                  // 20480
#define OFF_WB    6067792                  // bf16[81][4][16][32] = 82944 floats
#define OFF_VT    6150736                  // 10*16*128 = 20480
#define OFF_W1    6171216                  // bf16[32][352] = 5632 floats
// end: 6176848 floats = 24.7 MB

__device__ __forceinline__ unsigned short f2bf(float f) {
    unsigned int u = __float_as_uint(f);
    u = (u + 0x7FFFu + ((u >> 16) & 1u)) >> 16;   // RNE
    return (unsigned short)u;
}
__device__ __forceinline__ float bf2f(unsigned short h) {
    return __uint_as_float(((unsigned int)h) << 16);
}

// fused prep: Wb (conv2 weights bf16), bij zero, scale zero, W1 (conv1 weights bf16)
__global__ void k_prep(const float* __restrict__ cw, const float* __restrict__ pw,
                       unsigned short* __restrict__ W1, unsigned short* __restrict__ Wb,
                       float* __restrict__ bij, float* __restrict__ scale) {
    int idx = blockIdx.x * 256 + threadIdx.x;
    if (idx < 165888) {
        int ci = idx & 31, co = (idx >> 5) & 15, cog = (idx >> 9) & 3, tap = idx >> 11;
        Wb[idx] = f2bf(pw[((cog * 16 + co) * 32 + ci) * 81 + tap]);
        return;
    }
    idx -= 165888;
    if (idx < 23120) { bij[idx] = 0.f; return; }
    idx -= 23120;
    if (idx < 1024) { scale[idx] = 0.f; return; }
    idx -= 1024;
    if (idx < 32 * K1) {
        int co = idx / K1, k = idx - co * K1;
        int g = k / 12, kw = k - g * 12;
        float v = (kw < 9 && g < 27) ? cw[((co * 3 + g / 9) * 9 + (g % 9)) * 9 + kw] : 0.f;
        W1[idx] = f2bf(v);
    }
}

// conv1 via im2col-in-LDS MFMA: data fp32 -> xh bf16 [b][p][co=32] (+bias+relu)
__global__ __launch_bounds__(512) void k_conv1m(const float* __restrict__ data,
                                                const unsigned short* __restrict__ W1,
                                                const float* __restrict__ cb,
                                                unsigned short* __restrict__ xh) {
    int b = blockIdx.x / 27, g64 = blockIdx.x % 27;
    int p0 = g64 * 64;
    int t = threadIdx.x, lane = t & 63, wv = t >> 6;      // wv 0..7
    int quad = lane >> 4, mloc = lane & 15;
    int msub = wv & 3, chh = wv >> 2;
    __shared__ __align__(16) unsigned short As[88 * 64 * 4];   // 45056 B
    u64* ab = (u64*)As;
    for (int k = 81 * 64 + t; k < 88 * 64; k += 512) ab[k] = 0ull;
#pragma unroll 1
    for (int it = 0; it < 4; it++) {
        int g = wv + it * 8;
        if (g < 27) {
            int m = lane;
            int p = p0 + m; if (p > 1680) p = 1680;
            int h = p / 41, w = p - h * 41;
            int ci = g / 9, kh = g - ci * 9;
            const float* src = &data[((b * 3 + ci) * 49 + (h + kh)) * 49 + w];
            unsigned short pk[12];
#pragma unroll
            for (int kw = 0; kw < 9; kw++) pk[kw] = f2bf(src[kw]);
            pk[9] = 0; pk[10] = 0; pk[11] = 0;
            const u64* s = (const u64*)pk;
            ab[(3 * g + 0) * 64 + m] = s[0];
            ab[(3 * g + 1) * 64 + m] = s[1];
            ab[(3 * g + 2) * 64 + m] = s[2];
        }
    }
    __syncthreads();
    f32x4 acc = {0.f, 0.f, 0.f, 0.f};
    const unsigned short* wp = &W1[(size_t)(chh * 16 + mloc) * K1 + quad * 8];
    int mrow = msub * 16 + mloc;
#pragma unroll 1
    for (int kc = 0; kc < 11; kc++) {
        int c = kc * 8 + quad * 2;
        union { short8 v; u64 q[2]; } af;
        af.q[0] = ab[c * 64 + mrow];
        af.q[1] = ab[(c + 1) * 64 + mrow];
        short8 bfr = *(const short8*)(wp + kc * 32);
        acc = __builtin_amdgcn_mfma_f32_16x16x32_bf16(af.v, bfr, acc, 0, 0, 0);
    }
    __syncthreads();
    unsigned short* tile = As;                    // reuse: [64 m][40]
    float bias = cb[chh * 16 + mloc];
#pragma unroll
    for (int r = 0; r < 4; r++) {
        int m = msub * 16 + quad * 4 + r;
        float v0 = acc[r] + bias; v0 = v0 > 0.f ? v0 : 0.f;
        tile[m * 40 + chh * 16 + mloc] = f2bf(v0);
    }
    __syncthreads();
    if (t < 256) {
        int m = t >> 2, part = t & 3;
        int p = p0 + m;
        if (p < 1681)
            *(int4*)&xh[((size_t)(b * 1681 + p)) * 32 + part * 8] =
                *(const int4*)&tile[m * 40 + part * 8];
    }
}

// conv2 implicit-GEMM MFMA -> xTb bf16 directly (+ sumsq into scale).
// Grid 512 = (b, g of {73,72,72,72} positions), uniform 2 blocks/CU.
// 8 waves = 4 cg x 2 tap-halves; each wave: all 5 m-tiles for its cg.
// A-tile parity-split cols (e = even: col/2, odd: 21+col/2), stride 36 shorts.
__global__ __launch_bounds__(512) void k_conv2(const unsigned short* __restrict__ xh,
                                               const unsigned short* __restrict__ Wb,
                                               const float* __restrict__ pb,
                                               unsigned short* __restrict__ xTb,
                                               float* __restrict__ scale) {
    const int pstart[5] = {0, 73, 145, 217, 289};
    int b = blockIdx.x >> 2, g = blockIdx.x & 3;
    int p0 = pstart[g], np = pstart[g + 1] - p0;
    int r0 = 2 * (p0 / 17);
    int t = threadIdx.x, lane = t & 63, wv = t >> 6;
    int quad = lane >> 4, mloc = lane & 15;
    int cg = wv & 3, th = wv >> 2;
    __shared__ __align__(16) char lds[50184];     // max(17*41*36*2, 64*81*4)
    __shared__ float pbs[64];
    unsigned short* As = (unsigned short*)lds;
    if (t < 64) pbs[t] = pb[t];
    const unsigned short* xb = xh + (size_t)b * 53792;   // 1681*32
    for (int k = t; k < 17 * 164; k += 512) {
        int rl = k / 164, rem = k - rl * 164;
        int col = rem >> 2, ci8 = rem & 3;
        int e = (col & 1) ? 21 + (col >> 1) : (col >> 1);
        const u64* src = (const u64*)&xb[((r0 + rl) * 41 + col) * 32 + ci8 * 8];
        u64* dst = (u64*)&As[(rl * 41 + e) * 36 + ci8 * 8];
        dst[0] = src[0];
        dst[1] = src[1];
    }
    __syncthreads();
    int abase[5];
#pragma unroll
    for (int mt = 0; mt < 5; mt++) {
        int p = p0 + mt * 16 + mloc;
        if (p > 288) p = 288;
        abase[mt] = ((2 * (p / 17) - r0) * 41 + (p % 17)) * 36 + quad * 8;
    }
    const unsigned short* wbase = Wb + ((size_t)cg * 16 + mloc) * 32 + quad * 8;
    f32x4 acc[5];
#pragma unroll
    for (int mt = 0; mt < 5; mt++)
#pragma unroll
        for (int r = 0; r < 4; r++) acc[mt][r] = 0.f;
    int kh0 = th ? 5 : 0, kh1 = th ? 9 : 5;
#pragma unroll 1
    for (int kh = kh0; kh < kh1; kh++) {
        const unsigned short* wrow = wbase + (size_t)kh * 9 * 2048;
#pragma unroll
        for (int kw = 0; kw < 9; kw++) {
            short8 bf = *(const short8*)(wrow + (size_t)kw * 2048);
            int c0 = (kw & 1) ? 21 + (kw >> 1) : (kw >> 1);
            int off = (kh * 41 + c0) * 36;
#pragma unroll
            for (int mt = 0; mt < 5; mt++) {
                union { short8 v; u64 q[2]; } a;
                a.q[0] = *(const u64*)&As[abase[mt] + off];
                a.q[1] = *(const u64*)&As[abase[mt] + off + 4];
                acc[mt] = __builtin_amdgcn_mfma_f32_16x16x32_bf16(a.v, bf, acc[mt], 0, 0, 0);
            }
        }
    }
    __syncthreads();                              // done reading A-tile
    float* tile = (float*)lds;                    // [64 ch][81]
    if (th == 0) {
#pragma unroll
        for (int mt = 0; mt < 5; mt++)
#pragma unroll
            for (int r = 0; r < 4; r++)
                tile[(cg * 16 + mloc) * 81 + mt * 16 + quad * 4 + r] = acc[mt][r];
    }
    __syncthreads();
    if (th == 1) {
#pragma unroll
        for (int mt = 0; mt < 5; mt++)
#pragma unroll
            for (int r = 0; r < 4; r++)
                tile[(cg * 16 + mloc) * 81 + mt * 16 + quad * 4 + r] += acc[mt][r];
    }
    __syncthreads();
    // epilogue: (j, pp) -> pack 8 i's, write xTb[(j*289+p)*128+b][i], sumsq per i
    float ssq[8] = {0.f, 0.f, 0.f, 0.f, 0.f, 0.f, 0.f, 0.f};
#pragma unroll 1
    for (int idx = t; idx < 8 * np; idx += 512) {
        int pp = idx >> 3, j = idx & 7;
        unsigned short pk[8];
#pragma unroll
        for (int i = 0; i < 8; i++) {
            float val = tile[(i * 8 + j) * 81 + pp] + pbs[i * 8 + j];
            pk[i] = f2bf(val);
            ssq[i] += val * val;
        }
        *(int4*)&xTb[((size_t)(j * 289 + p0 + pp) * 128 + b) * 8] = *(const int4*)pk;
    }
#pragma unroll
    for (int i = 0; i < 8; i++) {
        float s = ssq[i];
#pragma unroll
        for (int d = 1; d < 64; d <<= 1) s += __shfl_xor(s, d);
        if (lane == 0) atomicAdd(&scale[b * 8 + i], s);
    }
}

// in-place squash scale: xTb[r][b][i] *= sn/((1+sn)sqrt(sn)), sn = scale[b*8+i]
__global__ __launch_bounds__(256) void k_xt(unsigned short* __restrict__ xTb,
                                            const float* __restrict__ scale) {
    __shared__ float fs[1024];
    int t = threadIdx.x;
    for (int k = t; k < 1024; k += 256) {
        float sn = scale[k];
        fs[k] = sn / ((1.f + sn) * sqrtf(sn));
    }
    __syncthreads();
    int idx = blockIdx.x * 256 + t;               // (r,b), 2312*128 exact
    int b = idx & 127;
    unsigned short* p = &xTb[(size_t)idx * 8];
    union { int4 v; unsigned short u[8]; } d;
    d.v = *(const int4*)p;
#pragma unroll
    for (int i = 0; i < 8; i++) d.u[i] = f2bf(bf2f(d.u[i]) * fs[b * 8 + i]);
    *(int4*)p = d.v;
}

// s partials via MFMA (softmax fused): block (chunk of 34 r, c)
// spart layout: [chunk][c][b][o]
__global__ __launch_bounds__(256) void k_s(const unsigned short* __restrict__ xTb,
                                           const float* __restrict__ W,
                                           const float* __restrict__ bij,
                                           float* __restrict__ spart) {
    int chunk = blockIdx.x / NC, c = blockIdx.x % NC;
    int r0 = chunk * RC;
    __shared__ __align__(16) unsigned short As[16 * 296];   // 9472 B
    __shared__ float cs[RC];
    int t = threadIdx.x;
    { int o = t >> 4, kk = t & 15; As[o * 296 + 272 + kk] = 0; }  // zero pad k 272..287
    if (t < RC) {
        int r = r0 + t;
        float x[NC], m = -1e30f;
#pragma unroll
        for (int k = 0; k < NC; k++) { x[k] = bij[r * NC + k]; m = fmaxf(m, x[k]); }
        float s = 0.f;
#pragma unroll
        for (int k = 0; k < NC; k++) { x[k] = expf(x[k] - m); s += x[k]; }
        cs[t] = x[c] / s;
    }
    __syncthreads();
    for (int k = t; k < RC * 16; k += 256) {
        int rr = k >> 4, o = k & 15;
        const float* wsrc = &W[(size_t)(r0 + rr) * 1280 + c * 128 + o * 8];
        float cr = cs[rr];
        unsigned short pk[8];
#pragma unroll
        for (int i = 0; i < 8; i++) pk[i] = f2bf(wsrc[i] * cr);
        *(int4*)&As[o * 296 + rr * 8] = *(const int4*)pk;
    }
    __syncthreads();
    int lane = t & 63, wv = t >> 6;
    int quad = lane >> 4, mloc = lane & 15;
    int n0 = wv * 32;
    f32x4 acc0 = {0.f, 0.f, 0.f, 0.f}, acc1 = {0.f, 0.f, 0.f, 0.f};
    const unsigned short* ap = &As[mloc * 296 + quad * 8];
#pragma unroll
    for (int kc = 0; kc < 9; kc++) {
        short8 af = *(const short8*)(ap + kc * 32);
        const unsigned short* bb = &xTb[(size_t)(r0 + kc * 4 + quad) * 1024];
        short8 b0 = *(const short8*)(bb + (n0 + mloc) * 8);
        short8 b1 = *(const short8*)(bb + (n0 + 16 + mloc) * 8);
        acc0 = __builtin_amdgcn_mfma_f32_16x16x32_bf16(af, b0, acc0, 0, 0, 0);
        acc1 = __builtin_amdgcn_mfma_f32_16x16x32_bf16(af, b1, acc1, 0, 0, 0);
    }
    float* sp = &spart[(size_t)(chunk * NC + c) * 2048];   // [b][o]
    *(f32x4*)&sp[(n0 + mloc) * 16 + quad * 4] = acc0;
    *(f32x4*)&sp[(n0 + 16 + mloc) * 16 + quad * 4] = acc1;
}

// reduce spart over chunks, squash -> v, vT, out; fused head on last iteration.
// grid 1280 = (b,c); 256 thr = 16 chunk-lanes x 16 o.
__global__ __launch_bounds__(256) void k_v(const float* __restrict__ spart,
                    float* __restrict__ v, float* __restrict__ vT,
                    float* __restrict__ out,
                    const float* __restrict__ w1, const float* __restrict__ b1,
                    const float* __restrict__ w2, const float* __restrict__ b2,
                    int do_head) {
    int b = blockIdx.x / NC, c = blockIdx.x % NC;
    int t = threadIdx.x;
    int cl = t >> 4, o = t & 15;
    float s = 0.f;
#pragma unroll 1
    for (int ch = cl; ch < NCH; ch += 16)
        s += spart[((size_t)(ch * NC + c) * 128 + b) * 16 + o];
    s += __shfl_xor(s, 16);
    s += __shfl_xor(s, 32);
    __shared__ float red[4][16];
    __shared__ float hred[2];
    if ((t & 63) < 16) red[t >> 6][t & 15] = s;
    __syncthreads();
    if (t < 16) {
        float sum = red[0][t] + red[1][t] + red[2][t] + red[3][t];
        float sq = sum * sum;
#pragma unroll
        for (int d = 1; d < 16; d <<= 1) sq += __shfl_xor(sq, d);
        float vv = sum * sq / ((1.f + sq) * sqrtf(sq));
        int idx = (b * NC + c) * 16 + t;
        v[idx] = vv;
        out[idx] = vv;
        vT[(c * 16 + t) * 128 + b] = vv;
        red[0][t] = vv;
    }
    if (do_head) {
        __syncthreads();
        float partial = 0.f;
        if (t < 100) {
            float hs = b1[c * 100 + t];
#pragma unroll
            for (int i = 0; i < 16; i++) hs = fmaf(red[0][i], w1[(c * 16 + i) * 100 + t], hs);
            partial = tanhf(hs) * w2[c * 100 + t];
        }
#pragma unroll
        for (int d = 1; d < 64; d <<= 1) partial += __shfl_xor(partial, d);
        if ((t & 63) == 0 && t < 128) hred[t >> 6] = partial;
        __syncthreads();
        if (t == 0)
            out[20480 + c * 128 + b] = 1.f / (1.f + expf(-(hred[0] + hred[1] + b2[c])));
    }
}

// a[r,c] = 1/B * sum_{b,o} vT[c,o,b] * sum_i W[r,c,o,i]*xTb[r,b,i];  bij += a
__global__ __launch_bounds__(256) void k_a(const unsigned short* __restrict__ xTb,
                                           const float* __restrict__ W,
                                           const float* __restrict__ vT,
                                           float* __restrict__ bij) {
    int wv = threadIdx.x >> 6, lane = threadIdx.x & 63;
    int wid = __builtin_amdgcn_readfirstlane(blockIdx.x * 4 + wv);
    int r = wid / NC, c = wid - r * NC;
    const unsigned short* xr = &xTb[(size_t)r * 1024];
    union { short8 v; unsigned short u[8]; } s0, s1;
    s0.v = *(const short8*)(xr + lane * 8);
    s1.v = *(const short8*)(xr + (lane + 64) * 8);
    float x0[8], x1[8];
#pragma unroll
    for (int i = 0; i < 8; i++) { x0[i] = bf2f(s0.u[i]); x1[i] = bf2f(s1.u[i]); }
    const float* wr = &W[(size_t)r * 1280 + c * 128];
    const float* vc = &vT[c * 2048];
    float acc = 0.f;
#pragma unroll
    for (int o = 0; o < 16; o++) {
        float w[8];
#pragma unroll
        for (int i = 0; i < 8; i++) w[i] = wr[o * 8 + i];
        float u0 = 0.f, u1 = 0.f;
#pragma unroll
        for (int i = 0; i < 8; i++) { u0 = fmaf(w[i], x0[i], u0); u1 = fmaf(w[i], x1[i], u1); }
        acc = fmaf(vc[o * 128 + lane], u0, acc);
        acc = fmaf(vc[o * 128 + lane + 64], u1, acc);
    }
#pragma unroll
    for (int d = 1; d < 64; d <<= 1) acc += __shfl_xor(acc, d);
    if (lane == 0) bij[wid] += acc * 0.0078125f;
}

extern "C" void kernel_launch(void* const* d_in, const int* in_sizes, int n_in,
                              void* d_out, int out_size, void* d_ws, size_t ws_size,
                              hipStream_t stream) {
    const float* data   = (const float*)d_in[0];
    const float* conv_w = (const float*)d_in[1];
    const float* conv_b = (const float*)d_in[2];
    const float* prim_w = (const float*)d_in[3];
    const float* prim_b = (const float*)d_in[4];
    const float* Wd     = (const float*)d_in[5];
    const float* hw1    = (const float*)d_in[6];
    const float* hb1    = (const float*)d_in[7];
    const float* hw2    = (const float*)d_in[8];
    const float* hb2    = (const float*)d_in[9];
    float* ws = (float*)d_ws;
    unsigned short* xh  = (unsigned short*)(ws + OFF_XH);
    unsigned short* xTb = (unsigned short*)(ws + OFF_XTB);
    float* scale = ws + OFF_SC;
    float* bij   = ws + OFF_BIJ;
    float* spart = ws + OFF_SP;
    float* v     = ws + OFF_V;
    unsigned short* Wb  = (unsigned short*)(ws + OFF_WB);
    float* vT    = ws + OFF_VT;
    unsigned short* W1  = (unsigned short*)(ws + OFF_W1);
    float* out = (float*)d_out;

    k_prep<<<787, 256, 0, stream>>>(conv_w, prim_w, W1, Wb, bij, scale);
    k_conv1m<<<128 * 27, 512, 0, stream>>>(data, W1, conv_b, xh);
    k_conv2<<<128 * 4, 512, 0, stream>>>(xh, Wb, prim_b, xTb, scale);
    k_xt<<<1156, 256, 0, stream>>>(xTb, scale);
    for (int it = 0; it < 3; it++) {
        k_s<<<NCH * NC, 256, 0, stream>>>(xTb, Wd, bij, spart);
        k_v<<<128 * NC, 256, 0, stream>>>(spart, v, vT, out, hw1, hb1, hw2, hb2,
                                          it == 2 ? 1 : 0);
        if (it < 2) k_a<<<5780, 256, 0, stream>>>(xTb, Wd, vT, bij);
    }
}